// Round 5
// baseline (1119.936 us; speedup 1.0000x reference)
//
#include <hip/hip_runtime.h>
#include <hip/hip_bf16.h>
#include <cstddef>

#define N_NODES 100000
#define E_EDGES 1600000
#define TOT_EDGES (E_EDGES + N_NODES)
#define NEG_SLOPE 0.2f
#define BN_EPS 1e-5f

typedef __attribute__((ext_vector_type(8))) short short8;
typedef __attribute__((ext_vector_type(4))) float f32x4;

__device__ __forceinline__ unsigned short f2bf(float f) {
    union { float f; unsigned u; } c; c.f = f;
    unsigned u = c.u;
    u += 0x7fffu + ((u >> 16) & 1u);
    return (unsigned short)(u >> 16);
}
__device__ __forceinline__ float bf2f(unsigned short h) {
    union { unsigned u; float f; } c; c.u = ((unsigned)h) << 16;
    return c.f;
}
__device__ __forceinline__ float bflo(unsigned u) {
    union { unsigned u; float f; } c; c.u = u << 16; return c.f;
}
__device__ __forceinline__ float bfhi(unsigned u) {
    union { unsigned u; float f; } c; c.u = u & 0xffff0000u; return c.f;
}
__device__ __forceinline__ float lrelu(float t) {
    return (t > 0.f) ? t : NEG_SLOPE * t;
}

// ---------------------------------------------------------------------------
// CSR build
// ---------------------------------------------------------------------------

__global__ __launch_bounds__(256) void count_kernel(const int* __restrict__ ei,
                                                    int* __restrict__ counts) {
    int idx = blockIdx.x * blockDim.x + threadIdx.x;
    int stride = gridDim.x * blockDim.x;
    for (int e = idx; e < TOT_EDGES; e += stride) {
        int d = (e < E_EDGES) ? ei[E_EDGES + e] : (e - E_EDGES);
        atomicAdd(&counts[d], 1);
    }
}

__global__ __launch_bounds__(256) void scan_partial(const int* __restrict__ counts,
                                                    int* __restrict__ partials) {
    __shared__ int s[256];
    int t = threadIdx.x;
    int i = blockIdx.x * 256 + t;
    s[t] = (i < N_NODES) ? counts[i] : 0;
    __syncthreads();
    for (int off = 128; off; off >>= 1) {
        if (t < off) s[t] += s[t + off];
        __syncthreads();
    }
    if (t == 0) partials[blockIdx.x] = s[0];
}

__global__ __launch_bounds__(512) void scan_partials_kernel(int* __restrict__ partials, int nb) {
    __shared__ int s[512];
    int t = threadIdx.x;
    int v = (t < nb) ? partials[t] : 0;
    s[t] = v;
    __syncthreads();
    for (int off = 1; off < 512; off <<= 1) {
        int y = (t >= off) ? s[t - off] : 0;
        __syncthreads();
        s[t] += y;
        __syncthreads();
    }
    if (t < nb) partials[t] = s[t] - v;
}

__global__ __launch_bounds__(256) void scan_final(const int* __restrict__ counts,
                                                  const int* __restrict__ partials,
                                                  int* __restrict__ row_ptr,
                                                  int* __restrict__ write_pos) {
    __shared__ int s[256];
    int t = threadIdx.x;
    int i = blockIdx.x * 256 + t;
    int v = (i < N_NODES) ? counts[i] : 0;
    s[t] = v;
    __syncthreads();
    for (int off = 1; off < 256; off <<= 1) {
        int y = (t >= off) ? s[t - off] : 0;
        __syncthreads();
        s[t] += y;
        __syncthreads();
    }
    int excl = s[t] - v;
    int rp = partials[blockIdx.x] + excl;
    if (i <= N_NODES) row_ptr[i] = rp;
    if (i < N_NODES) write_pos[i] = rp;
}

__global__ __launch_bounds__(256) void scatter_kernel(const int* __restrict__ ei,
                                                      int* __restrict__ write_pos,
                                                      int* __restrict__ src_sorted) {
    int idx = blockIdx.x * blockDim.x + threadIdx.x;
    int stride = gridDim.x * blockDim.x;
    for (int e = idx; e < TOT_EDGES; e += stride) {
        int srcv, d;
        if (e < E_EDGES) { srcv = ei[e]; d = ei[E_EDGES + e]; }
        else             { srcv = e - E_EDGES; d = srcv; }
        int p = atomicAdd(&write_pos[d], 1);
        src_sorted[p] = srcv;
    }
}

// ---------------------------------------------------------------------------
// Conversions
// ---------------------------------------------------------------------------

__global__ __launch_bounds__(256) void xconv(const float* __restrict__ x,
                                             unsigned short* __restrict__ hi,
                                             unsigned short* __restrict__ lo, int n) {
    int idx = blockIdx.x * blockDim.x + threadIdx.x;
    int stride = gridDim.x * blockDim.x;
    for (int i = idx; i < n; i += stride) {
        float v = x[i];
        unsigned short h = f2bf(v);
        hi[i] = h;
        lo[i] = f2bf(v - bf2f(h));
    }
}

// W [K][Nn] fp32 -> BT [Np][K] bf16 hi/lo (rows n >= Nn zero-padded)
__global__ __launch_bounds__(256) void wconv(const float* __restrict__ W,
                                             unsigned short* __restrict__ bth,
                                             unsigned short* __restrict__ btl,
                                             int K, int Nn, int Np) {
    int idx = blockIdx.x * blockDim.x + threadIdx.x;
    int total = Np * K;
    if (idx >= total) return;
    int n = idx / K, k = idx % K;
    float v = (n < Nn) ? W[k * Nn + n] : 0.f;
    unsigned short h = f2bf(v);
    bth[idx] = h;
    btl[idx] = f2bf(v - bf2f(h));
}

// alpha B-tile: rows 0/1 = split-bf16 of (W @ a_s) / (W @ a_d), rows 2..15 zero.
__global__ __launch_bounds__(256) void wav_kernel(const float* __restrict__ W,
                                                  const float* __restrict__ a_s,
                                                  const float* __restrict__ a_d,
                                                  int K, int Nn,
                                                  unsigned short* __restrict__ abh,
                                                  unsigned short* __restrict__ abl) {
    int idx = blockIdx.x * 256 + threadIdx.x;
    if (idx >= 16 * K) return;
    int r = idx / K, k = idx - r * K;
    float v = 0.f;
    if (r < 2) {
        const float* a = r ? a_d : a_s;
        const float* wr = W + (size_t)k * Nn;
        for (int n = 0; n < Nn; n++) v += wr[n] * a[n];
    }
    unsigned short h = f2bf(v);
    abh[idx] = h;
    abl[idx] = f2bf(v - bf2f(h));
}

// ---------------------------------------------------------------------------
// Split-bf16 MFMA GEMM (hi*hi + hi*lo + lo*hi) with fused alpha dots.
// Wave-group 0 (wave%NWAVES==0) additionally multiplies by the alpha B-tile
// (16 cols: col0=W@a_s, col1=W@a_d) and stores asrc/adst in the epilogue.
// ---------------------------------------------------------------------------
template<int K, int NTILES, int MWAVES, int NWAVES, int NACT, bool CFP32>
__global__ __launch_bounds__(256) void mfma_gemm(
    const unsigned short* __restrict__ Ahi, const unsigned short* __restrict__ Alo,
    const unsigned short* __restrict__ BThi, const unsigned short* __restrict__ BTlo,
    const unsigned short* __restrict__ ABh, const unsigned short* __restrict__ ABl,
    unsigned short* __restrict__ Chi, float* __restrict__ Cf,
    float* __restrict__ asrc, float* __restrict__ adst, int M)
{
    int lane = threadIdx.x & 63;
    int wave = threadIdx.x >> 6;
    int quad = lane >> 4;
    int l16  = lane & 15;
    long mbase = (long)blockIdx.x * (64 * MWAVES) + (long)(wave / NWAVES) * 64;
    int n0 = (wave % NWAVES) * (NTILES * 16);
    bool aw = (wave % NWAVES) == 0;

    const unsigned short* ah[4]; const unsigned short* al[4];
#pragma unroll
    for (int i = 0; i < 4; i++) {
        long r = mbase + i * 16 + l16;
        if (r > M - 1) r = M - 1;
        ah[i] = Ahi + r * K; al[i] = Alo + r * K;
    }
    const unsigned short* bh[NTILES]; const unsigned short* bl[NTILES];
#pragma unroll
    for (int j = 0; j < NTILES; j++) {
        long n = n0 + j * 16 + l16;
        bh[j] = BThi + n * K; bl[j] = BTlo + n * K;
    }
    const unsigned short* bah = ABh + (size_t)l16 * K;
    const unsigned short* bal = ABl + (size_t)l16 * K;
    const int ko = quad * 8;

    f32x4 acc[4][NTILES];
    f32x4 acca[4];
#pragma unroll
    for (int i = 0; i < 4; i++) {
        acca[i] = (f32x4){0.f, 0.f, 0.f, 0.f};
#pragma unroll
        for (int j = 0; j < NTILES; j++)
            acc[i][j] = (f32x4){0.f, 0.f, 0.f, 0.f};
    }

    for (int k0 = 0; k0 < K; k0 += 32) {
        short8 vah[4], vall[4], vbh[NTILES], vbl[NTILES];
#pragma unroll
        for (int i = 0; i < 4; i++) {
            vah[i]  = *(const short8*)(ah[i] + k0 + ko);
            vall[i] = *(const short8*)(al[i] + k0 + ko);
        }
#pragma unroll
        for (int j = 0; j < NTILES; j++) {
            vbh[j] = *(const short8*)(bh[j] + k0 + ko);
            vbl[j] = *(const short8*)(bl[j] + k0 + ko);
        }
#pragma unroll
        for (int i = 0; i < 4; i++)
#pragma unroll
            for (int j = 0; j < NTILES; j++) {
                acc[i][j] = __builtin_amdgcn_mfma_f32_16x16x32_bf16(vah[i],  vbh[j], acc[i][j], 0, 0, 0);
                acc[i][j] = __builtin_amdgcn_mfma_f32_16x16x32_bf16(vah[i],  vbl[j], acc[i][j], 0, 0, 0);
                acc[i][j] = __builtin_amdgcn_mfma_f32_16x16x32_bf16(vall[i], vbh[j], acc[i][j], 0, 0, 0);
            }
        if (aw) {
            short8 vbah = *(const short8*)(bah + k0 + ko);
            short8 vbal = *(const short8*)(bal + k0 + ko);
#pragma unroll
            for (int i = 0; i < 4; i++) {
                acca[i] = __builtin_amdgcn_mfma_f32_16x16x32_bf16(vah[i],  vbah, acca[i], 0, 0, 0);
                acca[i] = __builtin_amdgcn_mfma_f32_16x16x32_bf16(vah[i],  vbal, acca[i], 0, 0, 0);
                acca[i] = __builtin_amdgcn_mfma_f32_16x16x32_bf16(vall[i], vbah, acca[i], 0, 0, 0);
            }
        }
    }

#pragma unroll
    for (int i = 0; i < 4; i++)
#pragma unroll
        for (int j = 0; j < NTILES; j++)
#pragma unroll
            for (int r = 0; r < 4; r++) {
                long row = mbase + i * 16 + quad * 4 + r;
                int col = n0 + j * 16 + l16;
                if (row < M && col < NACT) {
                    float v = acc[i][j][r];
                    if constexpr (CFP32) Cf[row * NACT + col] = v;
                    else                 Chi[row * NACT + col] = f2bf(v);
                }
            }
    if (aw) {
#pragma unroll
        for (int i = 0; i < 4; i++)
#pragma unroll
            for (int r = 0; r < 4; r++) {
                long row = mbase + i * 16 + quad * 4 + r;
                if (row < M) {
                    float v = acca[i][r];
                    if (l16 == 0) asrc[row] = v;
                    else if (l16 == 1) adst[row] = v;
                }
            }
    }
}

// ---------------------------------------------------------------------------
// node_alpha: per-node segment softmax -> packed {src, alpha} per edge
// ---------------------------------------------------------------------------
__global__ __launch_bounds__(256) void node_alpha(
    const float* __restrict__ asrc, const float* __restrict__ adst,
    const int* __restrict__ row_ptr, const int* __restrict__ src_sorted,
    uint2* __restrict__ epair)
{
    int wave = threadIdx.x >> 6;
    int lane = threadIdx.x & 63;
    int node = blockIdx.x * 4 + wave;
    if (node >= N_NODES) return;
    int start = row_ptr[node];
    int end = row_ptr[node + 1];
    float ad = adst[node];

    int e0 = start + lane;
    int s_c = 0; float l_c = -1e30f;
    if (e0 < end) {
        s_c = src_sorted[e0];
        l_c = lrelu(asrc[s_c] + ad);
    }
    float m = l_c;
    for (int e = e0 + 64; e < end; e += 64) {
        int s = src_sorted[e];
        m = fmaxf(m, lrelu(asrc[s] + ad));
    }
#pragma unroll
    for (int off = 32; off; off >>= 1) m = fmaxf(m, __shfl_xor(m, off));

    float d = (e0 < end) ? __expf(l_c - m) : 0.f;
    for (int e = e0 + 64; e < end; e += 64) {
        int s = src_sorted[e];
        d += __expf(lrelu(asrc[s] + ad) - m);
    }
#pragma unroll
    for (int off = 32; off; off >>= 1) d += __shfl_xor(d, off);
    float inv = 1.0f / d;

    if (e0 < end)
        epair[e0] = make_uint2((unsigned)s_c, __float_as_uint(__expf(l_c - m) * inv));
    for (int e = e0 + 64; e < end; e += 64) {
        int s = src_sorted[e];
        float a = __expf(lrelu(asrc[s] + ad) - m) * inv;
        epair[e] = make_uint2((unsigned)s, __float_as_uint(a));
    }
}

// ---------------------------------------------------------------------------
// gat_agg4: wave per node; lanes split into GROUPS groups of LPG lanes, each
// group covers one full feature row per load (16 B/lane bf16, 8 B/lane fp32).
// {src, alpha} broadcast via v_readlane + cndmask select; one-ahead register
// double-buffer keeps the next row-load in flight during FMAs.
// ---------------------------------------------------------------------------
template<int EPI>
__device__ __forceinline__ int sel_bcast(int v, int base, int g) {
    int s0 = __builtin_amdgcn_readlane(v, base);
    if constexpr (EPI == 1) return s0;
    int s1 = __builtin_amdgcn_readlane(v, base + 1);
    if constexpr (EPI == 2) return g ? s1 : s0;
    int s2 = __builtin_amdgcn_readlane(v, base + 2);
    if constexpr (EPI == 3) return (g >= 2) ? s2 : (g ? s1 : s0);
    int s3 = __builtin_amdgcn_readlane(v, base + 3);
    return (g & 1) ? ((g & 2) ? s3 : s1) : ((g & 2) ? s2 : s0);
}

template<int F, int GROUPS, int LPG, bool G32, bool ACT, bool OSPLIT>
__global__ __launch_bounds__(256) void gat_agg4(
    const unsigned short* __restrict__ hbf, const float* __restrict__ hf,
    const uint2* __restrict__ epair, const int* __restrict__ row_ptr,
    const float* __restrict__ bias, const float* __restrict__ gamma,
    const float* __restrict__ beta, const float* __restrict__ rmean,
    const float* __restrict__ rvar,
    unsigned short* __restrict__ ohi, unsigned short* __restrict__ olo,
    float* __restrict__ outf)
{
    constexpr int EPI = GROUPS;
    constexpr int CHUNK = (EPI == 3) ? 63 : 64;
    constexpr int NA = G32 ? 2 : 8;          // floats per lane
    int wave = threadIdx.x >> 6;
    int lane = threadIdx.x & 63;
    int node = blockIdx.x * 4 + wave;
    if (node >= N_NODES) return;

    int start = row_ptr[node];
    int end = row_ptr[node + 1];
    int g = lane / LPG;
    int fl = lane - g * LPG;

    float acc[NA];
#pragma unroll
    for (int v = 0; v < NA; v++) acc[v] = 0.f;

    for (int cs = start; cs < end; cs += CHUNK) {
        int cnt = min(CHUNK, end - cs);
        int sv = 0, wv = 0;
        {
            int e = cs + lane;
            if (lane < CHUNK && e < end) { uint2 p = epair[e]; sv = (int)p.x; wv = (int)p.y; }
        }
        int niter = (cnt + EPI - 1) / EPI;

        int ss0 = sel_bcast<EPI>(sv, 0, g);
        uint4 curb; float2 curf;
        if constexpr (G32) curf = *reinterpret_cast<const float2*>(hf + (size_t)ss0 * F + fl * 2);
        else               curb = *reinterpret_cast<const uint4*>(hbf + (size_t)ss0 * F + fl * 8);

        for (int p = 0; p < niter; p++) {
            int wsb = sel_bcast<EPI>(wv, p * EPI, g);
            int pn = p + 1; if (pn >= niter) pn = niter - 1;
            int ssn = sel_bcast<EPI>(sv, pn * EPI, g);
            uint4 nb; float2 nf;
            if constexpr (G32) nf = *reinterpret_cast<const float2*>(hf + (size_t)ssn * F + fl * 2);
            else               nb = *reinterpret_cast<const uint4*>(hbf + (size_t)ssn * F + fl * 8);
            float ww = __int_as_float(wsb);
            if constexpr (G32) {
                acc[0] += ww * curf.x; acc[1] += ww * curf.y;
                curf = nf;
            } else {
                acc[0] += ww * bflo(curb.x); acc[1] += ww * bfhi(curb.x);
                acc[2] += ww * bflo(curb.y); acc[3] += ww * bfhi(curb.y);
                acc[4] += ww * bflo(curb.z); acc[5] += ww * bfhi(curb.z);
                acc[6] += ww * bflo(curb.w); acc[7] += ww * bfhi(curb.w);
                curb = nb;
            }
        }
    }

    // combine groups onto group 0
    float tot[NA];
    if constexpr (GROUPS == 2) {
#pragma unroll
        for (int v = 0; v < NA; v++) tot[v] = acc[v] + __shfl_xor(acc[v], 32);
    } else if constexpr (GROUPS == 4) {
#pragma unroll
        for (int v = 0; v < NA; v++) {
            float t = acc[v] + __shfl_xor(acc[v], 32);
            tot[v] = t + __shfl_xor(t, 16);
        }
    } else {  // GROUPS == 3 (LPG=20, lanes 60..63 idle)
#pragma unroll
        for (int v = 0; v < NA; v++)
            tot[v] = acc[v] + __shfl(acc[v], lane + 20) + __shfl(acc[v], lane + 40);
    }

    if (g != 0) return;
    float vals[NA];
#pragma unroll
    for (int v = 0; v < NA; v++) {
        int f = fl * NA + v;
        float val = tot[v] + bias[f];
        if constexpr (ACT) {
            float rs = rsqrtf(rvar[f] + BN_EPS);
            val = tanhf((val - rmean[f]) * rs * gamma[f] + beta[f]);
        }
        vals[v] = val;
    }
    if constexpr (OSPLIT) {
        unsigned hw[4], lw[4];
#pragma unroll
        for (int q = 0; q < 4; q++) {
            float v0 = vals[2 * q], v1 = vals[2 * q + 1];
            unsigned short h0 = f2bf(v0), h1 = f2bf(v1);
            hw[q] = (unsigned)h0 | ((unsigned)h1 << 16);
            unsigned short l0 = f2bf(v0 - bf2f(h0)), l1 = f2bf(v1 - bf2f(h1));
            lw[q] = (unsigned)l0 | ((unsigned)l1 << 16);
        }
        *reinterpret_cast<uint4*>(ohi + (size_t)node * F + fl * 8) = make_uint4(hw[0], hw[1], hw[2], hw[3]);
        *reinterpret_cast<uint4*>(olo + (size_t)node * F + fl * 8) = make_uint4(lw[0], lw[1], lw[2], lw[3]);
    } else {
        *reinterpret_cast<float2*>(outf + (size_t)node * F + fl * 2) = make_float2(vals[0], vals[1]);
    }
}

// ---------------------------------------------------------------------------

static inline size_t align256(size_t x) { return (x + 255) & ~(size_t)255; }

extern "C" void kernel_launch(void* const* d_in, const int* in_sizes, int n_in,
                              void* d_out, int out_size, void* d_ws, size_t ws_size,
                              hipStream_t stream) {
    const float* x   = (const float*)d_in[0];
    const int* ei    = (const int*)d_in[1];
    const float* w1  = (const float*)d_in[2];
    const float* as1 = (const float*)d_in[3];
    const float* ad1 = (const float*)d_in[4];
    const float* b1  = (const float*)d_in[5];
    const float* g1  = (const float*)d_in[6];
    const float* be1 = (const float*)d_in[7];
    const float* rm1 = (const float*)d_in[8];
    const float* rv1 = (const float*)d_in[9];
    const float* w2  = (const float*)d_in[10];
    const float* as2 = (const float*)d_in[11];
    const float* ad2 = (const float*)d_in[12];
    const float* b2  = (const float*)d_in[13];
    const float* g2  = (const float*)d_in[14];
    const float* be2 = (const float*)d_in[15];
    const float* rm2 = (const float*)d_in[16];
    const float* rv2 = (const float*)d_in[17];
    const float* w3  = (const float*)d_in[18];
    const float* as3 = (const float*)d_in[19];
    const float* ad3 = (const float*)d_in[20];
    const float* b3  = (const float*)d_in[21];
    float* out = (float*)d_out;

    const size_t P128 = align256((size_t)N_NODES * 128 * 2);
    const size_t P256 = align256((size_t)N_NODES * 256 * 2);

    char* p = (char*)d_ws;
    char* regA = p; p += P256;   // xhi|xlo -> o1hi|o1lo -> o2hi
    char* regB = p; p += P256;   // h1hi -> h2hi -> h3f
    char* regC = p; p += P256;   // o2lo
    unsigned short* xhi  = (unsigned short*)regA;
    unsigned short* xlo  = (unsigned short*)(regA + P128);
    unsigned short* o1hi = xhi;
    unsigned short* o1lo = xlo;
    unsigned short* o2hi = (unsigned short*)regA;
    unsigned short* h1hi = (unsigned short*)regB;
    unsigned short* h2hi = (unsigned short*)regB;
    float*          h3f  = (float*)regB;
    unsigned short* o2lo = (unsigned short*)regC;

    float* asrc = (float*)p;  p += align256((size_t)N_NODES * 4);
    float* adst = (float*)p;  p += align256((size_t)N_NODES * 4);
    int* counts    = (int*)p; p += align256((size_t)N_NODES * 4);
    int* row_ptr   = (int*)p; p += align256((size_t)(N_NODES + 1) * 4);
    int* write_pos = (int*)p; p += align256((size_t)N_NODES * 4);
    int* src_sorted = (int*)p; p += align256((size_t)TOT_EDGES * 4);
    uint2* epair   = (uint2*)p; p += align256((size_t)TOT_EDGES * 8);
    int* partials  = (int*)p;  p += align256(512 * 4);
    unsigned short* w1th = (unsigned short*)p; p += align256(128 * 128 * 2);
    unsigned short* w1tl = (unsigned short*)p; p += align256(128 * 128 * 2);
    unsigned short* w2th = (unsigned short*)p; p += align256(256 * 128 * 2);
    unsigned short* w2tl = (unsigned short*)p; p += align256(256 * 128 * 2);
    unsigned short* w3th = (unsigned short*)p; p += align256(48 * 256 * 2);
    unsigned short* w3tl = (unsigned short*)p; p += align256(48 * 256 * 2);
    unsigned short* ab1h = (unsigned short*)p; p += align256(16 * 128 * 2);
    unsigned short* ab1l = (unsigned short*)p; p += align256(16 * 128 * 2);
    unsigned short* ab2h = (unsigned short*)p; p += align256(16 * 128 * 2);
    unsigned short* ab2l = (unsigned short*)p; p += align256(16 * 128 * 2);
    unsigned short* ab3h = (unsigned short*)p; p += align256(16 * 256 * 2);
    unsigned short* ab3l = (unsigned short*)p; p += align256(16 * 256 * 2);

    const int NB = (N_NODES + 255) / 256;

    xconv<<<4096, 256, 0, stream>>>(x, xhi, xlo, N_NODES * 128);
    wconv<<<(128 * 128 + 255) / 256, 256, 0, stream>>>(w1, w1th, w1tl, 128, 128, 128);
    wconv<<<(256 * 128 + 255) / 256, 256, 0, stream>>>(w2, w2th, w2tl, 128, 256, 256);
    wconv<<<(48 * 256 + 255) / 256, 256, 0, stream>>>(w3, w3th, w3tl, 256, 40, 48);
    wav_kernel<<<(16 * 128 + 255) / 256, 256, 0, stream>>>(w1, as1, ad1, 128, 128, ab1h, ab1l);
    wav_kernel<<<(16 * 128 + 255) / 256, 256, 0, stream>>>(w2, as2, ad2, 128, 256, ab2h, ab2l);
    wav_kernel<<<(16 * 256 + 255) / 256, 256, 0, stream>>>(w3, as3, ad3, 256, 40, ab3h, ab3l);

    hipMemsetAsync(counts, 0, (size_t)N_NODES * 4, stream);
    count_kernel<<<4096, 256, 0, stream>>>(ei, counts);
    scan_partial<<<NB, 256, 0, stream>>>(counts, partials);
    scan_partials_kernel<<<1, 512, 0, stream>>>(partials, NB);
    scan_final<<<NB, 256, 0, stream>>>(counts, partials, row_ptr, write_pos);
    scatter_kernel<<<4096, 256, 0, stream>>>(ei, write_pos, src_sorted);

    const int NWB = (N_NODES + 3) / 4;
    const int G64 = (N_NODES + 63) / 64;
    const int G256 = (N_NODES + 255) / 256;

    // --- Layer 1 ---
    mfma_gemm<128, 2, 1, 4, 128, false><<<G64, 256, 0, stream>>>(
        xhi, xlo, w1th, w1tl, ab1h, ab1l, h1hi, nullptr, asrc, adst, N_NODES);
    node_alpha<<<NWB, 256, 0, stream>>>(asrc, adst, row_ptr, src_sorted, epair);
    gat_agg4<128, 4, 16, false, true, true><<<NWB, 256, 0, stream>>>(
        h1hi, nullptr, epair, row_ptr, b1, g1, be1, rm1, rv1, o1hi, o1lo, nullptr);

    // --- Layer 2 ---
    mfma_gemm<128, 4, 1, 4, 256, false><<<G64, 256, 0, stream>>>(
        o1hi, o1lo, w2th, w2tl, ab2h, ab2l, h2hi, nullptr, asrc, adst, N_NODES);
    node_alpha<<<NWB, 256, 0, stream>>>(asrc, adst, row_ptr, src_sorted, epair);
    gat_agg4<256, 2, 32, false, true, true><<<NWB, 256, 0, stream>>>(
        h2hi, nullptr, epair, row_ptr, b2, g2, be2, rm2, rv2, o2hi, o2lo, nullptr);

    // --- Layer 3 ---
    mfma_gemm<256, 3, 4, 1, 40, true><<<G256, 256, 0, stream>>>(
        o2hi, o2lo, w3th, w3tl, ab3h, ab3l, nullptr, h3f, asrc, adst, N_NODES);
    node_alpha<<<NWB, 256, 0, stream>>>(asrc, adst, row_ptr, src_sorted, epair);
    gat_agg4<40, 3, 20, true, false, false><<<NWB, 256, 0, stream>>>(
        nullptr, h3f, epair, row_ptr, b3, b3, b3, b3, b3, nullptr, nullptr, out);
}

// Round 6
// 1099.558 us; speedup vs baseline: 1.0185x; 1.0185x over previous
//
#include <hip/hip_runtime.h>
#include <hip/hip_bf16.h>
#include <cstddef>

#define N_NODES 100000
#define E_EDGES 1600000
#define TOT_EDGES (E_EDGES + N_NODES)
#define NEG_SLOPE 0.2f
#define BN_EPS 1e-5f

typedef __attribute__((ext_vector_type(8))) short short8;
typedef __attribute__((ext_vector_type(4))) float f32x4;

__device__ __forceinline__ unsigned short f2bf(float f) {
    union { float f; unsigned u; } c; c.f = f;
    unsigned u = c.u;
    u += 0x7fffu + ((u >> 16) & 1u);
    return (unsigned short)(u >> 16);
}
__device__ __forceinline__ float bf2f(unsigned short h) {
    union { unsigned u; float f; } c; c.u = ((unsigned)h) << 16;
    return c.f;
}
__device__ __forceinline__ float bflo(unsigned u) {
    union { unsigned u; float f; } c; c.u = u << 16; return c.f;
}
__device__ __forceinline__ float bfhi(unsigned u) {
    union { unsigned u; float f; } c; c.u = u & 0xffff0000u; return c.f;
}
__device__ __forceinline__ float lrelu(float t) {
    return (t > 0.f) ? t : NEG_SLOPE * t;
}

// ---------------------------------------------------------------------------
// CSR build
// ---------------------------------------------------------------------------

__global__ __launch_bounds__(256) void count_kernel(const int* __restrict__ ei,
                                                    int* __restrict__ counts) {
    int idx = blockIdx.x * blockDim.x + threadIdx.x;
    int stride = gridDim.x * blockDim.x;
    for (int e = idx; e < TOT_EDGES; e += stride) {
        int d = (e < E_EDGES) ? ei[E_EDGES + e] : (e - E_EDGES);
        atomicAdd(&counts[d], 1);
    }
}

__global__ __launch_bounds__(256) void scan_partial(const int* __restrict__ counts,
                                                    int* __restrict__ partials) {
    __shared__ int s[256];
    int t = threadIdx.x;
    int i = blockIdx.x * 256 + t;
    s[t] = (i < N_NODES) ? counts[i] : 0;
    __syncthreads();
    for (int off = 128; off; off >>= 1) {
        if (t < off) s[t] += s[t + off];
        __syncthreads();
    }
    if (t == 0) partials[blockIdx.x] = s[0];
}

__global__ __launch_bounds__(512) void scan_partials_kernel(int* __restrict__ partials, int nb) {
    __shared__ int s[512];
    int t = threadIdx.x;
    int v = (t < nb) ? partials[t] : 0;
    s[t] = v;
    __syncthreads();
    for (int off = 1; off < 512; off <<= 1) {
        int y = (t >= off) ? s[t - off] : 0;
        __syncthreads();
        s[t] += y;
        __syncthreads();
    }
    if (t < nb) partials[t] = s[t] - v;
}

__global__ __launch_bounds__(256) void scan_final(const int* __restrict__ counts,
                                                  const int* __restrict__ partials,
                                                  int* __restrict__ row_ptr,
                                                  int* __restrict__ write_pos) {
    __shared__ int s[256];
    int t = threadIdx.x;
    int i = blockIdx.x * 256 + t;
    int v = (i < N_NODES) ? counts[i] : 0;
    s[t] = v;
    __syncthreads();
    for (int off = 1; off < 256; off <<= 1) {
        int y = (t >= off) ? s[t - off] : 0;
        __syncthreads();
        s[t] += y;
        __syncthreads();
    }
    int excl = s[t] - v;
    int rp = partials[blockIdx.x] + excl;
    if (i <= N_NODES) row_ptr[i] = rp;
    if (i < N_NODES) write_pos[i] = rp;
}

__global__ __launch_bounds__(256) void scatter_kernel(const int* __restrict__ ei,
                                                      int* __restrict__ write_pos,
                                                      int* __restrict__ src_sorted) {
    int idx = blockIdx.x * blockDim.x + threadIdx.x;
    int stride = gridDim.x * blockDim.x;
    for (int e = idx; e < TOT_EDGES; e += stride) {
        int srcv, d;
        if (e < E_EDGES) { srcv = ei[e]; d = ei[E_EDGES + e]; }
        else             { srcv = e - E_EDGES; d = srcv; }
        int p = atomicAdd(&write_pos[d], 1);
        src_sorted[p] = srcv;
    }
}

// ---------------------------------------------------------------------------
// Conversions
// ---------------------------------------------------------------------------

__global__ __launch_bounds__(256) void xconv(const float* __restrict__ x,
                                             unsigned short* __restrict__ hi,
                                             unsigned short* __restrict__ lo, int n) {
    int idx = blockIdx.x * blockDim.x + threadIdx.x;
    int stride = gridDim.x * blockDim.x;
    for (int i = idx; i < n; i += stride) {
        float v = x[i];
        unsigned short h = f2bf(v);
        hi[i] = h;
        lo[i] = f2bf(v - bf2f(h));
    }
}

// W [K][Nn] fp32 -> BT [Np][K] bf16 hi/lo (rows n >= Nn zero-padded)
__global__ __launch_bounds__(256) void wconv(const float* __restrict__ W,
                                             unsigned short* __restrict__ bth,
                                             unsigned short* __restrict__ btl,
                                             int K, int Nn, int Np) {
    int idx = blockIdx.x * blockDim.x + threadIdx.x;
    int total = Np * K;
    if (idx >= total) return;
    int n = idx / K, k = idx % K;
    float v = (n < Nn) ? W[k * Nn + n] : 0.f;
    unsigned short h = f2bf(v);
    bth[idx] = h;
    btl[idx] = f2bf(v - bf2f(h));
}

// alpha B-tile: rows 0/1 = split-bf16 of (W @ a_s) / (W @ a_d), rows 2..15 zero.
__global__ __launch_bounds__(256) void wav_kernel(const float* __restrict__ W,
                                                  const float* __restrict__ a_s,
                                                  const float* __restrict__ a_d,
                                                  int K, int Nn,
                                                  unsigned short* __restrict__ abh,
                                                  unsigned short* __restrict__ abl) {
    int idx = blockIdx.x * 256 + threadIdx.x;
    if (idx >= 16 * K) return;
    int r = idx / K, k = idx - r * K;
    float v = 0.f;
    if (r < 2) {
        const float* a = r ? a_d : a_s;
        const float* wr = W + (size_t)k * Nn;
        for (int n = 0; n < Nn; n++) v += wr[n] * a[n];
    }
    unsigned short h = f2bf(v);
    abh[idx] = h;
    abl[idx] = f2bf(v - bf2f(h));
}

// ---------------------------------------------------------------------------
// Split-bf16 MFMA GEMM (hi*hi + hi*lo + lo*hi) with fused alpha dots.
// ---------------------------------------------------------------------------
template<int K, int NTILES, int MWAVES, int NWAVES, int NACT, bool CFP32>
__global__ __launch_bounds__(256) void mfma_gemm(
    const unsigned short* __restrict__ Ahi, const unsigned short* __restrict__ Alo,
    const unsigned short* __restrict__ BThi, const unsigned short* __restrict__ BTlo,
    const unsigned short* __restrict__ ABh, const unsigned short* __restrict__ ABl,
    unsigned short* __restrict__ Chi, float* __restrict__ Cf,
    float* __restrict__ asrc, float* __restrict__ adst, int M)
{
    int lane = threadIdx.x & 63;
    int wave = threadIdx.x >> 6;
    int quad = lane >> 4;
    int l16  = lane & 15;
    long mbase = (long)blockIdx.x * (64 * MWAVES) + (long)(wave / NWAVES) * 64;
    int n0 = (wave % NWAVES) * (NTILES * 16);
    bool aw = (wave % NWAVES) == 0;

    const unsigned short* ah[4]; const unsigned short* al[4];
#pragma unroll
    for (int i = 0; i < 4; i++) {
        long r = mbase + i * 16 + l16;
        if (r > M - 1) r = M - 1;
        ah[i] = Ahi + r * K; al[i] = Alo + r * K;
    }
    const unsigned short* bh[NTILES]; const unsigned short* bl[NTILES];
#pragma unroll
    for (int j = 0; j < NTILES; j++) {
        long n = n0 + j * 16 + l16;
        bh[j] = BThi + n * K; bl[j] = BTlo + n * K;
    }
    const unsigned short* bah = ABh + (size_t)l16 * K;
    const unsigned short* bal = ABl + (size_t)l16 * K;
    const int ko = quad * 8;

    f32x4 acc[4][NTILES];
    f32x4 acca[4];
#pragma unroll
    for (int i = 0; i < 4; i++) {
        acca[i] = (f32x4){0.f, 0.f, 0.f, 0.f};
#pragma unroll
        for (int j = 0; j < NTILES; j++)
            acc[i][j] = (f32x4){0.f, 0.f, 0.f, 0.f};
    }

    for (int k0 = 0; k0 < K; k0 += 32) {
        short8 vah[4], vall[4], vbh[NTILES], vbl[NTILES];
#pragma unroll
        for (int i = 0; i < 4; i++) {
            vah[i]  = *(const short8*)(ah[i] + k0 + ko);
            vall[i] = *(const short8*)(al[i] + k0 + ko);
        }
#pragma unroll
        for (int j = 0; j < NTILES; j++) {
            vbh[j] = *(const short8*)(bh[j] + k0 + ko);
            vbl[j] = *(const short8*)(bl[j] + k0 + ko);
        }
#pragma unroll
        for (int i = 0; i < 4; i++)
#pragma unroll
            for (int j = 0; j < NTILES; j++) {
                acc[i][j] = __builtin_amdgcn_mfma_f32_16x16x32_bf16(vah[i],  vbh[j], acc[i][j], 0, 0, 0);
                acc[i][j] = __builtin_amdgcn_mfma_f32_16x16x32_bf16(vah[i],  vbl[j], acc[i][j], 0, 0, 0);
                acc[i][j] = __builtin_amdgcn_mfma_f32_16x16x32_bf16(vall[i], vbh[j], acc[i][j], 0, 0, 0);
            }
        if (aw) {
            short8 vbah = *(const short8*)(bah + k0 + ko);
            short8 vbal = *(const short8*)(bal + k0 + ko);
#pragma unroll
            for (int i = 0; i < 4; i++) {
                acca[i] = __builtin_amdgcn_mfma_f32_16x16x32_bf16(vah[i],  vbah, acca[i], 0, 0, 0);
                acca[i] = __builtin_amdgcn_mfma_f32_16x16x32_bf16(vah[i],  vbal, acca[i], 0, 0, 0);
                acca[i] = __builtin_amdgcn_mfma_f32_16x16x32_bf16(vall[i], vbah, acca[i], 0, 0, 0);
            }
        }
    }

#pragma unroll
    for (int i = 0; i < 4; i++)
#pragma unroll
        for (int j = 0; j < NTILES; j++)
#pragma unroll
            for (int r = 0; r < 4; r++) {
                long row = mbase + i * 16 + quad * 4 + r;
                int col = n0 + j * 16 + l16;
                if (row < M && col < NACT) {
                    float v = acc[i][j][r];
                    if constexpr (CFP32) Cf[row * NACT + col] = v;
                    else                 Chi[row * NACT + col] = f2bf(v);
                }
            }
    if (aw) {
#pragma unroll
        for (int i = 0; i < 4; i++)
#pragma unroll
            for (int r = 0; r < 4; r++) {
                long row = mbase + i * 16 + quad * 4 + r;
                if (row < M) {
                    float v = acca[i][r];
                    if (l16 == 0) asrc[row] = v;
                    else if (l16 == 1) adst[row] = v;
                }
            }
    }
}

// ---------------------------------------------------------------------------
// node_alpha: per-node segment softmax -> packed {src, alpha} per edge
// ---------------------------------------------------------------------------
__global__ __launch_bounds__(256) void node_alpha(
    const float* __restrict__ asrc, const float* __restrict__ adst,
    const int* __restrict__ row_ptr, const int* __restrict__ src_sorted,
    uint2* __restrict__ epair)
{
    int wave = threadIdx.x >> 6;
    int lane = threadIdx.x & 63;
    int node = blockIdx.x * 4 + wave;
    if (node >= N_NODES) return;
    int start = row_ptr[node];
    int end = row_ptr[node + 1];
    float ad = adst[node];

    int e0 = start + lane;
    int s_c = 0; float l_c = -1e30f;
    if (e0 < end) {
        s_c = src_sorted[e0];
        l_c = lrelu(asrc[s_c] + ad);
    }
    float m = l_c;
    for (int e = e0 + 64; e < end; e += 64) {
        int s = src_sorted[e];
        m = fmaxf(m, lrelu(asrc[s] + ad));
    }
#pragma unroll
    for (int off = 32; off; off >>= 1) m = fmaxf(m, __shfl_xor(m, off));

    float d = (e0 < end) ? __expf(l_c - m) : 0.f;
    for (int e = e0 + 64; e < end; e += 64) {
        int s = src_sorted[e];
        d += __expf(lrelu(asrc[s] + ad) - m);
    }
#pragma unroll
    for (int off = 32; off; off >>= 1) d += __shfl_xor(d, off);
    float inv = 1.0f / d;

    if (e0 < end)
        epair[e0] = make_uint2((unsigned)s_c, __float_as_uint(__expf(l_c - m) * inv));
    for (int e = e0 + 64; e < end; e += 64) {
        int s = src_sorted[e];
        float a = __expf(lrelu(asrc[s] + ad) - m) * inv;
        epair[e] = make_uint2((unsigned)s, __float_as_uint(a));
    }
}

// ---------------------------------------------------------------------------
// gat_agg5: wave per node; GROUPS lane-groups each cover a full feature row
// per load (dwordx4 bf16 / dwordx2 fp32). Batches of 4 iterations: broadcast
// 4*GROUPS {src,alpha} (uniform readlane + cndmask), issue 4 INDEPENDENT row
// loads, then all FMAs. 4 loads in flight per wave, ~12 wave-inst/edge.
// ---------------------------------------------------------------------------
template<int EPI>
__device__ __forceinline__ int sel_bcast(int v, int base, int g) {
    int s0 = __builtin_amdgcn_readlane(v, base);
    if constexpr (EPI == 1) return s0;
    int s1 = __builtin_amdgcn_readlane(v, base + 1);
    if constexpr (EPI == 2) return g ? s1 : s0;
    int s2 = __builtin_amdgcn_readlane(v, base + 2);
    if constexpr (EPI == 3) return (g >= 2) ? s2 : (g ? s1 : s0);
    int s3 = __builtin_amdgcn_readlane(v, base + 3);
    return (g & 1) ? ((g & 2) ? s3 : s1) : ((g & 2) ? s2 : s0);
}

template<int F, int GROUPS, int LPG, bool G32, bool ACT, bool OSPLIT>
__global__ __launch_bounds__(256) void gat_agg5(
    const unsigned short* __restrict__ hbf, const float* __restrict__ hf,
    const uint2* __restrict__ epair, const int* __restrict__ row_ptr,
    const float* __restrict__ bias, const float* __restrict__ gamma,
    const float* __restrict__ beta, const float* __restrict__ rmean,
    const float* __restrict__ rvar,
    unsigned short* __restrict__ ohi, unsigned short* __restrict__ olo,
    float* __restrict__ outf)
{
    constexpr int EPI = GROUPS;                 // edges per iteration
    constexpr int CHUNK = (EPI == 3) ? 60 : 64; // edges per chunk (pad-safe)
    constexpr int NA = G32 ? 2 : 8;             // floats per lane
    int wave = threadIdx.x >> 6;
    int lane = threadIdx.x & 63;
    int node = blockIdx.x * 4 + wave;
    if (node >= N_NODES) return;

    int start = row_ptr[node];
    int end = row_ptr[node + 1];
    int g = lane / LPG;
    if (GROUPS == 3 && g > 2) g = 2;            // lanes 60-63: duplicate work, discarded
    int fl = lane - (lane / LPG) * LPG;

    float acc[NA];
#pragma unroll
    for (int v = 0; v < NA; v++) acc[v] = 0.f;

    for (int cs = start; cs < end; cs += CHUNK) {
        int cnt = min(CHUNK, end - cs);
        int sv = 0, wv = 0;
        {
            int e = cs + lane;
            if (lane < CHUNK && e < end) { uint2 p = epair[e]; sv = (int)p.x; wv = (int)p.y; }
        }
        int nbatch = (cnt + 4 * EPI - 1) / (4 * EPI);
        for (int b = 0; b < nbatch; b++) {
            int base = b * 4 * EPI;
            int ss[4], ws[4];
#pragma unroll
            for (int k = 0; k < 4; k++) {
                ss[k] = sel_bcast<EPI>(sv, base + k * EPI, g);
                ws[k] = sel_bcast<EPI>(wv, base + k * EPI, g);
            }
            if constexpr (G32) {
                float2 u[4];
#pragma unroll
                for (int k = 0; k < 4; k++)
                    u[k] = *reinterpret_cast<const float2*>(hf + (size_t)ss[k] * F + fl * 2);
#pragma unroll
                for (int k = 0; k < 4; k++) {
                    float ww = __int_as_float(ws[k]);
                    acc[0] += ww * u[k].x; acc[1] += ww * u[k].y;
                }
            } else {
                uint4 u[4];
#pragma unroll
                for (int k = 0; k < 4; k++)
                    u[k] = *reinterpret_cast<const uint4*>(hbf + (size_t)ss[k] * F + fl * 8);
#pragma unroll
                for (int k = 0; k < 4; k++) {
                    float ww = __int_as_float(ws[k]);
                    acc[0] += ww * bflo(u[k].x); acc[1] += ww * bfhi(u[k].x);
                    acc[2] += ww * bflo(u[k].y); acc[3] += ww * bfhi(u[k].y);
                    acc[4] += ww * bflo(u[k].z); acc[5] += ww * bfhi(u[k].z);
                    acc[6] += ww * bflo(u[k].w); acc[7] += ww * bfhi(u[k].w);
                }
            }
        }
    }

    // combine groups onto group 0
    float tot[NA];
    if constexpr (GROUPS == 2) {
#pragma unroll
        for (int v = 0; v < NA; v++) tot[v] = acc[v] + __shfl_xor(acc[v], 32);
    } else if constexpr (GROUPS == 4) {
#pragma unroll
        for (int v = 0; v < NA; v++) {
            float t = acc[v] + __shfl_xor(acc[v], 32);
            tot[v] = t + __shfl_xor(t, 16);
        }
    } else {  // GROUPS == 3 (LPG=20; lanes 60-63 discarded)
#pragma unroll
        for (int v = 0; v < NA; v++)
            tot[v] = acc[v] + __shfl(acc[v], lane + 20) + __shfl(acc[v], lane + 40);
    }

    if (lane >= LPG) return;
    float vals[NA];
#pragma unroll
    for (int v = 0; v < NA; v++) {
        int f = fl * NA + v;
        float val = tot[v] + bias[f];
        if constexpr (ACT) {
            float rs = rsqrtf(rvar[f] + BN_EPS);
            val = tanhf((val - rmean[f]) * rs * gamma[f] + beta[f]);
        }
        vals[v] = val;
    }
    if constexpr (OSPLIT) {
        unsigned hw[4], lw[4];
#pragma unroll
        for (int q = 0; q < 4; q++) {
            float v0 = vals[2 * q], v1 = vals[2 * q + 1];
            unsigned short h0 = f2bf(v0), h1 = f2bf(v1);
            hw[q] = (unsigned)h0 | ((unsigned)h1 << 16);
            unsigned short l0 = f2bf(v0 - bf2f(h0)), l1 = f2bf(v1 - bf2f(h1));
            lw[q] = (unsigned)l0 | ((unsigned)l1 << 16);
        }
        *reinterpret_cast<uint4*>(ohi + (size_t)node * F + fl * 8) = make_uint4(hw[0], hw[1], hw[2], hw[3]);
        *reinterpret_cast<uint4*>(olo + (size_t)node * F + fl * 8) = make_uint4(lw[0], lw[1], lw[2], lw[3]);
    } else {
        *reinterpret_cast<float2*>(outf + (size_t)node * F + fl * 2) = make_float2(vals[0], vals[1]);
    }
}

// ---------------------------------------------------------------------------

static inline size_t align256(size_t x) { return (x + 255) & ~(size_t)255; }

extern "C" void kernel_launch(void* const* d_in, const int* in_sizes, int n_in,
                              void* d_out, int out_size, void* d_ws, size_t ws_size,
                              hipStream_t stream) {
    const float* x   = (const float*)d_in[0];
    const int* ei    = (const int*)d_in[1];
    const float* w1  = (const float*)d_in[2];
    const float* as1 = (const float*)d_in[3];
    const float* ad1 = (const float*)d_in[4];
    const float* b1  = (const float*)d_in[5];
    const float* g1  = (const float*)d_in[6];
    const float* be1 = (const float*)d_in[7];
    const float* rm1 = (const float*)d_in[8];
    const float* rv1 = (const float*)d_in[9];
    const float* w2  = (const float*)d_in[10];
    const float* as2 = (const float*)d_in[11];
    const float* ad2 = (const float*)d_in[12];
    const float* b2  = (const float*)d_in[13];
    const float* g2  = (const float*)d_in[14];
    const float* be2 = (const float*)d_in[15];
    const float* rm2 = (const float*)d_in[16];
    const float* rv2 = (const float*)d_in[17];
    const float* w3  = (const float*)d_in[18];
    const float* as3 = (const float*)d_in[19];
    const float* ad3 = (const float*)d_in[20];
    const float* b3  = (const float*)d_in[21];
    float* out = (float*)d_out;

    const size_t P128 = align256((size_t)N_NODES * 128 * 2);
    const size_t P256 = align256((size_t)N_NODES * 256 * 2);

    char* p = (char*)d_ws;
    char* regA = p; p += P256;   // xhi|xlo -> o1hi|o1lo -> o2hi
    char* regB = p; p += P256;   // h1hi -> h2hi -> h3f
    char* regC = p; p += P256;   // o2lo
    unsigned short* xhi  = (unsigned short*)regA;
    unsigned short* xlo  = (unsigned short*)(regA + P128);
    unsigned short* o1hi = xhi;
    unsigned short* o1lo = xlo;
    unsigned short* o2hi = (unsigned short*)regA;
    unsigned short* h1hi = (unsigned short*)regB;
    unsigned short* h2hi = (unsigned short*)regB;
    float*          h3f  = (float*)regB;
    unsigned short* o2lo = (unsigned short*)regC;

    float* asrc = (float*)p;  p += align256((size_t)N_NODES * 4);
    float* adst = (float*)p;  p += align256((size_t)N_NODES * 4);
    int* counts    = (int*)p; p += align256((size_t)N_NODES * 4);
    int* row_ptr   = (int*)p; p += align256((size_t)(N_NODES + 1) * 4);
    int* write_pos = (int*)p; p += align256((size_t)N_NODES * 4);
    int* src_sorted = (int*)p; p += align256((size_t)TOT_EDGES * 4);
    uint2* epair   = (uint2*)p; p += align256((size_t)TOT_EDGES * 8);
    int* partials  = (int*)p;  p += align256(512 * 4);
    unsigned short* w1th = (unsigned short*)p; p += align256(128 * 128 * 2);
    unsigned short* w1tl = (unsigned short*)p; p += align256(128 * 128 * 2);
    unsigned short* w2th = (unsigned short*)p; p += align256(256 * 128 * 2);
    unsigned short* w2tl = (unsigned short*)p; p += align256(256 * 128 * 2);
    unsigned short* w3th = (unsigned short*)p; p += align256(48 * 256 * 2);
    unsigned short* w3tl = (unsigned short*)p; p += align256(48 * 256 * 2);
    unsigned short* ab1h = (unsigned short*)p; p += align256(16 * 128 * 2);
    unsigned short* ab1l = (unsigned short*)p; p += align256(16 * 128 * 2);
    unsigned short* ab2h = (unsigned short*)p; p += align256(16 * 128 * 2);
    unsigned short* ab2l = (unsigned short*)p; p += align256(16 * 128 * 2);
    unsigned short* ab3h = (unsigned short*)p; p += align256(16 * 256 * 2);
    unsigned short* ab3l = (unsigned short*)p; p += align256(16 * 256 * 2);

    const int NB = (N_NODES + 255) / 256;

    xconv<<<4096, 256, 0, stream>>>(x, xhi, xlo, N_NODES * 128);
    wconv<<<(128 * 128 + 255) / 256, 256, 0, stream>>>(w1, w1th, w1tl, 128, 128, 128);
    wconv<<<(256 * 128 + 255) / 256, 256, 0, stream>>>(w2, w2th, w2tl, 128, 256, 256);
    wconv<<<(48 * 256 + 255) / 256, 256, 0, stream>>>(w3, w3th, w3tl, 256, 40, 48);
    wav_kernel<<<(16 * 128 + 255) / 256, 256, 0, stream>>>(w1, as1, ad1, 128, 128, ab1h, ab1l);
    wav_kernel<<<(16 * 128 + 255) / 256, 256, 0, stream>>>(w2, as2, ad2, 128, 256, ab2h, ab2l);
    wav_kernel<<<(16 * 256 + 255) / 256, 256, 0, stream>>>(w3, as3, ad3, 256, 40, ab3h, ab3l);

    hipMemsetAsync(counts, 0, (size_t)N_NODES * 4, stream);
    count_kernel<<<4096, 256, 0, stream>>>(ei, counts);
    scan_partial<<<NB, 256, 0, stream>>>(counts, partials);
    scan_partials_kernel<<<1, 512, 0, stream>>>(partials, NB);
    scan_final<<<NB, 256, 0, stream>>>(counts, partials, row_ptr, write_pos);
    scatter_kernel<<<4096, 256, 0, stream>>>(ei, write_pos, src_sorted);

    const int NWB = (N_NODES + 3) / 4;
    const int G64 = (N_NODES + 63) / 64;
    const int G256 = (N_NODES + 255) / 256;

    // --- Layer 1 ---
    mfma_gemm<128, 2, 1, 4, 128, false><<<G64, 256, 0, stream>>>(
        xhi, xlo, w1th, w1tl, ab1h, ab1l, h1hi, nullptr, asrc, adst, N_NODES);
    node_alpha<<<NWB, 256, 0, stream>>>(asrc, adst, row_ptr, src_sorted, epair);
    gat_agg5<128, 4, 16, false, true, true><<<NWB, 256, 0, stream>>>(
        h1hi, nullptr, epair, row_ptr, b1, g1, be1, rm1, rv1, o1hi, o1lo, nullptr);

    // --- Layer 2 ---
    mfma_gemm<128, 4, 1, 4, 256, false><<<G64, 256, 0, stream>>>(
        o1hi, o1lo, w2th, w2tl, ab2h, ab2l, h2hi, nullptr, asrc, adst, N_NODES);
    node_alpha<<<NWB, 256, 0, stream>>>(asrc, adst, row_ptr, src_sorted, epair);
    gat_agg5<256, 2, 32, false, true, true><<<NWB, 256, 0, stream>>>(
        h2hi, nullptr, epair, row_ptr, b2, g2, be2, rm2, rv2, o2hi, o2lo, nullptr);

    // --- Layer 3 ---
    mfma_gemm<256, 3, 4, 1, 40, true><<<G256, 256, 0, stream>>>(
        o2hi, o2lo, w3th, w3tl, ab3h, ab3l, nullptr, h3f, asrc, adst, N_NODES);
    node_alpha<<<NWB, 256, 0, stream>>>(asrc, adst, row_ptr, src_sorted, epair);
    gat_agg5<40, 3, 20, true, false, false><<<NWB, 256, 0, stream>>>(
        nullptr, h3f, epair, row_ptr, b3, b3, b3, b3, b3, nullptr, nullptr, out);
}

// Round 7
// 947.312 us; speedup vs baseline: 1.1822x; 1.1607x over previous
//
#include <hip/hip_runtime.h>
#include <hip/hip_bf16.h>
#include <cstddef>

#define N_NODES 100000
#define E_EDGES 1600000
#define TOT_EDGES (E_EDGES + N_NODES)
#define NEG_SLOPE 0.2f
#define BN_EPS 1e-5f

typedef __attribute__((ext_vector_type(8))) short short8;
typedef __attribute__((ext_vector_type(4))) float f32x4;

__device__ __forceinline__ unsigned short f2bf(float f) {
    union { float f; unsigned u; } c; c.f = f;
    unsigned u = c.u;
    u += 0x7fffu + ((u >> 16) & 1u);
    return (unsigned short)(u >> 16);
}
__device__ __forceinline__ float bf2f(unsigned short h) {
    union { unsigned u; float f; } c; c.u = ((unsigned)h) << 16;
    return c.f;
}
__device__ __forceinline__ float bflo(unsigned u) {
    union { unsigned u; float f; } c; c.u = u << 16; return c.f;
}
__device__ __forceinline__ float bfhi(unsigned u) {
    union { unsigned u; float f; } c; c.u = u & 0xffff0000u; return c.f;
}
__device__ __forceinline__ float lrelu(float t) {
    return (t > 0.f) ? t : NEG_SLOPE * t;
}

// ---------------------------------------------------------------------------
// CSR build
// ---------------------------------------------------------------------------

__global__ __launch_bounds__(256) void count_kernel(const int* __restrict__ ei,
                                                    int* __restrict__ counts) {
    int idx = blockIdx.x * blockDim.x + threadIdx.x;
    int stride = gridDim.x * blockDim.x;
    for (int e = idx; e < TOT_EDGES; e += stride) {
        int d = (e < E_EDGES) ? ei[E_EDGES + e] : (e - E_EDGES);
        atomicAdd(&counts[d], 1);
    }
}

__global__ __launch_bounds__(256) void scan_partial(const int* __restrict__ counts,
                                                    int* __restrict__ partials) {
    __shared__ int s[256];
    int t = threadIdx.x;
    int i = blockIdx.x * 256 + t;
    s[t] = (i < N_NODES) ? counts[i] : 0;
    __syncthreads();
    for (int off = 128; off; off >>= 1) {
        if (t < off) s[t] += s[t + off];
        __syncthreads();
    }
    if (t == 0) partials[blockIdx.x] = s[0];
}

__global__ __launch_bounds__(512) void scan_partials_kernel(int* __restrict__ partials, int nb) {
    __shared__ int s[512];
    int t = threadIdx.x;
    int v = (t < nb) ? partials[t] : 0;
    s[t] = v;
    __syncthreads();
    for (int off = 1; off < 512; off <<= 1) {
        int y = (t >= off) ? s[t - off] : 0;
        __syncthreads();
        s[t] += y;
        __syncthreads();
    }
    if (t < nb) partials[t] = s[t] - v;
}

__global__ __launch_bounds__(256) void scan_final(const int* __restrict__ counts,
                                                  const int* __restrict__ partials,
                                                  int* __restrict__ row_ptr,
                                                  int* __restrict__ write_pos) {
    __shared__ int s[256];
    int t = threadIdx.x;
    int i = blockIdx.x * 256 + t;
    int v = (i < N_NODES) ? counts[i] : 0;
    s[t] = v;
    __syncthreads();
    for (int off = 1; off < 256; off <<= 1) {
        int y = (t >= off) ? s[t - off] : 0;
        __syncthreads();
        s[t] += y;
        __syncthreads();
    }
    int excl = s[t] - v;
    int rp = partials[blockIdx.x] + excl;
    if (i <= N_NODES) row_ptr[i] = rp;
    if (i < N_NODES) write_pos[i] = rp;
}

__global__ __launch_bounds__(256) void scatter_kernel(const int* __restrict__ ei,
                                                      int* __restrict__ write_pos,
                                                      int* __restrict__ src_sorted) {
    int idx = blockIdx.x * blockDim.x + threadIdx.x;
    int stride = gridDim.x * blockDim.x;
    for (int e = idx; e < TOT_EDGES; e += stride) {
        int srcv, d;
        if (e < E_EDGES) { srcv = ei[e]; d = ei[E_EDGES + e]; }
        else             { srcv = e - E_EDGES; d = srcv; }
        int p = atomicAdd(&write_pos[d], 1);
        src_sorted[p] = srcv;
    }
}

// ---------------------------------------------------------------------------
// Conversions
// ---------------------------------------------------------------------------

__global__ __launch_bounds__(256) void xconv(const float* __restrict__ x,
                                             unsigned short* __restrict__ hi,
                                             unsigned short* __restrict__ lo, int n) {
    int idx = blockIdx.x * blockDim.x + threadIdx.x;
    int stride = gridDim.x * blockDim.x;
    for (int i = idx; i < n; i += stride) {
        float v = x[i];
        unsigned short h = f2bf(v);
        hi[i] = h;
        lo[i] = f2bf(v - bf2f(h));
    }
}

// W [K][Nn] fp32 -> BT [Np][K] bf16 hi/lo (rows n >= Nn zero-padded)
__global__ __launch_bounds__(256) void wconv(const float* __restrict__ W,
                                             unsigned short* __restrict__ bth,
                                             unsigned short* __restrict__ btl,
                                             int K, int Nn, int Np) {
    int idx = blockIdx.x * blockDim.x + threadIdx.x;
    int total = Np * K;
    if (idx >= total) return;
    int n = idx / K, k = idx % K;
    float v = (n < Nn) ? W[k * Nn + n] : 0.f;
    unsigned short h = f2bf(v);
    bth[idx] = h;
    btl[idx] = f2bf(v - bf2f(h));
}

// alpha B-tile: rows 0/1 = split-bf16 of (W @ a_s) / (W @ a_d), rows 2..15 zero.
__global__ __launch_bounds__(256) void wav_kernel(const float* __restrict__ W,
                                                  const float* __restrict__ a_s,
                                                  const float* __restrict__ a_d,
                                                  int K, int Nn,
                                                  unsigned short* __restrict__ abh,
                                                  unsigned short* __restrict__ abl) {
    int idx = blockIdx.x * 256 + threadIdx.x;
    if (idx >= 16 * K) return;
    int r = idx / K, k = idx - r * K;
    float v = 0.f;
    if (r < 2) {
        const float* a = r ? a_d : a_s;
        const float* wr = W + (size_t)k * Nn;
        for (int n = 0; n < Nn; n++) v += wr[n] * a[n];
    }
    unsigned short h = f2bf(v);
    abh[idx] = h;
    abl[idx] = f2bf(v - bf2f(h));
}

// ---------------------------------------------------------------------------
// Split-bf16 MFMA GEMM (hi*hi + hi*lo + lo*hi) with fused alpha dots.
// ---------------------------------------------------------------------------
template<int K, int NTILES, int MWAVES, int NWAVES, int NACT, bool CFP32>
__global__ __launch_bounds__(256) void mfma_gemm(
    const unsigned short* __restrict__ Ahi, const unsigned short* __restrict__ Alo,
    const unsigned short* __restrict__ BThi, const unsigned short* __restrict__ BTlo,
    const unsigned short* __restrict__ ABh, const unsigned short* __restrict__ ABl,
    unsigned short* __restrict__ Chi, float* __restrict__ Cf,
    float* __restrict__ asrc, float* __restrict__ adst, int M)
{
    int lane = threadIdx.x & 63;
    int wave = threadIdx.x >> 6;
    int quad = lane >> 4;
    int l16  = lane & 15;
    long mbase = (long)blockIdx.x * (64 * MWAVES) + (long)(wave / NWAVES) * 64;
    int n0 = (wave % NWAVES) * (NTILES * 16);
    bool aw = (wave % NWAVES) == 0;

    const unsigned short* ah[4]; const unsigned short* al[4];
#pragma unroll
    for (int i = 0; i < 4; i++) {
        long r = mbase + i * 16 + l16;
        if (r > M - 1) r = M - 1;
        ah[i] = Ahi + r * K; al[i] = Alo + r * K;
    }
    const unsigned short* bh[NTILES]; const unsigned short* bl[NTILES];
#pragma unroll
    for (int j = 0; j < NTILES; j++) {
        long n = n0 + j * 16 + l16;
        bh[j] = BThi + n * K; bl[j] = BTlo + n * K;
    }
    const unsigned short* bah = ABh + (size_t)l16 * K;
    const unsigned short* bal = ABl + (size_t)l16 * K;
    const int ko = quad * 8;

    f32x4 acc[4][NTILES];
    f32x4 acca[4];
#pragma unroll
    for (int i = 0; i < 4; i++) {
        acca[i] = (f32x4){0.f, 0.f, 0.f, 0.f};
#pragma unroll
        for (int j = 0; j < NTILES; j++)
            acc[i][j] = (f32x4){0.f, 0.f, 0.f, 0.f};
    }

    for (int k0 = 0; k0 < K; k0 += 32) {
        short8 vah[4], vall[4], vbh[NTILES], vbl[NTILES];
#pragma unroll
        for (int i = 0; i < 4; i++) {
            vah[i]  = *(const short8*)(ah[i] + k0 + ko);
            vall[i] = *(const short8*)(al[i] + k0 + ko);
        }
#pragma unroll
        for (int j = 0; j < NTILES; j++) {
            vbh[j] = *(const short8*)(bh[j] + k0 + ko);
            vbl[j] = *(const short8*)(bl[j] + k0 + ko);
        }
#pragma unroll
        for (int i = 0; i < 4; i++)
#pragma unroll
            for (int j = 0; j < NTILES; j++) {
                acc[i][j] = __builtin_amdgcn_mfma_f32_16x16x32_bf16(vah[i],  vbh[j], acc[i][j], 0, 0, 0);
                acc[i][j] = __builtin_amdgcn_mfma_f32_16x16x32_bf16(vah[i],  vbl[j], acc[i][j], 0, 0, 0);
                acc[i][j] = __builtin_amdgcn_mfma_f32_16x16x32_bf16(vall[i], vbh[j], acc[i][j], 0, 0, 0);
            }
        if (aw) {
            short8 vbah = *(const short8*)(bah + k0 + ko);
            short8 vbal = *(const short8*)(bal + k0 + ko);
#pragma unroll
            for (int i = 0; i < 4; i++) {
                acca[i] = __builtin_amdgcn_mfma_f32_16x16x32_bf16(vah[i],  vbah, acca[i], 0, 0, 0);
                acca[i] = __builtin_amdgcn_mfma_f32_16x16x32_bf16(vah[i],  vbal, acca[i], 0, 0, 0);
                acca[i] = __builtin_amdgcn_mfma_f32_16x16x32_bf16(vall[i], vbah, acca[i], 0, 0, 0);
            }
        }
    }

#pragma unroll
    for (int i = 0; i < 4; i++)
#pragma unroll
        for (int j = 0; j < NTILES; j++)
#pragma unroll
            for (int r = 0; r < 4; r++) {
                long row = mbase + i * 16 + quad * 4 + r;
                int col = n0 + j * 16 + l16;
                if (row < M && col < NACT) {
                    float v = acc[i][j][r];
                    if constexpr (CFP32) Cf[row * NACT + col] = v;
                    else                 Chi[row * NACT + col] = f2bf(v);
                }
            }
    if (aw) {
#pragma unroll
        for (int i = 0; i < 4; i++)
#pragma unroll
            for (int r = 0; r < 4; r++) {
                long row = mbase + i * 16 + quad * 4 + r;
                if (row < M) {
                    float v = acca[i][r];
                    if (l16 == 0) asrc[row] = v;
                    else if (l16 == 1) adst[row] = v;
                }
            }
    }
}

// ---------------------------------------------------------------------------
// node_alpha: per-node segment softmax -> packed {src, alpha} per edge
// ---------------------------------------------------------------------------
__global__ __launch_bounds__(256) void node_alpha(
    const float* __restrict__ asrc, const float* __restrict__ adst,
    const int* __restrict__ row_ptr, const int* __restrict__ src_sorted,
    uint2* __restrict__ epair)
{
    int wave = threadIdx.x >> 6;
    int lane = threadIdx.x & 63;
    int node = blockIdx.x * 4 + wave;
    if (node >= N_NODES) return;
    int start = row_ptr[node];
    int end = row_ptr[node + 1];
    float ad = adst[node];

    int e0 = start + lane;
    int s_c = 0; float l_c = -1e30f;
    if (e0 < end) {
        s_c = src_sorted[e0];
        l_c = lrelu(asrc[s_c] + ad);
    }
    float m = l_c;
    for (int e = e0 + 64; e < end; e += 64) {
        int s = src_sorted[e];
        m = fmaxf(m, lrelu(asrc[s] + ad));
    }
#pragma unroll
    for (int off = 32; off; off >>= 1) m = fmaxf(m, __shfl_xor(m, off));

    float d = (e0 < end) ? __expf(l_c - m) : 0.f;
    for (int e = e0 + 64; e < end; e += 64) {
        int s = src_sorted[e];
        d += __expf(lrelu(asrc[s] + ad) - m);
    }
#pragma unroll
    for (int off = 32; off; off >>= 1) d += __shfl_xor(d, off);
    float inv = 1.0f / d;

    if (e0 < end)
        epair[e0] = make_uint2((unsigned)s_c, __float_as_uint(__expf(l_c - m) * inv));
    for (int e = e0 + 64; e < end; e += 64) {
        int s = src_sorted[e];
        float a = __expf(lrelu(asrc[s] + ad) - m) * inv;
        epair[e] = make_uint2((unsigned)s, __float_as_uint(a));
    }
}

// ---------------------------------------------------------------------------
// gat_agg6: wave per node, agg3's proven scalar-base structure with explicit
// two-phase unroll-8 batches: 8 readlane broadcasts (SGPR row bases) -> 8
// independent coalesced row loads -> 8x FMAs. 8 loads in flight per wave.
// ---------------------------------------------------------------------------
template<int F, bool G32, bool ACT, bool OSPLIT>
__global__ __launch_bounds__(256) void gat_agg6(
    const unsigned short* __restrict__ hbf, const float* __restrict__ hf,
    const uint2* __restrict__ epair, const int* __restrict__ row_ptr,
    const float* __restrict__ bias, const float* __restrict__ gamma,
    const float* __restrict__ beta, const float* __restrict__ rmean,
    const float* __restrict__ rvar,
    unsigned short* __restrict__ ohi, unsigned short* __restrict__ olo,
    float* __restrict__ outf)
{
    constexpr int NA = G32 ? 1 : (F / 64);  // floats per lane
    int wave = threadIdx.x >> 6;
    int lane = threadIdx.x & 63;
    int node = blockIdx.x * 4 + wave;
    if (node >= N_NODES) return;

    int start = row_ptr[node];
    int end = row_ptr[node + 1];

    float acc[NA];
#pragma unroll
    for (int v = 0; v < NA; v++) acc[v] = 0.f;

    int sv = 0, wv = 0;
    {
        int e = start + lane;
        if (e < end) { uint2 p = epair[e]; sv = (int)p.x; wv = (int)p.y; }
    }

    for (int cs = start; cs < end; cs += 64) {
        int cnt = min(64, end - cs);
        // prefetch next chunk's {src, alpha}
        int nsv = 0, nwv = 0;
        int en = cs + 64 + lane;
        if (en < end) { uint2 p = epair[en]; nsv = (int)p.x; nwv = (int)p.y; }

        int j = 0;
        for (; j + 8 <= cnt; j += 8) {
            int ss[8], wb[8];
#pragma unroll
            for (int k = 0; k < 8; k++) {
                ss[k] = __builtin_amdgcn_readlane(sv, j + k);
                wb[k] = __builtin_amdgcn_readlane(wv, j + k);
            }
            if constexpr (G32) {
                float u[8];
#pragma unroll
                for (int k = 0; k < 8; k++)
                    u[k] = hf[(size_t)ss[k] * F + lane];
#pragma unroll
                for (int k = 0; k < 8; k++)
                    acc[0] += __int_as_float(wb[k]) * u[k];
            } else if constexpr (F == 256) {
                uint2 u[8];
#pragma unroll
                for (int k = 0; k < 8; k++)
                    u[k] = *reinterpret_cast<const uint2*>(hbf + (size_t)ss[k] * F + lane * 4);
#pragma unroll
                for (int k = 0; k < 8; k++) {
                    float ww = __int_as_float(wb[k]);
                    acc[0] += ww * bflo(u[k].x); acc[1] += ww * bfhi(u[k].x);
                    acc[2] += ww * bflo(u[k].y); acc[3] += ww * bfhi(u[k].y);
                }
            } else {  // F == 128
                unsigned u[8];
#pragma unroll
                for (int k = 0; k < 8; k++)
                    u[k] = *reinterpret_cast<const unsigned*>(hbf + (size_t)ss[k] * F + lane * 2);
#pragma unroll
                for (int k = 0; k < 8; k++) {
                    float ww = __int_as_float(wb[k]);
                    acc[0] += ww * bflo(u[k]); acc[1] += ww * bfhi(u[k]);
                }
            }
        }
        for (; j < cnt; j++) {
            int ss = __builtin_amdgcn_readlane(sv, j);
            int wb = __builtin_amdgcn_readlane(wv, j);
            float ww = __int_as_float(wb);
            if constexpr (G32) {
                acc[0] += ww * hf[(size_t)ss * F + lane];
            } else if constexpr (F == 256) {
                uint2 u = *reinterpret_cast<const uint2*>(hbf + (size_t)ss * F + lane * 4);
                acc[0] += ww * bflo(u.x); acc[1] += ww * bfhi(u.x);
                acc[2] += ww * bflo(u.y); acc[3] += ww * bfhi(u.y);
            } else {
                unsigned u = *reinterpret_cast<const unsigned*>(hbf + (size_t)ss * F + lane * 2);
                acc[0] += ww * bflo(u); acc[1] += ww * bfhi(u);
            }
        }
        sv = nsv; wv = nwv;
    }

    if (G32 && lane >= F) return;
#pragma unroll
    for (int v = 0; v < NA; v++) {
        int f = G32 ? lane : lane * NA + v;
        float val = acc[v] + bias[f];
        if constexpr (ACT) {
            float rs = rsqrtf(rvar[f] + BN_EPS);
            val = tanhf((val - rmean[f]) * rs * gamma[f] + beta[f]);
        }
        size_t idx = (size_t)node * F + f;
        if constexpr (OSPLIT) {
            unsigned short h = f2bf(val);
            ohi[idx] = h;
            olo[idx] = f2bf(val - bf2f(h));
        } else {
            outf[idx] = val;
        }
    }
}

// ---------------------------------------------------------------------------

static inline size_t align256(size_t x) { return (x + 255) & ~(size_t)255; }

extern "C" void kernel_launch(void* const* d_in, const int* in_sizes, int n_in,
                              void* d_out, int out_size, void* d_ws, size_t ws_size,
                              hipStream_t stream) {
    const float* x   = (const float*)d_in[0];
    const int* ei    = (const int*)d_in[1];
    const float* w1  = (const float*)d_in[2];
    const float* as1 = (const float*)d_in[3];
    const float* ad1 = (const float*)d_in[4];
    const float* b1  = (const float*)d_in[5];
    const float* g1  = (const float*)d_in[6];
    const float* be1 = (const float*)d_in[7];
    const float* rm1 = (const float*)d_in[8];
    const float* rv1 = (const float*)d_in[9];
    const float* w2  = (const float*)d_in[10];
    const float* as2 = (const float*)d_in[11];
    const float* ad2 = (const float*)d_in[12];
    const float* b2  = (const float*)d_in[13];
    const float* g2  = (const float*)d_in[14];
    const float* be2 = (const float*)d_in[15];
    const float* rm2 = (const float*)d_in[16];
    const float* rv2 = (const float*)d_in[17];
    const float* w3  = (const float*)d_in[18];
    const float* as3 = (const float*)d_in[19];
    const float* ad3 = (const float*)d_in[20];
    const float* b3  = (const float*)d_in[21];
    float* out = (float*)d_out;

    const size_t P128 = align256((size_t)N_NODES * 128 * 2);
    const size_t P256 = align256((size_t)N_NODES * 256 * 2);

    char* p = (char*)d_ws;
    char* regA = p; p += P256;   // xhi|xlo -> o1hi|o1lo -> o2hi
    char* regB = p; p += P256;   // h1hi -> h2hi -> h3f
    char* regC = p; p += P256;   // o2lo
    unsigned short* xhi  = (unsigned short*)regA;
    unsigned short* xlo  = (unsigned short*)(regA + P128);
    unsigned short* o1hi = xhi;
    unsigned short* o1lo = xlo;
    unsigned short* o2hi = (unsigned short*)regA;
    unsigned short* h1hi = (unsigned short*)regB;
    unsigned short* h2hi = (unsigned short*)regB;
    float*          h3f  = (float*)regB;
    unsigned short* o2lo = (unsigned short*)regC;

    float* asrc = (float*)p;  p += align256((size_t)N_NODES * 4);
    float* adst = (float*)p;  p += align256((size_t)N_NODES * 4);
    int* counts    = (int*)p; p += align256((size_t)N_NODES * 4);
    int* row_ptr   = (int*)p; p += align256((size_t)(N_NODES + 1) * 4);
    int* write_pos = (int*)p; p += align256((size_t)N_NODES * 4);
    int* src_sorted = (int*)p; p += align256((size_t)TOT_EDGES * 4);
    uint2* epair   = (uint2*)p; p += align256((size_t)TOT_EDGES * 8);
    int* partials  = (int*)p;  p += align256(512 * 4);
    unsigned short* w1th = (unsigned short*)p; p += align256(128 * 128 * 2);
    unsigned short* w1tl = (unsigned short*)p; p += align256(128 * 128 * 2);
    unsigned short* w2th = (unsigned short*)p; p += align256(256 * 128 * 2);
    unsigned short* w2tl = (unsigned short*)p; p += align256(256 * 128 * 2);
    unsigned short* w3th = (unsigned short*)p; p += align256(48 * 256 * 2);
    unsigned short* w3tl = (unsigned short*)p; p += align256(48 * 256 * 2);
    unsigned short* ab1h = (unsigned short*)p; p += align256(16 * 128 * 2);
    unsigned short* ab1l = (unsigned short*)p; p += align256(16 * 128 * 2);
    unsigned short* ab2h = (unsigned short*)p; p += align256(16 * 128 * 2);
    unsigned short* ab2l = (unsigned short*)p; p += align256(16 * 128 * 2);
    unsigned short* ab3h = (unsigned short*)p; p += align256(16 * 256 * 2);
    unsigned short* ab3l = (unsigned short*)p; p += align256(16 * 256 * 2);

    const int NB = (N_NODES + 255) / 256;

    xconv<<<4096, 256, 0, stream>>>(x, xhi, xlo, N_NODES * 128);
    wconv<<<(128 * 128 + 255) / 256, 256, 0, stream>>>(w1, w1th, w1tl, 128, 128, 128);
    wconv<<<(256 * 128 + 255) / 256, 256, 0, stream>>>(w2, w2th, w2tl, 128, 256, 256);
    wconv<<<(48 * 256 + 255) / 256, 256, 0, stream>>>(w3, w3th, w3tl, 256, 40, 48);
    wav_kernel<<<(16 * 128 + 255) / 256, 256, 0, stream>>>(w1, as1, ad1, 128, 128, ab1h, ab1l);
    wav_kernel<<<(16 * 128 + 255) / 256, 256, 0, stream>>>(w2, as2, ad2, 128, 256, ab2h, ab2l);
    wav_kernel<<<(16 * 256 + 255) / 256, 256, 0, stream>>>(w3, as3, ad3, 256, 40, ab3h, ab3l);

    hipMemsetAsync(counts, 0, (size_t)N_NODES * 4, stream);
    count_kernel<<<4096, 256, 0, stream>>>(ei, counts);
    scan_partial<<<NB, 256, 0, stream>>>(counts, partials);
    scan_partials_kernel<<<1, 512, 0, stream>>>(partials, NB);
    scan_final<<<NB, 256, 0, stream>>>(counts, partials, row_ptr, write_pos);
    scatter_kernel<<<4096, 256, 0, stream>>>(ei, write_pos, src_sorted);

    const int NWB = (N_NODES + 3) / 4;
    const int G64 = (N_NODES + 63) / 64;
    const int G256 = (N_NODES + 255) / 256;

    // --- Layer 1 ---
    mfma_gemm<128, 2, 1, 4, 128, false><<<G64, 256, 0, stream>>>(
        xhi, xlo, w1th, w1tl, ab1h, ab1l, h1hi, nullptr, asrc, adst, N_NODES);
    node_alpha<<<NWB, 256, 0, stream>>>(asrc, adst, row_ptr, src_sorted, epair);
    gat_agg6<128, false, true, true><<<NWB, 256, 0, stream>>>(
        h1hi, nullptr, epair, row_ptr, b1, g1, be1, rm1, rv1, o1hi, o1lo, nullptr);

    // --- Layer 2 ---
    mfma_gemm<128, 4, 1, 4, 256, false><<<G64, 256, 0, stream>>>(
        o1hi, o1lo, w2th, w2tl, ab2h, ab2l, h2hi, nullptr, asrc, adst, N_NODES);
    node_alpha<<<NWB, 256, 0, stream>>>(asrc, adst, row_ptr, src_sorted, epair);
    gat_agg6<256, false, true, true><<<NWB, 256, 0, stream>>>(
        h2hi, nullptr, epair, row_ptr, b2, g2, be2, rm2, rv2, o2hi, o2lo, nullptr);

    // --- Layer 3 ---
    mfma_gemm<256, 3, 4, 1, 40, true><<<G256, 256, 0, stream>>>(
        o2hi, o2lo, w3th, w3tl, ab3h, ab3l, nullptr, h3f, asrc, adst, N_NODES);
    node_alpha<<<NWB, 256, 0, stream>>>(asrc, adst, row_ptr, src_sorted, epair);
    gat_agg6<40, true, false, false><<<NWB, 256, 0, stream>>>(
        nullptr, h3f, epair, row_ptr, b3, b3, b3, b3, b3, nullptr, nullptr, out);
}

// Round 8
// 864.366 us; speedup vs baseline: 1.2957x; 1.0960x over previous
//
#include <hip/hip_runtime.h>
#include <hip/hip_bf16.h>
#include <cstddef>

#define N_NODES 100000
#define E_EDGES 1600000
#define TOT_EDGES (E_EDGES + N_NODES)
#define NEG_SLOPE 0.2f
#define BN_EPS 1e-5f

typedef __attribute__((ext_vector_type(8))) short short8;
typedef __attribute__((ext_vector_type(4))) float f32x4;

__device__ __forceinline__ unsigned short f2bf(float f) {
    union { float f; unsigned u; } c; c.f = f;
    unsigned u = c.u;
    u += 0x7fffu + ((u >> 16) & 1u);
    return (unsigned short)(u >> 16);
}
__device__ __forceinline__ float bf2f(unsigned short h) {
    union { unsigned u; float f; } c; c.u = ((unsigned)h) << 16;
    return c.f;
}
__device__ __forceinline__ float bflo(unsigned u) {
    union { unsigned u; float f; } c; c.u = u << 16; return c.f;
}
__device__ __forceinline__ float bfhi(unsigned u) {
    union { unsigned u; float f; } c; c.u = u & 0xffff0000u; return c.f;
}
__device__ __forceinline__ float lrelu(float t) {
    return (t > 0.f) ? t : NEG_SLOPE * t;
}

// ---------------------------------------------------------------------------
// CSR build
// ---------------------------------------------------------------------------

__global__ __launch_bounds__(256) void count_kernel(const int* __restrict__ ei,
                                                    int* __restrict__ counts) {
    int idx = blockIdx.x * blockDim.x + threadIdx.x;
    int stride = gridDim.x * blockDim.x;
    for (int e = idx; e < TOT_EDGES; e += stride) {
        int d = (e < E_EDGES) ? ei[E_EDGES + e] : (e - E_EDGES);
        atomicAdd(&counts[d], 1);
    }
}

__global__ __launch_bounds__(256) void scan_partial(const int* __restrict__ counts,
                                                    int* __restrict__ partials) {
    __shared__ int s[256];
    int t = threadIdx.x;
    int i = blockIdx.x * 256 + t;
    s[t] = (i < N_NODES) ? counts[i] : 0;
    __syncthreads();
    for (int off = 128; off; off >>= 1) {
        if (t < off) s[t] += s[t + off];
        __syncthreads();
    }
    if (t == 0) partials[blockIdx.x] = s[0];
}

__global__ __launch_bounds__(512) void scan_partials_kernel(int* __restrict__ partials, int nb) {
    __shared__ int s[512];
    int t = threadIdx.x;
    int v = (t < nb) ? partials[t] : 0;
    s[t] = v;
    __syncthreads();
    for (int off = 1; off < 512; off <<= 1) {
        int y = (t >= off) ? s[t - off] : 0;
        __syncthreads();
        s[t] += y;
        __syncthreads();
    }
    if (t < nb) partials[t] = s[t] - v;
}

__global__ __launch_bounds__(256) void scan_final(const int* __restrict__ counts,
                                                  const int* __restrict__ partials,
                                                  int* __restrict__ row_ptr,
                                                  int* __restrict__ write_pos) {
    __shared__ int s[256];
    int t = threadIdx.x;
    int i = blockIdx.x * 256 + t;
    int v = (i < N_NODES) ? counts[i] : 0;
    s[t] = v;
    __syncthreads();
    for (int off = 1; off < 256; off <<= 1) {
        int y = (t >= off) ? s[t - off] : 0;
        __syncthreads();
        s[t] += y;
        __syncthreads();
    }
    int excl = s[t] - v;
    int rp = partials[blockIdx.x] + excl;
    if (i <= N_NODES) row_ptr[i] = rp;
    if (i < N_NODES) write_pos[i] = rp;
}

__global__ __launch_bounds__(256) void scatter_kernel(const int* __restrict__ ei,
                                                      int* __restrict__ write_pos,
                                                      int* __restrict__ src_sorted) {
    int idx = blockIdx.x * blockDim.x + threadIdx.x;
    int stride = gridDim.x * blockDim.x;
    for (int e = idx; e < TOT_EDGES; e += stride) {
        int srcv, d;
        if (e < E_EDGES) { srcv = ei[e]; d = ei[E_EDGES + e]; }
        else             { srcv = e - E_EDGES; d = srcv; }
        int p = atomicAdd(&write_pos[d], 1);
        src_sorted[p] = srcv;
    }
}

// ---------------------------------------------------------------------------
// Conversions
// ---------------------------------------------------------------------------

__global__ __launch_bounds__(256) void xconv(const float* __restrict__ x,
                                             unsigned short* __restrict__ hi,
                                             unsigned short* __restrict__ lo, int n) {
    int idx = blockIdx.x * blockDim.x + threadIdx.x;
    int stride = gridDim.x * blockDim.x;
    for (int i = idx; i < n; i += stride) {
        float v = x[i];
        unsigned short h = f2bf(v);
        hi[i] = h;
        lo[i] = f2bf(v - bf2f(h));
    }
}

// W [K][Nn] fp32 -> BT [Np][K] bf16 hi/lo (rows n >= Nn zero-padded)
__global__ __launch_bounds__(256) void wconv(const float* __restrict__ W,
                                             unsigned short* __restrict__ bth,
                                             unsigned short* __restrict__ btl,
                                             int K, int Nn, int Np) {
    int idx = blockIdx.x * blockDim.x + threadIdx.x;
    int total = Np * K;
    if (idx >= total) return;
    int n = idx / K, k = idx % K;
    float v = (n < Nn) ? W[k * Nn + n] : 0.f;
    unsigned short h = f2bf(v);
    bth[idx] = h;
    btl[idx] = f2bf(v - bf2f(h));
}

// alpha B-tile: rows 0/1 = split-bf16 of (W @ a_s) / (W @ a_d), rows 2..15 zero.
__global__ __launch_bounds__(256) void wav_kernel(const float* __restrict__ W,
                                                  const float* __restrict__ a_s,
                                                  const float* __restrict__ a_d,
                                                  int K, int Nn,
                                                  unsigned short* __restrict__ abh,
                                                  unsigned short* __restrict__ abl) {
    int idx = blockIdx.x * 256 + threadIdx.x;
    if (idx >= 16 * K) return;
    int r = idx / K, k = idx - r * K;
    float v = 0.f;
    if (r < 2) {
        const float* a = r ? a_d : a_s;
        const float* wr = W + (size_t)k * Nn;
        for (int n = 0; n < Nn; n++) v += wr[n] * a[n];
    }
    unsigned short h = f2bf(v);
    abh[idx] = h;
    abl[idx] = f2bf(v - bf2f(h));
}

// ---------------------------------------------------------------------------
// Split-bf16 MFMA GEMM with fused alpha dots.
// ASPLIT=true: A has hi+lo planes (3 products). false: A hi only (2 products).
// ---------------------------------------------------------------------------
template<int K, int NTILES, int MWAVES, int NWAVES, int NACT, bool CFP32, bool ASPLIT>
__global__ __launch_bounds__(256) void mfma_gemm(
    const unsigned short* __restrict__ Ahi, const unsigned short* __restrict__ Alo,
    const unsigned short* __restrict__ BThi, const unsigned short* __restrict__ BTlo,
    const unsigned short* __restrict__ ABh, const unsigned short* __restrict__ ABl,
    unsigned short* __restrict__ Chi, float* __restrict__ Cf,
    float* __restrict__ asrc, float* __restrict__ adst, int M)
{
    int lane = threadIdx.x & 63;
    int wave = threadIdx.x >> 6;
    int quad = lane >> 4;
    int l16  = lane & 15;
    long mbase = (long)blockIdx.x * (64 * MWAVES) + (long)(wave / NWAVES) * 64;
    int n0 = (wave % NWAVES) * (NTILES * 16);
    bool aw = (wave % NWAVES) == 0;

    const unsigned short* ah[4]; const unsigned short* al[4];
#pragma unroll
    for (int i = 0; i < 4; i++) {
        long r = mbase + i * 16 + l16;
        if (r > M - 1) r = M - 1;
        ah[i] = Ahi + r * K;
        if constexpr (ASPLIT) al[i] = Alo + r * K;
    }
    const unsigned short* bh[NTILES]; const unsigned short* bl[NTILES];
#pragma unroll
    for (int j = 0; j < NTILES; j++) {
        long n = n0 + j * 16 + l16;
        bh[j] = BThi + n * K; bl[j] = BTlo + n * K;
    }
    const unsigned short* bah = ABh + (size_t)l16 * K;
    const unsigned short* bal = ABl + (size_t)l16 * K;
    const int ko = quad * 8;

    f32x4 acc[4][NTILES];
    f32x4 acca[4];
#pragma unroll
    for (int i = 0; i < 4; i++) {
        acca[i] = (f32x4){0.f, 0.f, 0.f, 0.f};
#pragma unroll
        for (int j = 0; j < NTILES; j++)
            acc[i][j] = (f32x4){0.f, 0.f, 0.f, 0.f};
    }

    for (int k0 = 0; k0 < K; k0 += 32) {
        short8 vah[4], vall[4], vbh[NTILES], vbl[NTILES];
#pragma unroll
        for (int i = 0; i < 4; i++) {
            vah[i] = *(const short8*)(ah[i] + k0 + ko);
            if constexpr (ASPLIT) vall[i] = *(const short8*)(al[i] + k0 + ko);
        }
#pragma unroll
        for (int j = 0; j < NTILES; j++) {
            vbh[j] = *(const short8*)(bh[j] + k0 + ko);
            vbl[j] = *(const short8*)(bl[j] + k0 + ko);
        }
#pragma unroll
        for (int i = 0; i < 4; i++)
#pragma unroll
            for (int j = 0; j < NTILES; j++) {
                acc[i][j] = __builtin_amdgcn_mfma_f32_16x16x32_bf16(vah[i], vbh[j], acc[i][j], 0, 0, 0);
                acc[i][j] = __builtin_amdgcn_mfma_f32_16x16x32_bf16(vah[i], vbl[j], acc[i][j], 0, 0, 0);
                if constexpr (ASPLIT)
                    acc[i][j] = __builtin_amdgcn_mfma_f32_16x16x32_bf16(vall[i], vbh[j], acc[i][j], 0, 0, 0);
            }
        if (aw) {
            short8 vbah = *(const short8*)(bah + k0 + ko);
            short8 vbal = *(const short8*)(bal + k0 + ko);
#pragma unroll
            for (int i = 0; i < 4; i++) {
                acca[i] = __builtin_amdgcn_mfma_f32_16x16x32_bf16(vah[i], vbah, acca[i], 0, 0, 0);
                acca[i] = __builtin_amdgcn_mfma_f32_16x16x32_bf16(vah[i], vbal, acca[i], 0, 0, 0);
                if constexpr (ASPLIT)
                    acca[i] = __builtin_amdgcn_mfma_f32_16x16x32_bf16(vall[i], vbah, acca[i], 0, 0, 0);
            }
        }
    }

#pragma unroll
    for (int i = 0; i < 4; i++)
#pragma unroll
        for (int j = 0; j < NTILES; j++)
#pragma unroll
            for (int r = 0; r < 4; r++) {
                long row = mbase + i * 16 + quad * 4 + r;
                int col = n0 + j * 16 + l16;
                if (row < M && col < NACT) {
                    float v = acc[i][j][r];
                    if constexpr (CFP32) Cf[row * NACT + col] = v;
                    else                 Chi[row * NACT + col] = f2bf(v);
                }
            }
    if (aw) {
#pragma unroll
        for (int i = 0; i < 4; i++)
#pragma unroll
            for (int r = 0; r < 4; r++) {
                long row = mbase + i * 16 + quad * 4 + r;
                if (row < M) {
                    float v = acca[i][r];
                    if (l16 == 0) asrc[row] = v;
                    else if (l16 == 1) adst[row] = v;
                }
            }
    }
}

// ---------------------------------------------------------------------------
// chunk_gather: the proven readlane scalar-base gather core (agg6), unroll-8.
// sv/wv hold {src, alpha-bits} for this chunk's edges in lanes 0..cnt-1.
// ---------------------------------------------------------------------------
template<int F, bool G32>
__device__ __forceinline__ void chunk_gather(
    const unsigned short* __restrict__ hbf, const float* __restrict__ hf,
    int sv, int wv, int cnt, int lane, float* acc)
{
    int j = 0;
    for (; j + 8 <= cnt; j += 8) {
        int ss[8], wb[8];
#pragma unroll
        for (int k = 0; k < 8; k++) {
            ss[k] = __builtin_amdgcn_readlane(sv, j + k);
            wb[k] = __builtin_amdgcn_readlane(wv, j + k);
        }
        if constexpr (G32) {
            float u[8];
#pragma unroll
            for (int k = 0; k < 8; k++)
                u[k] = hf[(size_t)ss[k] * F + lane];
#pragma unroll
            for (int k = 0; k < 8; k++)
                acc[0] += __int_as_float(wb[k]) * u[k];
        } else if constexpr (F == 256) {
            uint2 u[8];
#pragma unroll
            for (int k = 0; k < 8; k++)
                u[k] = *reinterpret_cast<const uint2*>(hbf + (size_t)ss[k] * F + lane * 4);
#pragma unroll
            for (int k = 0; k < 8; k++) {
                float ww = __int_as_float(wb[k]);
                acc[0] += ww * bflo(u[k].x); acc[1] += ww * bfhi(u[k].x);
                acc[2] += ww * bflo(u[k].y); acc[3] += ww * bfhi(u[k].y);
            }
        } else {  // F == 128
            unsigned u[8];
#pragma unroll
            for (int k = 0; k < 8; k++)
                u[k] = *reinterpret_cast<const unsigned*>(hbf + (size_t)ss[k] * F + lane * 2);
#pragma unroll
            for (int k = 0; k < 8; k++) {
                float ww = __int_as_float(wb[k]);
                acc[0] += ww * bflo(u[k]); acc[1] += ww * bfhi(u[k]);
            }
        }
    }
    for (; j < cnt; j++) {
        int ss = __builtin_amdgcn_readlane(sv, j);
        int wb = __builtin_amdgcn_readlane(wv, j);
        float ww = __int_as_float(wb);
        if constexpr (G32) {
            acc[0] += ww * hf[(size_t)ss * F + lane];
        } else if constexpr (F == 256) {
            uint2 u = *reinterpret_cast<const uint2*>(hbf + (size_t)ss * F + lane * 4);
            acc[0] += ww * bflo(u.x); acc[1] += ww * bfhi(u.x);
            acc[2] += ww * bflo(u.y); acc[3] += ww * bfhi(u.y);
        } else {
            unsigned u = *reinterpret_cast<const unsigned*>(hbf + (size_t)ss * F + lane * 2);
            acc[0] += ww * bflo(u); acc[1] += ww * bfhi(u);
        }
    }
}

// ---------------------------------------------------------------------------
// gat_agg7: FUSED segment-softmax + gather-aggregate. Wave per node.
// Fast path (deg <= 64): one random asrc gather per edge (asrc is 400 KB,
// L2-resident), softmax entirely in registers, then chunk_gather once.
// Rare deg > 64: online-softmax pass then per-chunk recompute.
// Epilogue: bias (+BN+tanh), write bf16-hi plane (OHI) or fp32.
// ---------------------------------------------------------------------------
template<int F, bool G32, bool ACT, bool OHI>
__global__ __launch_bounds__(256) void gat_agg7(
    const unsigned short* __restrict__ hbf, const float* __restrict__ hf,
    const float* __restrict__ asrc, const float* __restrict__ adst,
    const int* __restrict__ row_ptr, const int* __restrict__ src_sorted,
    const float* __restrict__ bias, const float* __restrict__ gamma,
    const float* __restrict__ beta, const float* __restrict__ rmean,
    const float* __restrict__ rvar,
    unsigned short* __restrict__ ohi, float* __restrict__ outf)
{
    constexpr int NA = G32 ? 1 : (F / 64);
    int wave = threadIdx.x >> 6;
    int lane = threadIdx.x & 63;
    int node = blockIdx.x * 4 + wave;
    if (node >= N_NODES) return;

    int start = row_ptr[node];
    int end = row_ptr[node + 1];
    int deg = end - start;
    float ad = adst[node];

    float acc[NA];
#pragma unroll
    for (int v = 0; v < NA; v++) acc[v] = 0.f;

    if (deg <= 64) {
        int e = start + lane;
        int s = 0; float l = -1e30f;
        if (e < end) { s = src_sorted[e]; l = lrelu(asrc[s] + ad); }
        float m = l;
#pragma unroll
        for (int off = 32; off; off >>= 1) m = fmaxf(m, __shfl_xor(m, off));
        float pr = (e < end) ? __expf(l - m) : 0.f;
        float d = pr;
#pragma unroll
        for (int off = 32; off; off >>= 1) d += __shfl_xor(d, off);
        int wv = __float_as_int(pr / d);
        chunk_gather<F, G32>(hbf, hf, s, wv, deg, lane, acc);
    } else {
        // online softmax over chunks
        float m = -1e30f, d = 0.f;
        for (int cs = start; cs < end; cs += 64) {
            int e = cs + lane;
            float l = -1e30f;
            if (e < end) { int s = src_sorted[e]; l = lrelu(asrc[s] + ad); }
            float cm = l;
#pragma unroll
            for (int off = 32; off; off >>= 1) cm = fmaxf(cm, __shfl_xor(cm, off));
            float nm = fmaxf(m, cm);
            float cp = (e < end) ? __expf(l - nm) : 0.f;
#pragma unroll
            for (int off = 32; off; off >>= 1) cp += __shfl_xor(cp, off);
            d = d * __expf(m - nm) + cp;
            m = nm;
        }
        float inv = 1.0f / d;
        for (int cs = start; cs < end; cs += 64) {
            int e = cs + lane;
            int s = 0, wv = 0;
            if (e < end) {
                s = src_sorted[e];
                float l = lrelu(asrc[s] + ad);
                wv = __float_as_int(__expf(l - m) * inv);
            }
            chunk_gather<F, G32>(hbf, hf, s, wv, min(64, end - cs), lane, acc);
        }
    }

    if (G32 && lane >= F) return;
    float vals[NA];
#pragma unroll
    for (int v = 0; v < NA; v++) {
        int f = G32 ? lane : lane * NA + v;
        float val = acc[v] + bias[f];
        if constexpr (ACT) {
            float rs = rsqrtf(rvar[f] + BN_EPS);
            val = tanhf((val - rmean[f]) * rs * gamma[f] + beta[f]);
        }
        vals[v] = val;
    }
    if constexpr (OHI) {
        if constexpr (NA == 4) {
            unsigned w0 = (unsigned)f2bf(vals[0]) | ((unsigned)f2bf(vals[1]) << 16);
            unsigned w1 = (unsigned)f2bf(vals[2]) | ((unsigned)f2bf(vals[3]) << 16);
            *reinterpret_cast<uint2*>(ohi + (size_t)node * F + lane * 4) = make_uint2(w0, w1);
        } else {  // NA == 2
            unsigned w0 = (unsigned)f2bf(vals[0]) | ((unsigned)f2bf(vals[1]) << 16);
            *reinterpret_cast<unsigned*>(ohi + (size_t)node * F + lane * 2) = w0;
        }
    } else {
        outf[(size_t)node * F + lane] = vals[0];
    }
}

// ---------------------------------------------------------------------------

static inline size_t align256(size_t x) { return (x + 255) & ~(size_t)255; }

extern "C" void kernel_launch(void* const* d_in, const int* in_sizes, int n_in,
                              void* d_out, int out_size, void* d_ws, size_t ws_size,
                              hipStream_t stream) {
    const float* x   = (const float*)d_in[0];
    const int* ei    = (const int*)d_in[1];
    const float* w1  = (const float*)d_in[2];
    const float* as1 = (const float*)d_in[3];
    const float* ad1 = (const float*)d_in[4];
    const float* b1  = (const float*)d_in[5];
    const float* g1  = (const float*)d_in[6];
    const float* be1 = (const float*)d_in[7];
    const float* rm1 = (const float*)d_in[8];
    const float* rv1 = (const float*)d_in[9];
    const float* w2  = (const float*)d_in[10];
    const float* as2 = (const float*)d_in[11];
    const float* ad2 = (const float*)d_in[12];
    const float* b2  = (const float*)d_in[13];
    const float* g2  = (const float*)d_in[14];
    const float* be2 = (const float*)d_in[15];
    const float* rm2 = (const float*)d_in[16];
    const float* rv2 = (const float*)d_in[17];
    const float* w3  = (const float*)d_in[18];
    const float* as3 = (const float*)d_in[19];
    const float* ad3 = (const float*)d_in[20];
    const float* b3  = (const float*)d_in[21];
    float* out = (float*)d_out;

    const size_t P128 = align256((size_t)N_NODES * 128 * 2);
    const size_t P256 = align256((size_t)N_NODES * 256 * 2);

    char* p = (char*)d_ws;
    // regA: xhi|xlo -> o1hi (over xhi) -> o2hi (full region)
    char* regA = p; p += P256;
    // regB: h1hi -> h2hi -> h3f
    char* regB = p; p += P256;
    unsigned short* xhi  = (unsigned short*)regA;
    unsigned short* xlo  = (unsigned short*)(regA + P128);
    unsigned short* o1hi = (unsigned short*)regA;   // xhi dead after GEMM-1
    unsigned short* o2hi = (unsigned short*)regA;   // o1hi dead after GEMM-2
    unsigned short* h1hi = (unsigned short*)regB;
    unsigned short* h2hi = (unsigned short*)regB;
    float*          h3f  = (float*)regB;

    float* asrc = (float*)p;  p += align256((size_t)N_NODES * 4);
    float* adst = (float*)p;  p += align256((size_t)N_NODES * 4);
    int* counts    = (int*)p; p += align256((size_t)N_NODES * 4);
    int* row_ptr   = (int*)p; p += align256((size_t)(N_NODES + 1) * 4);
    int* write_pos = (int*)p; p += align256((size_t)N_NODES * 4);
    int* src_sorted = (int*)p; p += align256((size_t)TOT_EDGES * 4);
    int* partials  = (int*)p;  p += align256(512 * 4);
    unsigned short* w1th = (unsigned short*)p; p += align256(128 * 128 * 2);
    unsigned short* w1tl = (unsigned short*)p; p += align256(128 * 128 * 2);
    unsigned short* w2th = (unsigned short*)p; p += align256(256 * 128 * 2);
    unsigned short* w2tl = (unsigned short*)p; p += align256(256 * 128 * 2);
    unsigned short* w3th = (unsigned short*)p; p += align256(48 * 256 * 2);
    unsigned short* w3tl = (unsigned short*)p; p += align256(48 * 256 * 2);
    unsigned short* ab1h = (unsigned short*)p; p += align256(16 * 128 * 2);
    unsigned short* ab1l = (unsigned short*)p; p += align256(16 * 128 * 2);
    unsigned short* ab2h = (unsigned short*)p; p += align256(16 * 128 * 2);
    unsigned short* ab2l = (unsigned short*)p; p += align256(16 * 128 * 2);
    unsigned short* ab3h = (unsigned short*)p; p += align256(16 * 256 * 2);
    unsigned short* ab3l = (unsigned short*)p; p += align256(16 * 256 * 2);

    const int NB = (N_NODES + 255) / 256;

    xconv<<<4096, 256, 0, stream>>>(x, xhi, xlo, N_NODES * 128);
    wconv<<<(128 * 128 + 255) / 256, 256, 0, stream>>>(w1, w1th, w1tl, 128, 128, 128);
    wconv<<<(256 * 128 + 255) / 256, 256, 0, stream>>>(w2, w2th, w2tl, 128, 256, 256);
    wconv<<<(48 * 256 + 255) / 256, 256, 0, stream>>>(w3, w3th, w3tl, 256, 40, 48);
    wav_kernel<<<(16 * 128 + 255) / 256, 256, 0, stream>>>(w1, as1, ad1, 128, 128, ab1h, ab1l);
    wav_kernel<<<(16 * 128 + 255) / 256, 256, 0, stream>>>(w2, as2, ad2, 128, 256, ab2h, ab2l);
    wav_kernel<<<(16 * 256 + 255) / 256, 256, 0, stream>>>(w3, as3, ad3, 256, 40, ab3h, ab3l);

    hipMemsetAsync(counts, 0, (size_t)N_NODES * 4, stream);
    count_kernel<<<4096, 256, 0, stream>>>(ei, counts);
    scan_partial<<<NB, 256, 0, stream>>>(counts, partials);
    scan_partials_kernel<<<1, 512, 0, stream>>>(partials, NB);
    scan_final<<<NB, 256, 0, stream>>>(counts, partials, row_ptr, write_pos);
    scatter_kernel<<<4096, 256, 0, stream>>>(ei, write_pos, src_sorted);

    const int NWB = (N_NODES + 3) / 4;
    const int G64 = (N_NODES + 63) / 64;
    const int G256 = (N_NODES + 255) / 256;

    // --- Layer 1: A = x (split, 3 products) ---
    mfma_gemm<128, 2, 1, 4, 128, false, true><<<G64, 256, 0, stream>>>(
        xhi, xlo, w1th, w1tl, ab1h, ab1l, h1hi, nullptr, asrc, adst, N_NODES);
    gat_agg7<128, false, true, true><<<NWB, 256, 0, stream>>>(
        h1hi, nullptr, asrc, adst, row_ptr, src_sorted,
        b1, g1, be1, rm1, rv1, o1hi, nullptr);

    // --- Layer 2: A = o1 (hi only, 2 products) ---
    mfma_gemm<128, 4, 1, 4, 256, false, false><<<G64, 256, 0, stream>>>(
        o1hi, nullptr, w2th, w2tl, ab2h, ab2l, h2hi, nullptr, asrc, adst, N_NODES);
    gat_agg7<256, false, true, true><<<NWB, 256, 0, stream>>>(
        h2hi, nullptr, asrc, adst, row_ptr, src_sorted,
        b2, g2, be2, rm2, rv2, o2hi, nullptr);

    // --- Layer 3: A = o2 (hi only), fp32 C ---
    mfma_gemm<256, 3, 4, 1, 40, true, false><<<G256, 256, 0, stream>>>(
        o2hi, nullptr, w3th, w3tl, ab3h, ab3l, nullptr, h3f, asrc, adst, N_NODES);
    gat_agg7<40, true, false, false><<<NWB, 256, 0, stream>>>(
        nullptr, h3f, asrc, adst, row_ptr, src_sorted,
        b3, b3, b3, b3, b3, nullptr, out);
}

// Round 9
// 724.136 us; speedup vs baseline: 1.5466x; 1.1937x over previous
//
#include <hip/hip_runtime.h>
#include <hip/hip_bf16.h>
#include <cstddef>

#define N_NODES 100000
#define E_EDGES 1600000
#define TOT_EDGES (E_EDGES + N_NODES)
#define NEG_SLOPE 0.2f
#define BN_EPS 1e-5f

typedef __attribute__((ext_vector_type(8))) short short8;
typedef __attribute__((ext_vector_type(4))) float f32x4;
typedef __attribute__((ext_vector_type(2))) float f32x2;

__device__ __forceinline__ unsigned short f2bf(float f) {
    union { float f; unsigned u; } c; c.f = f;
    unsigned u = c.u;
    u += 0x7fffu + ((u >> 16) & 1u);
    return (unsigned short)(u >> 16);
}
__device__ __forceinline__ float bf2f(unsigned short h) {
    union { unsigned u; float f; } c; c.u = ((unsigned)h) << 16;
    return c.f;
}
__device__ __forceinline__ float bflo(unsigned u) {
    union { unsigned u; float f; } c; c.u = u << 16; return c.f;
}
__device__ __forceinline__ float bfhi(unsigned u) {
    union { unsigned u; float f; } c; c.u = u & 0xffff0000u; return c.f;
}
__device__ __forceinline__ float lrelu(float t) {
    return (t > 0.f) ? t : NEG_SLOPE * t;
}

// ---------------------------------------------------------------------------
// CSR build
// ---------------------------------------------------------------------------

__global__ __launch_bounds__(256) void count_kernel(const int* __restrict__ ei,
                                                    int* __restrict__ counts) {
    int idx = blockIdx.x * blockDim.x + threadIdx.x;
    int stride = gridDim.x * blockDim.x;
    for (int e = idx; e < TOT_EDGES; e += stride) {
        int d = (e < E_EDGES) ? ei[E_EDGES + e] : (e - E_EDGES);
        atomicAdd(&counts[d], 1);
    }
}

__global__ __launch_bounds__(256) void scan_partial(const int* __restrict__ counts,
                                                    int* __restrict__ partials) {
    __shared__ int s[256];
    int t = threadIdx.x;
    int i = blockIdx.x * 256 + t;
    s[t] = (i < N_NODES) ? counts[i] : 0;
    __syncthreads();
    for (int off = 128; off; off >>= 1) {
        if (t < off) s[t] += s[t + off];
        __syncthreads();
    }
    if (t == 0) partials[blockIdx.x] = s[0];
}

__global__ __launch_bounds__(512) void scan_partials_kernel(int* __restrict__ partials, int nb) {
    __shared__ int s[512];
    int t = threadIdx.x;
    int v = (t < nb) ? partials[t] : 0;
    s[t] = v;
    __syncthreads();
    for (int off = 1; off < 512; off <<= 1) {
        int y = (t >= off) ? s[t - off] : 0;
        __syncthreads();
        s[t] += y;
        __syncthreads();
    }
    if (t < nb) partials[t] = s[t] - v;
}

__global__ __launch_bounds__(256) void scan_final(const int* __restrict__ counts,
                                                  const int* __restrict__ partials,
                                                  int* __restrict__ row_ptr,
                                                  int* __restrict__ write_pos) {
    __shared__ int s[256];
    int t = threadIdx.x;
    int i = blockIdx.x * 256 + t;
    int v = (i < N_NODES) ? counts[i] : 0;
    s[t] = v;
    __syncthreads();
    for (int off = 1; off < 256; off <<= 1) {
        int y = (t >= off) ? s[t - off] : 0;
        __syncthreads();
        s[t] += y;
        __syncthreads();
    }
    int excl = s[t] - v;
    int rp = partials[blockIdx.x] + excl;
    if (i <= N_NODES) row_ptr[i] = rp;
    if (i < N_NODES) write_pos[i] = rp;
}

__global__ __launch_bounds__(256) void scatter_kernel(const int* __restrict__ ei,
                                                      int* __restrict__ write_pos,
                                                      int* __restrict__ src_sorted) {
    int idx = blockIdx.x * blockDim.x + threadIdx.x;
    int stride = gridDim.x * blockDim.x;
    for (int e = idx; e < TOT_EDGES; e += stride) {
        int srcv, d;
        if (e < E_EDGES) { srcv = ei[e]; d = ei[E_EDGES + e]; }
        else             { srcv = e - E_EDGES; d = srcv; }
        int p = atomicAdd(&write_pos[d], 1);
        src_sorted[p] = srcv;
    }
}

// ---------------------------------------------------------------------------
// Conversions (fused)
// ---------------------------------------------------------------------------

__global__ __launch_bounds__(256) void xconv(const float* __restrict__ x,
                                             unsigned short* __restrict__ hi,
                                             unsigned short* __restrict__ lo, int n) {
    int idx = blockIdx.x * blockDim.x + threadIdx.x;
    int stride = gridDim.x * blockDim.x;
    for (int i = idx; i < n; i += stride) {
        float v = x[i];
        unsigned short h = f2bf(v);
        hi[i] = h;
        lo[i] = f2bf(v - bf2f(h));
    }
}

// all three weight transposes in one launch
__global__ __launch_bounds__(256) void wconv_all(
    const float* __restrict__ w1, const float* __restrict__ w2, const float* __restrict__ w3,
    unsigned short* __restrict__ w1th, unsigned short* __restrict__ w1tl,
    unsigned short* __restrict__ w2th, unsigned short* __restrict__ w2tl,
    unsigned short* __restrict__ w3th, unsigned short* __restrict__ w3tl) {
    const int T1 = 128 * 128, T2 = 256 * 128, T3 = 48 * 256;
    int idx = blockIdx.x * 256 + threadIdx.x;
    float v; unsigned short* th; unsigned short* tl; int o;
    if (idx < T1) {
        int n = idx / 128, k = idx % 128;
        v = w1[k * 128 + n]; th = w1th; tl = w1tl; o = idx;
    } else if (idx < T1 + T2) {
        int i = idx - T1; int n = i / 128, k = i % 128;
        v = w2[k * 256 + n]; th = w2th; tl = w2tl; o = i;
    } else if (idx < T1 + T2 + T3) {
        int i = idx - T1 - T2; int n = i / 256, k = i % 256;
        v = (n < 40) ? w3[k * 40 + n] : 0.f; th = w3th; tl = w3tl; o = i;
    } else return;
    unsigned short h = f2bf(v);
    th[o] = h;
    tl[o] = f2bf(v - bf2f(h));
}

// alpha vectors: ab1 (16x128 bf16 tile), ab3 (16x256 tile), ws2f/wd2f (fp32[128])
__global__ __launch_bounds__(256) void wav_all(
    const float* __restrict__ w1, const float* __restrict__ as1, const float* __restrict__ ad1,
    const float* __restrict__ w3, const float* __restrict__ as3, const float* __restrict__ ad3,
    const float* __restrict__ w2, const float* __restrict__ as2, const float* __restrict__ ad2,
    unsigned short* __restrict__ ab1h, unsigned short* __restrict__ ab1l,
    unsigned short* __restrict__ ab3h, unsigned short* __restrict__ ab3l,
    float* __restrict__ ws2f, float* __restrict__ wd2f) {
    int idx = blockIdx.x * 256 + threadIdx.x;
    if (idx < 2048) {                       // layer 1 tile
        int r = idx / 128, k = idx % 128;
        float v = 0.f;
        if (r < 2) {
            const float* a = r ? ad1 : as1;
            const float* wr = w1 + (size_t)k * 128;
            for (int n = 0; n < 128; n++) v += wr[n] * a[n];
        }
        unsigned short h = f2bf(v);
        ab1h[idx] = h; ab1l[idx] = f2bf(v - bf2f(h));
    } else if (idx < 2048 + 4096) {         // layer 3 tile
        int i = idx - 2048; int r = i / 256, k = i % 256;
        float v = 0.f;
        if (r < 2) {
            const float* a = r ? ad3 : as3;
            const float* wr = w3 + (size_t)k * 40;
            for (int n = 0; n < 40; n++) v += wr[n] * a[n];
        }
        unsigned short h = f2bf(v);
        ab3h[i] = h; ab3l[i] = f2bf(v - bf2f(h));
    } else if (idx < 2048 + 4096 + 256) {   // layer 2 fp32 vectors
        int i = idx - 2048 - 4096; int r = i / 128, k = i % 128;
        const float* a = r ? ad2 : as2;
        const float* wr = w2 + (size_t)k * 256;
        float v = 0.f;
        for (int n = 0; n < 256; n++) v += wr[n] * a[n];
        if (r == 0) ws2f[k] = v; else wd2f[k] = v;
    }
}

// ---------------------------------------------------------------------------
// Split-bf16 MFMA GEMM. ASPLIT: A hi+lo (3 products) vs hi (2).
// ALPHA: fused alpha dots via 16-col AB tile -> asrc/adst.
// BNT: epilogue bias+BN+tanh (layer-2). C always bf16-hi, row stride ldc.
// ---------------------------------------------------------------------------
template<int K, int NTILES, int MWAVES, int NWAVES, int NACT, bool ASPLIT, bool ALPHA, bool BNT>
__global__ __launch_bounds__(256) void mfma_gemm(
    const unsigned short* __restrict__ Ahi, const unsigned short* __restrict__ Alo,
    const unsigned short* __restrict__ BThi, const unsigned short* __restrict__ BTlo,
    const unsigned short* __restrict__ ABh, const unsigned short* __restrict__ ABl,
    unsigned short* __restrict__ Chi, int ldc,
    const float* __restrict__ bias, const float* __restrict__ gamma,
    const float* __restrict__ beta, const float* __restrict__ rmean,
    const float* __restrict__ rvar,
    float* __restrict__ asrc, float* __restrict__ adst, int M)
{
    int lane = threadIdx.x & 63;
    int wave = threadIdx.x >> 6;
    int quad = lane >> 4;
    int l16  = lane & 15;
    long mbase = (long)blockIdx.x * (64 * MWAVES) + (long)(wave / NWAVES) * 64;
    int n0 = (wave % NWAVES) * (NTILES * 16);
    bool aw = (wave % NWAVES) == 0;

    const unsigned short* ah[4]; const unsigned short* al[4];
#pragma unroll
    for (int i = 0; i < 4; i++) {
        long r = mbase + i * 16 + l16;
        if (r > M - 1) r = M - 1;
        ah[i] = Ahi + r * K;
        if constexpr (ASPLIT) al[i] = Alo + r * K;
    }
    const unsigned short* bh[NTILES]; const unsigned short* bl[NTILES];
#pragma unroll
    for (int j = 0; j < NTILES; j++) {
        long n = n0 + j * 16 + l16;
        bh[j] = BThi + n * K; bl[j] = BTlo + n * K;
    }
    const unsigned short* bah = nullptr; const unsigned short* bal = nullptr;
    if constexpr (ALPHA) { bah = ABh + (size_t)l16 * K; bal = ABl + (size_t)l16 * K; }
    const int ko = quad * 8;

    f32x4 acc[4][NTILES];
    f32x4 acca[4];
#pragma unroll
    for (int i = 0; i < 4; i++) {
        acca[i] = (f32x4){0.f, 0.f, 0.f, 0.f};
#pragma unroll
        for (int j = 0; j < NTILES; j++)
            acc[i][j] = (f32x4){0.f, 0.f, 0.f, 0.f};
    }

    for (int k0 = 0; k0 < K; k0 += 32) {
        short8 vah[4], vall[4], vbh[NTILES], vbl[NTILES];
#pragma unroll
        for (int i = 0; i < 4; i++) {
            vah[i] = *(const short8*)(ah[i] + k0 + ko);
            if constexpr (ASPLIT) vall[i] = *(const short8*)(al[i] + k0 + ko);
        }
#pragma unroll
        for (int j = 0; j < NTILES; j++) {
            vbh[j] = *(const short8*)(bh[j] + k0 + ko);
            vbl[j] = *(const short8*)(bl[j] + k0 + ko);
        }
#pragma unroll
        for (int i = 0; i < 4; i++)
#pragma unroll
            for (int j = 0; j < NTILES; j++) {
                acc[i][j] = __builtin_amdgcn_mfma_f32_16x16x32_bf16(vah[i], vbh[j], acc[i][j], 0, 0, 0);
                acc[i][j] = __builtin_amdgcn_mfma_f32_16x16x32_bf16(vah[i], vbl[j], acc[i][j], 0, 0, 0);
                if constexpr (ASPLIT)
                    acc[i][j] = __builtin_amdgcn_mfma_f32_16x16x32_bf16(vall[i], vbh[j], acc[i][j], 0, 0, 0);
            }
        if constexpr (ALPHA) {
            if (aw) {
                short8 vbah = *(const short8*)(bah + k0 + ko);
                short8 vbal = *(const short8*)(bal + k0 + ko);
#pragma unroll
                for (int i = 0; i < 4; i++) {
                    acca[i] = __builtin_amdgcn_mfma_f32_16x16x32_bf16(vah[i], vbah, acca[i], 0, 0, 0);
                    acca[i] = __builtin_amdgcn_mfma_f32_16x16x32_bf16(vah[i], vbal, acca[i], 0, 0, 0);
                    if constexpr (ASPLIT)
                        acca[i] = __builtin_amdgcn_mfma_f32_16x16x32_bf16(vall[i], vbah, acca[i], 0, 0, 0);
                }
            }
        }
    }

#pragma unroll
    for (int i = 0; i < 4; i++)
#pragma unroll
        for (int j = 0; j < NTILES; j++) {
            int col = n0 + j * 16 + l16;
            float bb = 0.f, rs = 1.f, gg = 1.f, bt = 0.f, rm = 0.f;
            if constexpr (BNT) {
                bb = bias[col]; gg = gamma[col]; bt = beta[col];
                rm = rmean[col]; rs = rsqrtf(rvar[col] + BN_EPS);
            }
#pragma unroll
            for (int r = 0; r < 4; r++) {
                long row = mbase + i * 16 + quad * 4 + r;
                if (row < M && col < NACT) {
                    float v = acc[i][j][r];
                    if constexpr (BNT) v = tanhf((v + bb - rm) * rs * gg + bt);
                    Chi[row * ldc + col] = f2bf(v);
                }
            }
        }
    if constexpr (ALPHA) {
        if (aw) {
#pragma unroll
            for (int i = 0; i < 4; i++)
#pragma unroll
                for (int r = 0; r < 4; r++) {
                    long row = mbase + i * 16 + quad * 4 + r;
                    if (row < M) {
                        float v = acca[i][r];
                        if (l16 == 0) asrc[row] = v;
                        else if (l16 == 1) adst[row] = v;
                    }
                }
        }
    }
}

// ---------------------------------------------------------------------------
// chunk_gather8: readlane scalar-base gather, unroll-8.
// GIN 0: u32/lane (bf16, F=128). GIN 1: u16/lane (bf16, F=40).
// ---------------------------------------------------------------------------
template<int F, int GIN>
__device__ __forceinline__ void chunk_gather8(
    const unsigned short* __restrict__ hbf,
    int sv, int wv, int cnt, int lane, float* acc)
{
    int j = 0;
    for (; j + 8 <= cnt; j += 8) {
        int ss[8], wb[8];
#pragma unroll
        for (int k = 0; k < 8; k++) {
            ss[k] = __builtin_amdgcn_readlane(sv, j + k);
            wb[k] = __builtin_amdgcn_readlane(wv, j + k);
        }
        if constexpr (GIN == 0) {
            unsigned u[8];
#pragma unroll
            for (int k = 0; k < 8; k++)
                u[k] = *reinterpret_cast<const unsigned*>(hbf + (size_t)ss[k] * F + lane * 2);
            f32x2* a2 = reinterpret_cast<f32x2*>(acc);
#pragma unroll
            for (int k = 0; k < 8; k++) {
                float ww = __int_as_float(wb[k]);
                *a2 += (f32x2){ww, ww} * (f32x2){bflo(u[k]), bfhi(u[k])};
            }
        } else {
            unsigned short u[8];
#pragma unroll
            for (int k = 0; k < 8; k++)
                u[k] = hbf[(size_t)ss[k] * F + lane];
#pragma unroll
            for (int k = 0; k < 8; k++)
                acc[0] += __int_as_float(wb[k]) * bf2f(u[k]);
        }
    }
    for (; j < cnt; j++) {
        int ss = __builtin_amdgcn_readlane(sv, j);
        int wb = __builtin_amdgcn_readlane(wv, j);
        float ww = __int_as_float(wb);
        if constexpr (GIN == 0) {
            unsigned u = *reinterpret_cast<const unsigned*>(hbf + (size_t)ss * F + lane * 2);
            acc[0] += ww * bflo(u); acc[1] += ww * bfhi(u);
        } else {
            acc[0] += ww * bf2f(hbf[(size_t)ss * F + lane]);
        }
    }
}

// ---------------------------------------------------------------------------
// gat_agg8: fused segment-softmax + gather-aggregate, wave per node.
// OMODE 0: bias+BN+tanh, write o hi bf16, fused next-layer alpha dots (wsn/wdn)
// OMODE 1: raw sum, write split hi/lo (GEMM input)
// OMODE 2: +bias, write fp32 out (F=40)
// ---------------------------------------------------------------------------
template<int F, int GIN, int OMODE>
__global__ __launch_bounds__(256) void gat_agg8(
    const unsigned short* __restrict__ hbf,
    const float* __restrict__ asrc, const float* __restrict__ adst,
    const int* __restrict__ row_ptr, const int* __restrict__ src_sorted,
    const float* __restrict__ bias, const float* __restrict__ gamma,
    const float* __restrict__ beta, const float* __restrict__ rmean,
    const float* __restrict__ rvar,
    const float* __restrict__ wsn, const float* __restrict__ wdn,
    unsigned short* __restrict__ ohi, unsigned short* __restrict__ olo,
    float* __restrict__ outf,
    float* __restrict__ asrc_n, float* __restrict__ adst_n)
{
    constexpr int NA = (GIN == 0) ? 2 : 1;
    int wave = threadIdx.x >> 6;
    int lane = threadIdx.x & 63;
    int node = blockIdx.x * 4 + wave;
    if (node >= N_NODES) return;

    int start = row_ptr[node];
    int end = row_ptr[node + 1];
    int deg = end - start;
    float ad = adst[node];

    float acc[NA];
#pragma unroll
    for (int v = 0; v < NA; v++) acc[v] = 0.f;

    if (deg <= 64) {
        int e = start + lane;
        int s = 0; float l = -1e30f;
        if (e < end) { s = src_sorted[e]; l = lrelu(asrc[s] + ad); }
        float m = l;
#pragma unroll
        for (int off = 32; off; off >>= 1) m = fmaxf(m, __shfl_xor(m, off));
        float pr = (e < end) ? __expf(l - m) : 0.f;
        float d = pr;
#pragma unroll
        for (int off = 32; off; off >>= 1) d += __shfl_xor(d, off);
        int wv = __float_as_int(pr / d);
        chunk_gather8<F, GIN>(hbf, s, wv, deg, lane, acc);
    } else {
        float m = -1e30f, d = 0.f;
        for (int cs = start; cs < end; cs += 64) {
            int e = cs + lane;
            float l = -1e30f;
            if (e < end) { int s = src_sorted[e]; l = lrelu(asrc[s] + ad); }
            float cm = l;
#pragma unroll
            for (int off = 32; off; off >>= 1) cm = fmaxf(cm, __shfl_xor(cm, off));
            float nm = fmaxf(m, cm);
            float cp = (e < end) ? __expf(l - nm) : 0.f;
#pragma unroll
            for (int off = 32; off; off >>= 1) cp += __shfl_xor(cp, off);
            d = d * __expf(m - nm) + cp;
            m = nm;
        }
        float inv = 1.0f / d;
        for (int cs = start; cs < end; cs += 64) {
            int e = cs + lane;
            int s = 0, wv = 0;
            if (e < end) {
                s = src_sorted[e];
                float l = lrelu(asrc[s] + ad);
                wv = __float_as_int(__expf(l - m) * inv);
            }
            chunk_gather8<F, GIN>(hbf, s, wv, min(64, end - cs), lane, acc);
        }
    }

    if constexpr (OMODE == 0) {
        // bias + BN + tanh, write bf16 hi, fused alpha dots for next layer
        float vals[2];
#pragma unroll
        for (int v = 0; v < 2; v++) {
            int f = lane * 2 + v;
            float val = acc[v] + bias[f];
            float rs = rsqrtf(rvar[f] + BN_EPS);
            vals[v] = tanhf((val - rmean[f]) * rs * gamma[f] + beta[f]);
        }
        unsigned w0 = (unsigned)f2bf(vals[0]) | ((unsigned)f2bf(vals[1]) << 16);
        *reinterpret_cast<unsigned*>(ohi + (size_t)node * F + lane * 2) = w0;
        float ps = vals[0] * wsn[lane * 2] + vals[1] * wsn[lane * 2 + 1];
        float pd = vals[0] * wdn[lane * 2] + vals[1] * wdn[lane * 2 + 1];
#pragma unroll
        for (int off = 32; off; off >>= 1) {
            ps += __shfl_xor(ps, off);
            pd += __shfl_xor(pd, off);
        }
        if (lane == 0) { asrc_n[node] = ps; adst_n[node] = pd; }
    } else if constexpr (OMODE == 1) {
        unsigned short h0 = f2bf(acc[0]), h1 = f2bf(acc[1]);
        unsigned short l0 = f2bf(acc[0] - bf2f(h0)), l1 = f2bf(acc[1] - bf2f(h1));
        *reinterpret_cast<unsigned*>(ohi + (size_t)node * F + lane * 2) =
            (unsigned)h0 | ((unsigned)h1 << 16);
        *reinterpret_cast<unsigned*>(olo + (size_t)node * F + lane * 2) =
            (unsigned)l0 | ((unsigned)l1 << 16);
    } else {
        if (lane < F) outf[(size_t)node * F + lane] = acc[0] + bias[lane];
    }
}

// ---------------------------------------------------------------------------

static inline size_t align256(size_t x) { return (x + 255) & ~(size_t)255; }

extern "C" void kernel_launch(void* const* d_in, const int* in_sizes, int n_in,
                              void* d_out, int out_size, void* d_ws, size_t ws_size,
                              hipStream_t stream) {
    const float* x   = (const float*)d_in[0];
    const int* ei    = (const int*)d_in[1];
    const float* w1  = (const float*)d_in[2];
    const float* as1 = (const float*)d_in[3];
    const float* ad1 = (const float*)d_in[4];
    const float* b1  = (const float*)d_in[5];
    const float* g1  = (const float*)d_in[6];
    const float* be1 = (const float*)d_in[7];
    const float* rm1 = (const float*)d_in[8];
    const float* rv1 = (const float*)d_in[9];
    const float* w2  = (const float*)d_in[10];
    const float* as2 = (const float*)d_in[11];
    const float* ad2 = (const float*)d_in[12];
    const float* b2  = (const float*)d_in[13];
    const float* g2  = (const float*)d_in[14];
    const float* be2 = (const float*)d_in[15];
    const float* rm2 = (const float*)d_in[16];
    const float* rv2 = (const float*)d_in[17];
    const float* w3  = (const float*)d_in[18];
    const float* as3 = (const float*)d_in[19];
    const float* ad3 = (const float*)d_in[20];
    const float* b3  = (const float*)d_in[21];
    float* out = (float*)d_out;

    const size_t P128 = align256((size_t)N_NODES * 128 * 2);
    const size_t P256 = align256((size_t)N_NODES * 256 * 2);

    char* p = (char*)d_ws;
    // regA: xhi|xlo -> o1hi (front half) -> o2hi (full)
    char* regA = p; p += P256;
    // regB: h1hi (front) -> g2hi|g2lo -> h3hi (front)
    char* regB = p; p += P256;
    unsigned short* xhi  = (unsigned short*)regA;
    unsigned short* xlo  = (unsigned short*)(regA + P128);
    unsigned short* o1hi = (unsigned short*)regA;
    unsigned short* o2hi = (unsigned short*)regA;
    unsigned short* h1hi = (unsigned short*)regB;
    unsigned short* g2hi = (unsigned short*)regB;
    unsigned short* g2lo = (unsigned short*)(regB + P128);
    unsigned short* h3hi = (unsigned short*)regB;  // N*40 + pad, < P128

    float* asrcA = (float*)p; p += align256((size_t)N_NODES * 4);
    float* adstA = (float*)p; p += align256((size_t)N_NODES * 4);
    float* asrcB = (float*)p; p += align256((size_t)N_NODES * 4);
    float* adstB = (float*)p; p += align256((size_t)N_NODES * 4);
    int* counts    = (int*)p; p += align256((size_t)N_NODES * 4);
    int* row_ptr   = (int*)p; p += align256((size_t)(N_NODES + 1) * 4);
    int* write_pos = (int*)p; p += align256((size_t)N_NODES * 4);
    int* src_sorted = (int*)p; p += align256((size_t)TOT_EDGES * 4);
    int* partials  = (int*)p;  p += align256(512 * 4);
    unsigned short* w1th = (unsigned short*)p; p += align256(128 * 128 * 2);
    unsigned short* w1tl = (unsigned short*)p; p += align256(128 * 128 * 2);
    unsigned short* w2th = (unsigned short*)p; p += align256(256 * 128 * 2);
    unsigned short* w2tl = (unsigned short*)p; p += align256(256 * 128 * 2);
    unsigned short* w3th = (unsigned short*)p; p += align256(48 * 256 * 2);
    unsigned short* w3tl = (unsigned short*)p; p += align256(48 * 256 * 2);
    unsigned short* ab1h = (unsigned short*)p; p += align256(16 * 128 * 2);
    unsigned short* ab1l = (unsigned short*)p; p += align256(16 * 128 * 2);
    unsigned short* ab3h = (unsigned short*)p; p += align256(16 * 256 * 2);
    unsigned short* ab3l = (unsigned short*)p; p += align256(16 * 256 * 2);
    float* ws2f = (float*)p; p += align256(128 * 4);
    float* wd2f = (float*)p; p += align256(128 * 4);

    const int NB = (N_NODES + 255) / 256;
    const int WTOT = 128 * 128 + 256 * 128 + 48 * 256;

    xconv<<<4096, 256, 0, stream>>>(x, xhi, xlo, N_NODES * 128);
    wconv_all<<<(WTOT + 255) / 256, 256, 0, stream>>>(w1, w2, w3, w1th, w1tl,
                                                      w2th, w2tl, w3th, w3tl);
    wav_all<<<(2048 + 4096 + 256 + 255) / 256, 256, 0, stream>>>(
        w1, as1, ad1, w3, as3, ad3, w2, as2, ad2,
        ab1h, ab1l, ab3h, ab3l, ws2f, wd2f);

    hipMemsetAsync(counts, 0, (size_t)N_NODES * 4, stream);
    count_kernel<<<4096, 256, 0, stream>>>(ei, counts);
    scan_partial<<<NB, 256, 0, stream>>>(counts, partials);
    scan_partials_kernel<<<1, 512, 0, stream>>>(partials, NB);
    scan_final<<<NB, 256, 0, stream>>>(counts, partials, row_ptr, write_pos);
    scatter_kernel<<<4096, 256, 0, stream>>>(ei, write_pos, src_sorted);

    const int NWB = (N_NODES + 3) / 4;
    const int G64 = (N_NODES + 63) / 64;
    const int G256 = (N_NODES + 255) / 256;

    // --- Layer 1: h1 = x@w1 (+alpha1); agg1 -> o1 (+alpha2 dots fused) ---
    mfma_gemm<128, 2, 1, 4, 128, true, true, false><<<G64, 256, 0, stream>>>(
        xhi, xlo, w1th, w1tl, ab1h, ab1l, h1hi, 128,
        nullptr, nullptr, nullptr, nullptr, nullptr, asrcA, adstA, N_NODES);
    gat_agg8<128, 0, 0><<<NWB, 256, 0, stream>>>(
        h1hi, asrcA, adstA, row_ptr, src_sorted,
        b1, g1, be1, rm1, rv1, ws2f, wd2f,
        o1hi, nullptr, nullptr, asrcB, adstB);

    // --- Layer 2 (commuted): g2 = S2(o1); o2 = tanh(BN(g2@w2 + b2)) ---
    gat_agg8<128, 0, 1><<<NWB, 256, 0, stream>>>(
        o1hi, asrcB, adstB, row_ptr, src_sorted,
        nullptr, nullptr, nullptr, nullptr, nullptr, nullptr, nullptr,
        g2hi, g2lo, nullptr, nullptr, nullptr);
    mfma_gemm<128, 4, 1, 4, 256, true, false, true><<<G64, 256, 0, stream>>>(
        g2hi, g2lo, w2th, w2tl, nullptr, nullptr, o2hi, 256,
        b2, g2, be2, rm2, rv2, nullptr, nullptr, N_NODES);

    // --- Layer 3: h3 = o2@w3 (bf16, +alpha3); agg3 -> out ---
    mfma_gemm<256, 3, 4, 1, 40, false, true, false><<<G256, 256, 0, stream>>>(
        o2hi, nullptr, w3th, w3tl, ab3h, ab3l, h3hi, 40,
        nullptr, nullptr, nullptr, nullptr, nullptr, asrcA, adstA, N_NODES);
    gat_agg8<40, 1, 2><<<NWB, 256, 0, stream>>>(
        h3hi, asrcA, adstA, row_ptr, src_sorted,
        b3, nullptr, nullptr, nullptr, nullptr, nullptr, nullptr,
        nullptr, nullptr, out, nullptr, nullptr);
}

// Round 10
// 721.764 us; speedup vs baseline: 1.5517x; 1.0033x over previous
//
#include <hip/hip_runtime.h>
#include <hip/hip_bf16.h>
#include <cstddef>

#define N_NODES 100000
#define E_EDGES 1600000
#define TOT_EDGES (E_EDGES + N_NODES)
#define NEG_SLOPE 0.2f
#define BN_EPS 1e-5f
#define NPASS 8
#define PASS_W ((N_NODES + NPASS - 1) / NPASS)

typedef __attribute__((ext_vector_type(8))) short short8;
typedef __attribute__((ext_vector_type(4))) float f32x4;
typedef __attribute__((ext_vector_type(2))) float f32x2;

__device__ __forceinline__ unsigned short f2bf(float f) {
    union { float f; unsigned u; } c; c.f = f;
    unsigned u = c.u;
    u += 0x7fffu + ((u >> 16) & 1u);
    return (unsigned short)(u >> 16);
}
__device__ __forceinline__ float bf2f(unsigned short h) {
    union { unsigned u; float f; } c; c.u = ((unsigned)h) << 16;
    return c.f;
}
__device__ __forceinline__ float bflo(unsigned u) {
    union { unsigned u; float f; } c; c.u = u << 16; return c.f;
}
__device__ __forceinline__ float bfhi(unsigned u) {
    union { unsigned u; float f; } c; c.u = u & 0xffff0000u; return c.f;
}
__device__ __forceinline__ float lrelu(float t) {
    return (t > 0.f) ? t : NEG_SLOPE * t;
}

// ---------------------------------------------------------------------------
// CSR build
// ---------------------------------------------------------------------------

__global__ __launch_bounds__(256) void count_kernel(const int* __restrict__ ei,
                                                    int* __restrict__ counts) {
    int idx = blockIdx.x * blockDim.x + threadIdx.x;
    int stride = gridDim.x * blockDim.x;
    for (int e = idx; e < TOT_EDGES; e += stride) {
        int d = (e < E_EDGES) ? ei[E_EDGES + e] : (e - E_EDGES);
        atomicAdd(&counts[d], 1);
    }
}

__global__ __launch_bounds__(256) void scan_partial(const int* __restrict__ counts,
                                                    int* __restrict__ partials) {
    __shared__ int s[256];
    int t = threadIdx.x;
    int i = blockIdx.x * 256 + t;
    s[t] = (i < N_NODES) ? counts[i] : 0;
    __syncthreads();
    for (int off = 128; off; off >>= 1) {
        if (t < off) s[t] += s[t + off];
        __syncthreads();
    }
    if (t == 0) partials[blockIdx.x] = s[0];
}

__global__ __launch_bounds__(512) void scan_partials_kernel(int* __restrict__ partials, int nb) {
    __shared__ int s[512];
    int t = threadIdx.x;
    int v = (t < nb) ? partials[t] : 0;
    s[t] = v;
    __syncthreads();
    for (int off = 1; off < 512; off <<= 1) {
        int y = (t >= off) ? s[t - off] : 0;
        __syncthreads();
        s[t] += y;
        __syncthreads();
    }
    if (t < nb) partials[t] = s[t] - v;
}

__global__ __launch_bounds__(256) void scan_final(const int* __restrict__ counts,
                                                  const int* __restrict__ partials,
                                                  int* __restrict__ row_ptr,
                                                  int* __restrict__ write_pos) {
    __shared__ int s[256];
    int t = threadIdx.x;
    int i = blockIdx.x * 256 + t;
    int v = (i < N_NODES) ? counts[i] : 0;
    s[t] = v;
    __syncthreads();
    for (int off = 1; off < 256; off <<= 1) {
        int y = (t >= off) ? s[t - off] : 0;
        __syncthreads();
        s[t] += y;
        __syncthreads();
    }
    int excl = s[t] - v;
    int rp = partials[blockIdx.x] + excl;
    if (i <= N_NODES) row_ptr[i] = rp;
    if (i < N_NODES) write_pos[i] = rp;
}

// dst-range-partitioned scatter: pass p only handles dst in [p*PASS_W,(p+1)*PASS_W).
// Active CSR write window ~850 KB -> L2-resident -> full-line write combining.
__global__ __launch_bounds__(256) void scatter_pass(const int* __restrict__ ei,
                                                    int* __restrict__ write_pos,
                                                    int* __restrict__ src_sorted,
                                                    int lo, int hi) {
    int idx = blockIdx.x * blockDim.x + threadIdx.x;
    int stride = gridDim.x * blockDim.x;
    for (int e = idx; e < TOT_EDGES; e += stride) {
        int srcv, d;
        if (e < E_EDGES) { srcv = ei[e]; d = ei[E_EDGES + e]; }
        else             { srcv = e - E_EDGES; d = srcv; }
        if (d >= lo && d < hi) {
            int p = atomicAdd(&write_pos[d], 1);
            src_sorted[p] = srcv;
        }
    }
}

// ---------------------------------------------------------------------------
// Conversions (fused)
// ---------------------------------------------------------------------------

__global__ __launch_bounds__(256) void xconv(const float* __restrict__ x,
                                             unsigned short* __restrict__ hi,
                                             unsigned short* __restrict__ lo, int n) {
    int idx = blockIdx.x * blockDim.x + threadIdx.x;
    int stride = gridDim.x * blockDim.x;
    for (int i = idx; i < n; i += stride) {
        float v = x[i];
        unsigned short h = f2bf(v);
        hi[i] = h;
        lo[i] = f2bf(v - bf2f(h));
    }
}

// all three weight transposes in one launch
__global__ __launch_bounds__(256) void wconv_all(
    const float* __restrict__ w1, const float* __restrict__ w2, const float* __restrict__ w3,
    unsigned short* __restrict__ w1th, unsigned short* __restrict__ w1tl,
    unsigned short* __restrict__ w2th, unsigned short* __restrict__ w2tl,
    unsigned short* __restrict__ w3th, unsigned short* __restrict__ w3tl) {
    const int T1 = 128 * 128, T2 = 256 * 128, T3 = 48 * 256;
    int idx = blockIdx.x * 256 + threadIdx.x;
    float v; unsigned short* th; unsigned short* tl; int o;
    if (idx < T1) {
        int n = idx / 128, k = idx % 128;
        v = w1[k * 128 + n]; th = w1th; tl = w1tl; o = idx;
    } else if (idx < T1 + T2) {
        int i = idx - T1; int n = i / 128, k = i % 128;
        v = w2[k * 256 + n]; th = w2th; tl = w2tl; o = i;
    } else if (idx < T1 + T2 + T3) {
        int i = idx - T1 - T2; int n = i / 256, k = i % 256;
        v = (n < 40) ? w3[k * 40 + n] : 0.f; th = w3th; tl = w3tl; o = i;
    } else return;
    unsigned short h = f2bf(v);
    th[o] = h;
    tl[o] = f2bf(v - bf2f(h));
}

// alpha vectors: ab1 (16x128 bf16 tile), ab3 (16x256 tile), ws2f/wd2f (fp32[128])
__global__ __launch_bounds__(256) void wav_all(
    const float* __restrict__ w1, const float* __restrict__ as1, const float* __restrict__ ad1,
    const float* __restrict__ w3, const float* __restrict__ as3, const float* __restrict__ ad3,
    const float* __restrict__ w2, const float* __restrict__ as2, const float* __restrict__ ad2,
    unsigned short* __restrict__ ab1h, unsigned short* __restrict__ ab1l,
    unsigned short* __restrict__ ab3h, unsigned short* __restrict__ ab3l,
    float* __restrict__ ws2f, float* __restrict__ wd2f) {
    int idx = blockIdx.x * 256 + threadIdx.x;
    if (idx < 2048) {                       // layer 1 tile
        int r = idx / 128, k = idx % 128;
        float v = 0.f;
        if (r < 2) {
            const float* a = r ? ad1 : as1;
            const float* wr = w1 + (size_t)k * 128;
            for (int n = 0; n < 128; n++) v += wr[n] * a[n];
        }
        unsigned short h = f2bf(v);
        ab1h[idx] = h; ab1l[idx] = f2bf(v - bf2f(h));
    } else if (idx < 2048 + 4096) {         // layer 3 tile
        int i = idx - 2048; int r = i / 256, k = i % 256;
        float v = 0.f;
        if (r < 2) {
            const float* a = r ? ad3 : as3;
            const float* wr = w3 + (size_t)k * 40;
            for (int n = 0; n < 40; n++) v += wr[n] * a[n];
        }
        unsigned short h = f2bf(v);
        ab3h[i] = h; ab3l[i] = f2bf(v - bf2f(h));
    } else if (idx < 2048 + 4096 + 256) {   // layer 2 fp32 vectors
        int i = idx - 2048 - 4096; int r = i / 128, k = i % 128;
        const float* a = r ? ad2 : as2;
        const float* wr = w2 + (size_t)k * 256;
        float v = 0.f;
        for (int n = 0; n < 256; n++) v += wr[n] * a[n];
        if (r == 0) ws2f[k] = v; else wd2f[k] = v;
    }
}

// ---------------------------------------------------------------------------
// Split-bf16 MFMA GEMM. ASPLIT: A hi+lo (3 products) vs hi (2).
// ALPHA: fused alpha dots via 16-col AB tile -> asrc/adst.
// BNT: epilogue bias+BN+tanh (layer-2). C always bf16-hi, row stride ldc.
// ---------------------------------------------------------------------------
template<int K, int NTILES, int MWAVES, int NWAVES, int NACT, bool ASPLIT, bool ALPHA, bool BNT>
__global__ __launch_bounds__(256) void mfma_gemm(
    const unsigned short* __restrict__ Ahi, const unsigned short* __restrict__ Alo,
    const unsigned short* __restrict__ BThi, const unsigned short* __restrict__ BTlo,
    const unsigned short* __restrict__ ABh, const unsigned short* __restrict__ ABl,
    unsigned short* __restrict__ Chi, int ldc,
    const float* __restrict__ bias, const float* __restrict__ gamma,
    const float* __restrict__ beta, const float* __restrict__ rmean,
    const float* __restrict__ rvar,
    float* __restrict__ asrc, float* __restrict__ adst, int M)
{
    int lane = threadIdx.x & 63;
    int wave = threadIdx.x >> 6;
    int quad = lane >> 4;
    int l16  = lane & 15;
    long mbase = (long)blockIdx.x * (64 * MWAVES) + (long)(wave / NWAVES) * 64;
    int n0 = (wave % NWAVES) * (NTILES * 16);
    bool aw = (wave % NWAVES) == 0;

    const unsigned short* ah[4]; const unsigned short* al[4];
#pragma unroll
    for (int i = 0; i < 4; i++) {
        long r = mbase + i * 16 + l16;
        if (r > M - 1) r = M - 1;
        ah[i] = Ahi + r * K;
        if constexpr (ASPLIT) al[i] = Alo + r * K;
    }
    const unsigned short* bh[NTILES]; const unsigned short* bl[NTILES];
#pragma unroll
    for (int j = 0; j < NTILES; j++) {
        long n = n0 + j * 16 + l16;
        bh[j] = BThi + n * K; bl[j] = BTlo + n * K;
    }
    const unsigned short* bah = nullptr; const unsigned short* bal = nullptr;
    if constexpr (ALPHA) { bah = ABh + (size_t)l16 * K; bal = ABl + (size_t)l16 * K; }
    const int ko = quad * 8;

    f32x4 acc[4][NTILES];
    f32x4 acca[4];
#pragma unroll
    for (int i = 0; i < 4; i++) {
        acca[i] = (f32x4){0.f, 0.f, 0.f, 0.f};
#pragma unroll
        for (int j = 0; j < NTILES; j++)
            acc[i][j] = (f32x4){0.f, 0.f, 0.f, 0.f};
    }

    for (int k0 = 0; k0 < K; k0 += 32) {
        short8 vah[4], vall[4], vbh[NTILES], vbl[NTILES];
#pragma unroll
        for (int i = 0; i < 4; i++) {
            vah[i] = *(const short8*)(ah[i] + k0 + ko);
            if constexpr (ASPLIT) vall[i] = *(const short8*)(al[i] + k0 + ko);
        }
#pragma unroll
        for (int j = 0; j < NTILES; j++) {
            vbh[j] = *(const short8*)(bh[j] + k0 + ko);
            vbl[j] = *(const short8*)(bl[j] + k0 + ko);
        }
#pragma unroll
        for (int i = 0; i < 4; i++)
#pragma unroll
            for (int j = 0; j < NTILES; j++) {
                acc[i][j] = __builtin_amdgcn_mfma_f32_16x16x32_bf16(vah[i], vbh[j], acc[i][j], 0, 0, 0);
                acc[i][j] = __builtin_amdgcn_mfma_f32_16x16x32_bf16(vah[i], vbl[j], acc[i][j], 0, 0, 0);
                if constexpr (ASPLIT)
                    acc[i][j] = __builtin_amdgcn_mfma_f32_16x16x32_bf16(vall[i], vbh[j], acc[i][j], 0, 0, 0);
            }
        if constexpr (ALPHA) {
            if (aw) {
                short8 vbah = *(const short8*)(bah + k0 + ko);
                short8 vbal = *(const short8*)(bal + k0 + ko);
#pragma unroll
                for (int i = 0; i < 4; i++) {
                    acca[i] = __builtin_amdgcn_mfma_f32_16x16x32_bf16(vah[i], vbah, acca[i], 0, 0, 0);
                    acca[i] = __builtin_amdgcn_mfma_f32_16x16x32_bf16(vah[i], vbal, acca[i], 0, 0, 0);
                    if constexpr (ASPLIT)
                        acca[i] = __builtin_amdgcn_mfma_f32_16x16x32_bf16(vall[i], vbah, acca[i], 0, 0, 0);
                }
            }
        }
    }

#pragma unroll
    for (int i = 0; i < 4; i++)
#pragma unroll
        for (int j = 0; j < NTILES; j++) {
            int col = n0 + j * 16 + l16;
            float bb = 0.f, rs = 1.f, gg = 1.f, bt = 0.f, rm = 0.f;
            if constexpr (BNT) {
                bb = bias[col]; gg = gamma[col]; bt = beta[col];
                rm = rmean[col]; rs = rsqrtf(rvar[col] + BN_EPS);
            }
#pragma unroll
            for (int r = 0; r < 4; r++) {
                long row = mbase + i * 16 + quad * 4 + r;
                if (row < M && col < NACT) {
                    float v = acc[i][j][r];
                    if constexpr (BNT) v = tanhf((v + bb - rm) * rs * gg + bt);
                    Chi[row * ldc + col] = f2bf(v);
                }
            }
        }
    if constexpr (ALPHA) {
        if (aw) {
#pragma unroll
            for (int i = 0; i < 4; i++)
#pragma unroll
                for (int r = 0; r < 4; r++) {
                    long row = mbase + i * 16 + quad * 4 + r;
                    if (row < M) {
                        float v = acca[i][r];
                        if (l16 == 0) asrc[row] = v;
                        else if (l16 == 1) adst[row] = v;
                    }
                }
        }
    }
}

// ---------------------------------------------------------------------------
// chunk_gather8: readlane scalar-base gather, unroll-8.
// GIN 0: u32/lane (bf16, row stride F). GIN 1: u16/lane (bf16, stride LDH).
// ---------------------------------------------------------------------------
template<int F, int GIN, int LDH>
__device__ __forceinline__ void chunk_gather8(
    const unsigned short* __restrict__ hbf,
    int sv, int wv, int cnt, int lane, float* acc)
{
    int j = 0;
    for (; j + 8 <= cnt; j += 8) {
        int ss[8], wb[8];
#pragma unroll
        for (int k = 0; k < 8; k++) {
            ss[k] = __builtin_amdgcn_readlane(sv, j + k);
            wb[k] = __builtin_amdgcn_readlane(wv, j + k);
        }
        if constexpr (GIN == 0) {
            unsigned u[8];
#pragma unroll
            for (int k = 0; k < 8; k++)
                u[k] = *reinterpret_cast<const unsigned*>(hbf + (size_t)ss[k] * F + lane * 2);
            f32x2* a2 = reinterpret_cast<f32x2*>(acc);
#pragma unroll
            for (int k = 0; k < 8; k++) {
                float ww = __int_as_float(wb[k]);
                *a2 += (f32x2){ww, ww} * (f32x2){bflo(u[k]), bfhi(u[k])};
            }
        } else {
            unsigned short u[8];
#pragma unroll
            for (int k = 0; k < 8; k++)
                u[k] = hbf[(size_t)ss[k] * LDH + lane];
#pragma unroll
            for (int k = 0; k < 8; k++)
                acc[0] += __int_as_float(wb[k]) * bf2f(u[k]);
        }
    }
    for (; j < cnt; j++) {
        int ss = __builtin_amdgcn_readlane(sv, j);
        int wb = __builtin_amdgcn_readlane(wv, j);
        float ww = __int_as_float(wb);
        if constexpr (GIN == 0) {
            unsigned u = *reinterpret_cast<const unsigned*>(hbf + (size_t)ss * F + lane * 2);
            acc[0] += ww * bflo(u); acc[1] += ww * bfhi(u);
        } else {
            acc[0] += ww * bf2f(hbf[(size_t)ss * LDH + lane]);
        }
    }
}

// ---------------------------------------------------------------------------
// gat_agg8: fused segment-softmax + gather-aggregate, wave per node.
// OMODE 0: bias+BN+tanh, write o hi bf16, fused next-layer alpha dots (wsn/wdn)
// OMODE 1: raw sum, write split hi/lo (GEMM input)
// OMODE 2: +bias, write fp32 out (F=40, LDH=64 padded input rows)
// ---------------------------------------------------------------------------
template<int F, int GIN, int OMODE, int LDH>
__global__ __launch_bounds__(256) void gat_agg8(
    const unsigned short* __restrict__ hbf,
    const float* __restrict__ asrc, const float* __restrict__ adst,
    const int* __restrict__ row_ptr, const int* __restrict__ src_sorted,
    const float* __restrict__ bias, const float* __restrict__ gamma,
    const float* __restrict__ beta, const float* __restrict__ rmean,
    const float* __restrict__ rvar,
    const float* __restrict__ wsn, const float* __restrict__ wdn,
    unsigned short* __restrict__ ohi, unsigned short* __restrict__ olo,
    float* __restrict__ outf,
    float* __restrict__ asrc_n, float* __restrict__ adst_n)
{
    constexpr int NA = (GIN == 0) ? 2 : 1;
    int wave = threadIdx.x >> 6;
    int lane = threadIdx.x & 63;
    int node = blockIdx.x * 4 + wave;
    if (node >= N_NODES) return;

    int start = row_ptr[node];
    int end = row_ptr[node + 1];
    int deg = end - start;
    float ad = adst[node];

    float acc[NA];
#pragma unroll
    for (int v = 0; v < NA; v++) acc[v] = 0.f;

    if (deg <= 64) {
        int e = start + lane;
        int s = 0; float l = -1e30f;
        if (e < end) { s = src_sorted[e]; l = lrelu(asrc[s] + ad); }
        float m = l;
#pragma unroll
        for (int off = 32; off; off >>= 1) m = fmaxf(m, __shfl_xor(m, off));
        float pr = (e < end) ? __expf(l - m) : 0.f;
        float d = pr;
#pragma unroll
        for (int off = 32; off; off >>= 1) d += __shfl_xor(d, off);
        int wv = __float_as_int(pr / d);
        chunk_gather8<F, GIN, LDH>(hbf, s, wv, deg, lane, acc);
    } else {
        float m = -1e30f, d = 0.f;
        for (int cs = start; cs < end; cs += 64) {
            int e = cs + lane;
            float l = -1e30f;
            if (e < end) { int s = src_sorted[e]; l = lrelu(asrc[s] + ad); }
            float cm = l;
#pragma unroll
            for (int off = 32; off; off >>= 1) cm = fmaxf(cm, __shfl_xor(cm, off));
            float nm = fmaxf(m, cm);
            float cp = (e < end) ? __expf(l - nm) : 0.f;
#pragma unroll
            for (int off = 32; off; off >>= 1) cp += __shfl_xor(cp, off);
            d = d * __expf(m - nm) + cp;
            m = nm;
        }
        float inv = 1.0f / d;
        for (int cs = start; cs < end; cs += 64) {
            int e = cs + lane;
            int s = 0, wv = 0;
            if (e < end) {
                s = src_sorted[e];
                float l = lrelu(asrc[s] + ad);
                wv = __float_as_int(__expf(l - m) * inv);
            }
            chunk_gather8<F, GIN, LDH>(hbf, s, wv, min(64, end - cs), lane, acc);
        }
    }

    if constexpr (OMODE == 0) {
        float vals[2];
#pragma unroll
        for (int v = 0; v < 2; v++) {
            int f = lane * 2 + v;
            float val = acc[v] + bias[f];
            float rs = rsqrtf(rvar[f] + BN_EPS);
            vals[v] = tanhf((val - rmean[f]) * rs * gamma[f] + beta[f]);
        }
        unsigned w0 = (unsigned)f2bf(vals[0]) | ((unsigned)f2bf(vals[1]) << 16);
        *reinterpret_cast<unsigned*>(ohi + (size_t)node * F + lane * 2) = w0;
        float ps = vals[0] * wsn[lane * 2] + vals[1] * wsn[lane * 2 + 1];
        float pd = vals[0] * wdn[lane * 2] + vals[1] * wdn[lane * 2 + 1];
#pragma unroll
        for (int off = 32; off; off >>= 1) {
            ps += __shfl_xor(ps, off);
            pd += __shfl_xor(pd, off);
        }
        if (lane == 0) { asrc_n[node] = ps; adst_n[node] = pd; }
    } else if constexpr (OMODE == 1) {
        unsigned short h0 = f2bf(acc[0]), h1 = f2bf(acc[1]);
        unsigned short l0 = f2bf(acc[0] - bf2f(h0)), l1 = f2bf(acc[1] - bf2f(h1));
        *reinterpret_cast<unsigned*>(ohi + (size_t)node * F + lane * 2) =
            (unsigned)h0 | ((unsigned)h1 << 16);
        *reinterpret_cast<unsigned*>(olo + (size_t)node * F + lane * 2) =
            (unsigned)l0 | ((unsigned)l1 << 16);
    } else {
        if (lane < F) outf[(size_t)node * F + lane] = acc[0] + bias[lane];
    }
}

// ---------------------------------------------------------------------------

static inline size_t align256(size_t x) { return (x + 255) & ~(size_t)255; }

extern "C" void kernel_launch(void* const* d_in, const int* in_sizes, int n_in,
                              void* d_out, int out_size, void* d_ws, size_t ws_size,
                              hipStream_t stream) {
    const float* x   = (const float*)d_in[0];
    const int* ei    = (const int*)d_in[1];
    const float* w1  = (const float*)d_in[2];
    const float* as1 = (const float*)d_in[3];
    const float* ad1 = (const float*)d_in[4];
    const float* b1  = (const float*)d_in[5];
    const float* g1  = (const float*)d_in[6];
    const float* be1 = (const float*)d_in[7];
    const float* rm1 = (const float*)d_in[8];
    const float* rv1 = (const float*)d_in[9];
    const float* w2  = (const float*)d_in[10];
    const float* as2 = (const float*)d_in[11];
    const float* ad2 = (const float*)d_in[12];
    const float* b2  = (const float*)d_in[13];
    const float* g2  = (const float*)d_in[14];
    const float* be2 = (const float*)d_in[15];
    const float* rm2 = (const float*)d_in[16];
    const float* rv2 = (const float*)d_in[17];
    const float* w3  = (const float*)d_in[18];
    const float* as3 = (const float*)d_in[19];
    const float* ad3 = (const float*)d_in[20];
    const float* b3  = (const float*)d_in[21];
    float* out = (float*)d_out;

    const size_t P128 = align256((size_t)N_NODES * 128 * 2);
    const size_t P256 = align256((size_t)N_NODES * 256 * 2);

    char* p = (char*)d_ws;
    // regA: xhi|xlo -> o1hi (front half) -> o2hi (full)
    char* regA = p; p += P256;
    // regB: h1hi (front) -> g2hi|g2lo -> h3hi (front, ldh=64 padded)
    char* regB = p; p += P256;
    unsigned short* xhi  = (unsigned short*)regA;
    unsigned short* xlo  = (unsigned short*)(regA + P128);
    unsigned short* o1hi = (unsigned short*)regA;
    unsigned short* o2hi = (unsigned short*)regA;
    unsigned short* h1hi = (unsigned short*)regB;
    unsigned short* g2hi = (unsigned short*)regB;
    unsigned short* g2lo = (unsigned short*)(regB + P128);
    unsigned short* h3hi = (unsigned short*)regB;  // N*64*2B = 12.8MB < P128

    float* asrcA = (float*)p; p += align256((size_t)N_NODES * 4);
    float* adstA = (float*)p; p += align256((size_t)N_NODES * 4);
    float* asrcB = (float*)p; p += align256((size_t)N_NODES * 4);
    float* adstB = (float*)p; p += align256((size_t)N_NODES * 4);
    int* counts    = (int*)p; p += align256((size_t)N_NODES * 4);
    int* row_ptr   = (int*)p; p += align256((size_t)(N_NODES + 1) * 4);
    int* write_pos = (int*)p; p += align256((size_t)N_NODES * 4);
    int* src_sorted = (int*)p; p += align256((size_t)TOT_EDGES * 4);
    int* partials  = (int*)p;  p += align256(512 * 4);
    unsigned short* w1th = (unsigned short*)p; p += align256(128 * 128 * 2);
    unsigned short* w1tl = (unsigned short*)p; p += align256(128 * 128 * 2);
    unsigned short* w2th = (unsigned short*)p; p += align256(256 * 128 * 2);
    unsigned short* w2tl = (unsigned short*)p; p += align256(256 * 128 * 2);
    unsigned short* w3th = (unsigned short*)p; p += align256(48 * 256 * 2);
    unsigned short* w3tl = (unsigned short*)p; p += align256(48 * 256 * 2);
    unsigned short* ab1h = (unsigned short*)p; p += align256(16 * 128 * 2);
    unsigned short* ab1l = (unsigned short*)p; p += align256(16 * 128 * 2);
    unsigned short* ab3h = (unsigned short*)p; p += align256(16 * 256 * 2);
    unsigned short* ab3l = (unsigned short*)p; p += align256(16 * 256 * 2);
    float* ws2f = (float*)p; p += align256(128 * 4);
    float* wd2f = (float*)p; p += align256(128 * 4);

    const int NB = (N_NODES + 255) / 256;
    const int WTOT = 128 * 128 + 256 * 128 + 48 * 256;

    xconv<<<4096, 256, 0, stream>>>(x, xhi, xlo, N_NODES * 128);
    wconv_all<<<(WTOT + 255) / 256, 256, 0, stream>>>(w1, w2, w3, w1th, w1tl,
                                                      w2th, w2tl, w3th, w3tl);
    wav_all<<<(2048 + 4096 + 256 + 255) / 256, 256, 0, stream>>>(
        w1, as1, ad1, w3, as3, ad3, w2, as2, ad2,
        ab1h, ab1l, ab3h, ab3l, ws2f, wd2f);

    hipMemsetAsync(counts, 0, (size_t)N_NODES * 4, stream);
    count_kernel<<<4096, 256, 0, stream>>>(ei, counts);
    scan_partial<<<NB, 256, 0, stream>>>(counts, partials);
    scan_partials_kernel<<<1, 512, 0, stream>>>(partials, NB);
    scan_final<<<NB, 256, 0, stream>>>(counts, partials, row_ptr, write_pos);
    for (int ps = 0; ps < NPASS; ps++)
        scatter_pass<<<2048, 256, 0, stream>>>(ei, write_pos, src_sorted,
                                               ps * PASS_W, (ps + 1) * PASS_W);

    const int NWB = (N_NODES + 3) / 4;
    const int G64 = (N_NODES + 63) / 64;
    const int G256 = (N_NODES + 255) / 256;

    // --- Layer 1: h1 = x@w1 (+alpha1); agg1 -> o1 (+alpha2 dots fused) ---
    mfma_gemm<128, 2, 1, 4, 128, true, true, false><<<G64, 256, 0, stream>>>(
        xhi, xlo, w1th, w1tl, ab1h, ab1l, h1hi, 128,
        nullptr, nullptr, nullptr, nullptr, nullptr, asrcA, adstA, N_NODES);
    gat_agg8<128, 0, 0, 128><<<NWB, 256, 0, stream>>>(
        h1hi, asrcA, adstA, row_ptr, src_sorted,
        b1, g1, be1, rm1, rv1, ws2f, wd2f,
        o1hi, nullptr, nullptr, asrcB, adstB);

    // --- Layer 2 (commuted): g2 = S2(o1); o2 = tanh(BN(g2@w2 + b2)) ---
    gat_agg8<128, 0, 1, 128><<<NWB, 256, 0, stream>>>(
        o1hi, asrcB, adstB, row_ptr, src_sorted,
        nullptr, nullptr, nullptr, nullptr, nullptr, nullptr, nullptr,
        g2hi, g2lo, nullptr, nullptr, nullptr);
    mfma_gemm<128, 4, 1, 4, 256, true, false, true><<<G64, 256, 0, stream>>>(
        g2hi, g2lo, w2th, w2tl, nullptr, nullptr, o2hi, 256,
        b2, g2, be2, rm2, rv2, nullptr, nullptr, N_NODES);

    // --- Layer 3: h3 = o2@w3 (bf16, +alpha3, rows padded to 64); agg3 -> out ---
    mfma_gemm<256, 3, 4, 1, 48, false, true, false><<<G256, 256, 0, stream>>>(
        o2hi, nullptr, w3th, w3tl, ab3h, ab3l, h3hi, 64,
        nullptr, nullptr, nullptr, nullptr, nullptr, asrcA, adstA, N_NODES);
    gat_agg8<40, 1, 2, 64><<<NWB, 256, 0, stream>>>(
        h3hi, asrcA, adstA, row_ptr, src_sorted,
        b3, nullptr, nullptr, nullptr, nullptr, nullptr, nullptr,
        nullptr, nullptr, out, nullptr, nullptr);
}

// Round 12
// 710.052 us; speedup vs baseline: 1.5773x; 1.0165x over previous
//
#include <hip/hip_runtime.h>
#include <hip/hip_bf16.h>
#include <cstddef>

#define N_NODES 100000
#define E_EDGES 1600000
#define TOT_EDGES (E_EDGES + N_NODES)
#define NEG_SLOPE 0.2f
#define BN_EPS 1e-5f
#define NPASS 8
#define PASS_W ((N_NODES + NPASS - 1) / NPASS)

typedef __attribute__((ext_vector_type(8))) short short8;
typedef __attribute__((ext_vector_type(4))) float f32x4;
typedef __attribute__((ext_vector_type(2))) float f32x2;

__device__ __forceinline__ unsigned short f2bf(float f) {
    union { float f; unsigned u; } c; c.f = f;
    unsigned u = c.u;
    u += 0x7fffu + ((u >> 16) & 1u);
    return (unsigned short)(u >> 16);
}
__device__ __forceinline__ float bf2f(unsigned short h) {
    union { unsigned u; float f; } c; c.u = ((unsigned)h) << 16;
    return c.f;
}
__device__ __forceinline__ float bflo(unsigned u) {
    union { unsigned u; float f; } c; c.u = u << 16; return c.f;
}
__device__ __forceinline__ float bfhi(unsigned u) {
    union { unsigned u; float f; } c; c.u = u & 0xffff0000u; return c.f;
}
__device__ __forceinline__ float lrelu(float t) {
    return (t > 0.f) ? t : NEG_SLOPE * t;
}
// fast tanh: 1 - 2/(e^{2x}+1). |err| ~1e-6 absolute; saturates correctly.
__device__ __forceinline__ float tanh_fast(float x) {
    float e = __expf(2.f * x);
    return 1.f - 2.f / (e + 1.f);
}

// ---------------------------------------------------------------------------
// CSR build
// ---------------------------------------------------------------------------

__global__ __launch_bounds__(256) void count_kernel(const int* __restrict__ ei,
                                                    int* __restrict__ counts) {
    int idx = blockIdx.x * blockDim.x + threadIdx.x;
    int stride = gridDim.x * blockDim.x;
    for (int e = idx; e < TOT_EDGES; e += stride) {
        int d = (e < E_EDGES) ? ei[E_EDGES + e] : (e - E_EDGES);
        atomicAdd(&counts[d], 1);
    }
}

__global__ __launch_bounds__(256) void scan_partial(const int* __restrict__ counts,
                                                    int* __restrict__ partials) {
    __shared__ int s[256];
    int t = threadIdx.x;
    int i = blockIdx.x * 256 + t;
    s[t] = (i < N_NODES) ? counts[i] : 0;
    __syncthreads();
    for (int off = 128; off; off >>= 1) {
        if (t < off) s[t] += s[t + off];
        __syncthreads();
    }
    if (t == 0) partials[blockIdx.x] = s[0];
}

__global__ __launch_bounds__(512) void scan_partials_kernel(int* __restrict__ partials, int nb) {
    __shared__ int s[512];
    int t = threadIdx.x;
    int v = (t < nb) ? partials[t] : 0;
    s[t] = v;
    __syncthreads();
    for (int off = 1; off < 512; off <<= 1) {
        int y = (t >= off) ? s[t - off] : 0;
        __syncthreads();
        s[t] += y;
        __syncthreads();
    }
    if (t < nb) partials[t] = s[t] - v;
}

__global__ __launch_bounds__(256) void scan_final(const int* __restrict__ counts,
                                                  const int* __restrict__ partials,
                                                  int* __restrict__ row_ptr,
                                                  int* __restrict__ write_pos) {
    __shared__ int s[256];
    int t = threadIdx.x;
    int i = blockIdx.x * 256 + t;
    int v = (i < N_NODES) ? counts[i] : 0;
    s[t] = v;
    __syncthreads();
    for (int off = 1; off < 256; off <<= 1) {
        int y = (t >= off) ? s[t - off] : 0;
        __syncthreads();
        s[t] += y;
        __syncthreads();
    }
    int excl = s[t] - v;
    int rp = partials[blockIdx.x] + excl;
    if (i <= N_NODES) row_ptr[i] = rp;
    if (i < N_NODES) write_pos[i] = rp;
}

__global__ __launch_bounds__(256) void scatter_pass(const int* __restrict__ ei,
                                                    int* __restrict__ write_pos,
                                                    int* __restrict__ src_sorted,
                                                    int lo, int hi) {
    int idx = blockIdx.x * blockDim.x + threadIdx.x;
    int stride = gridDim.x * blockDim.x;
    for (int e = idx; e < TOT_EDGES; e += stride) {
        int srcv, d;
        if (e < E_EDGES) { srcv = ei[e]; d = ei[E_EDGES + e]; }
        else             { srcv = e - E_EDGES; d = srcv; }
        if (d >= lo && d < hi) {
            int p = atomicAdd(&write_pos[d], 1);
            src_sorted[p] = srcv;
        }
    }
}

// ---------------------------------------------------------------------------
// Conversions (fused)
// ---------------------------------------------------------------------------

__global__ __launch_bounds__(256) void xconv(const float* __restrict__ x,
                                             unsigned short* __restrict__ hi,
                                             unsigned short* __restrict__ lo, int n) {
    int idx = blockIdx.x * blockDim.x + threadIdx.x;
    int stride = gridDim.x * blockDim.x;
    for (int i = idx; i < n; i += stride) {
        float v = x[i];
        unsigned short h = f2bf(v);
        hi[i] = h;
        lo[i] = f2bf(v - bf2f(h));
    }
}

__global__ __launch_bounds__(256) void wconv_all(
    const float* __restrict__ w1, const float* __restrict__ w2, const float* __restrict__ w3,
    unsigned short* __restrict__ w1th, unsigned short* __restrict__ w1tl,
    unsigned short* __restrict__ w2th, unsigned short* __restrict__ w2tl,
    unsigned short* __restrict__ w3th, unsigned short* __restrict__ w3tl) {
    const int T1 = 128 * 128, T2 = 256 * 128, T3 = 48 * 256;
    int idx = blockIdx.x * 256 + threadIdx.x;
    float v; unsigned short* th; unsigned short* tl; int o;
    if (idx < T1) {
        int n = idx / 128, k = idx % 128;
        v = w1[k * 128 + n]; th = w1th; tl = w1tl; o = idx;
    } else if (idx < T1 + T2) {
        int i = idx - T1; int n = i / 128, k = i % 128;
        v = w2[k * 256 + n]; th = w2th; tl = w2tl; o = i;
    } else if (idx < T1 + T2 + T3) {
        int i = idx - T1 - T2; int n = i / 256, k = i % 256;
        v = (n < 40) ? w3[k * 40 + n] : 0.f; th = w3th; tl = w3tl; o = i;
    } else return;
    unsigned short h = f2bf(v);
    th[o] = h;
    tl[o] = f2bf(v - bf2f(h));
}

__global__ __launch_bounds__(256) void wav_all(
    const float* __restrict__ w1, const float* __restrict__ as1, const float* __restrict__ ad1,
    const float* __restrict__ w3, const float* __restrict__ as3, const float* __restrict__ ad3,
    const float* __restrict__ w2, const float* __restrict__ as2, const float* __restrict__ ad2,
    unsigned short* __restrict__ ab1h, unsigned short* __restrict__ ab1l,
    unsigned short* __restrict__ ab3h, unsigned short* __restrict__ ab3l,
    float* __restrict__ ws2f, float* __restrict__ wd2f) {
    int idx = blockIdx.x * 256 + threadIdx.x;
    if (idx < 2048) {
        int r = idx / 128, k = idx % 128;
        float v = 0.f;
        if (r < 2) {
            const float* a = r ? ad1 : as1;
            const float* wr = w1 + (size_t)k * 128;
            for (int n = 0; n < 128; n++) v += wr[n] * a[n];
        }
        unsigned short h = f2bf(v);
        ab1h[idx] = h; ab1l[idx] = f2bf(v - bf2f(h));
    } else if (idx < 2048 + 4096) {
        int i = idx - 2048; int r = i / 256, k = i % 256;
        float v = 0.f;
        if (r < 2) {
            const float* a = r ? ad3 : as3;
            const float* wr = w3 + (size_t)k * 40;
            for (int n = 0; n < 40; n++) v += wr[n] * a[n];
        }
        unsigned short h = f2bf(v);
        ab3h[i] = h; ab3l[i] = f2bf(v - bf2f(h));
    } else if (idx < 2048 + 4096 + 256) {
        int i = idx - 2048 - 4096; int r = i / 128, k = i % 128;
        const float* a = r ? ad2 : as2;
        const float* wr = w2 + (size_t)k * 256;
        float v = 0.f;
        for (int n = 0; n < 256; n++) v += wr[n] * a[n];
        if (r == 0) ws2f[k] = v; else wd2f[k] = v;
    }
}

// ---------------------------------------------------------------------------
// Split-bf16 MFMA GEMM. Column-split grids via blockIdx.y.
// ---------------------------------------------------------------------------
template<int K, int NTILES, int MWAVES, int NWAVES, int NACT, bool ASPLIT, bool ALPHA, bool BNT>
__global__ __launch_bounds__(256) void mfma_gemm(
    const unsigned short* __restrict__ Ahi, const unsigned short* __restrict__ Alo,
    const unsigned short* __restrict__ BThi, const unsigned short* __restrict__ BTlo,
    const unsigned short* __restrict__ ABh, const unsigned short* __restrict__ ABl,
    unsigned short* __restrict__ Chi, int ldc,
    const float* __restrict__ bias, const float* __restrict__ gamma,
    const float* __restrict__ beta, const float* __restrict__ rmean,
    const float* __restrict__ rvar,
    float* __restrict__ asrc, float* __restrict__ adst, int M)
{
    int lane = threadIdx.x & 63;
    int wave = threadIdx.x >> 6;
    int quad = lane >> 4;
    int l16  = lane & 15;
    long mbase = (long)blockIdx.x * (64 * MWAVES) + (long)(wave / NWAVES) * 64;
    int n0 = ((wave % NWAVES) + blockIdx.y * NWAVES) * (NTILES * 16);
    bool aw = ((wave % NWAVES) == 0) && (blockIdx.y == 0);

    const unsigned short* ah[4]; const unsigned short* al[4];
#pragma unroll
    for (int i = 0; i < 4; i++) {
        long r = mbase + i * 16 + l16;
        if (r > M - 1) r = M - 1;
        ah[i] = Ahi + r * K;
        if constexpr (ASPLIT) al[i] = Alo + r * K;
    }
    const unsigned short* bh[NTILES]; const unsigned short* bl[NTILES];
#pragma unroll
    for (int j = 0; j < NTILES; j++) {
        long n = n0 + j * 16 + l16;
        bh[j] = BThi + n * K; bl[j] = BTlo + n * K;
    }
    const unsigned short* bah = nullptr; const unsigned short* bal = nullptr;
    if constexpr (ALPHA) { bah = ABh + (size_t)l16 * K; bal = ABl + (size_t)l16 * K; }
    const int ko = quad * 8;

    f32x4 acc[4][NTILES];
    f32x4 acca[4];
#pragma unroll
    for (int i = 0; i < 4; i++) {
        acca[i] = (f32x4){0.f, 0.f, 0.f, 0.f};
#pragma unroll
        for (int j = 0; j < NTILES; j++)
            acc[i][j] = (f32x4){0.f, 0.f, 0.f, 0.f};
    }

    for (int k0 = 0; k0 < K; k0 += 32) {
        short8 vah[4], vall[4], vbh[NTILES], vbl[NTILES];
#pragma unroll
        for (int i = 0; i < 4; i++) {
            vah[i] = *(const short8*)(ah[i] + k0 + ko);
            if constexpr (ASPLIT) vall[i] = *(const short8*)(al[i] + k0 + ko);
        }
#pragma unroll
        for (int j = 0; j < NTILES; j++) {
            vbh[j] = *(const short8*)(bh[j] + k0 + ko);
            vbl[j] = *(const short8*)(bl[j] + k0 + ko);
        }
#pragma unroll
        for (int i = 0; i < 4; i++)
#pragma unroll
            for (int j = 0; j < NTILES; j++) {
                acc[i][j] = __builtin_amdgcn_mfma_f32_16x16x32_bf16(vah[i], vbh[j], acc[i][j], 0, 0, 0);
                acc[i][j] = __builtin_amdgcn_mfma_f32_16x16x32_bf16(vah[i], vbl[j], acc[i][j], 0, 0, 0);
                if constexpr (ASPLIT)
                    acc[i][j] = __builtin_amdgcn_mfma_f32_16x16x32_bf16(vall[i], vbh[j], acc[i][j], 0, 0, 0);
            }
        if constexpr (ALPHA) {
            if (aw) {
                short8 vbah = *(const short8*)(bah + k0 + ko);
                short8 vbal = *(const short8*)(bal + k0 + ko);
#pragma unroll
                for (int i = 0; i < 4; i++) {
                    acca[i] = __builtin_amdgcn_mfma_f32_16x16x32_bf16(vah[i], vbah, acca[i], 0, 0, 0);
                    acca[i] = __builtin_amdgcn_mfma_f32_16x16x32_bf16(vah[i], vbal, acca[i], 0, 0, 0);
                    if constexpr (ASPLIT)
                        acca[i] = __builtin_amdgcn_mfma_f32_16x16x32_bf16(vall[i], vbah, acca[i], 0, 0, 0);
                }
            }
        }
    }

#pragma unroll
    for (int i = 0; i < 4; i++)
#pragma unroll
        for (int j = 0; j < NTILES; j++) {
            int col = n0 + j * 16 + l16;
            float bb = 0.f, rs = 1.f, gg = 1.f, bt = 0.f, rm = 0.f;
            if constexpr (BNT) {
                bb = bias[col]; gg = gamma[col]; bt = beta[col];
                rm = rmean[col]; rs = rsqrtf(rvar[col] + BN_EPS);
            }
#pragma unroll
            for (int r = 0; r < 4; r++) {
                long row = mbase + i * 16 + quad * 4 + r;
                if (row < M && col < NACT) {
                    float v = acc[i][j][r];
                    if constexpr (BNT) v = tanh_fast((v + bb - rm) * rs * gg + bt);
                    Chi[row * ldc + col] = f2bf(v);
                }
            }
        }
    if constexpr (ALPHA) {
        if (aw) {
#pragma unroll
            for (int i = 0; i < 4; i++)
#pragma unroll
                for (int r = 0; r < 4; r++) {
                    long row = mbase + i * 16 + quad * 4 + r;
                    if (row < M) {
                        float v = acca[i][r];
                        if (l16 == 0) asrc[row] = v;
                        else if (l16 == 1) adst[row] = v;
                    }
                }
        }
    }
}

// ---------------------------------------------------------------------------
// chunk_gather8: readlane scalar-base gather, unroll-8.
// GIN 0: u32/lane (bf16 pair, row stride LDH u16). GIN 1: u16/lane (stride LDH).
// ---------------------------------------------------------------------------
template<int GIN, int LDH>
__device__ __forceinline__ void chunk_gather8(
    const unsigned short* __restrict__ hbf,
    int sv, int wv, int cnt, int lane, float* acc)
{
    int j = 0;
    for (; j + 8 <= cnt; j += 8) {
        int ss[8], wb[8];
#pragma unroll
        for (int k = 0; k < 8; k++) {
            ss[k] = __builtin_amdgcn_readlane(sv, j + k);
            wb[k] = __builtin_amdgcn_readlane(wv, j + k);
        }
        if constexpr (GIN == 0) {
            unsigned u[8];
#pragma unroll
            for (int k = 0; k < 8; k++)
                u[k] = *reinterpret_cast<const unsigned*>(hbf + (size_t)ss[k] * LDH + lane * 2);
            f32x2* a2 = reinterpret_cast<f32x2*>(acc);
#pragma unroll
            for (int k = 0; k < 8; k++) {
                float ww = __int_as_float(wb[k]);
                *a2 += (f32x2){ww, ww} * (f32x2){bflo(u[k]), bfhi(u[k])};
            }
        } else {
            unsigned short u[8];
#pragma unroll
            for (int k = 0; k < 8; k++)
                u[k] = hbf[(size_t)ss[k] * LDH + lane];
#pragma unroll
            for (int k = 0; k < 8; k++)
                acc[0] += __int_as_float(wb[k]) * bf2f(u[k]);
        }
    }
    for (; j < cnt; j++) {
        int ss = __builtin_amdgcn_readlane(sv, j);
        int wb = __builtin_amdgcn_readlane(wv, j);
        float ww = __int_as_float(wb);
        if constexpr (GIN == 0) {
            unsigned u = *reinterpret_cast<const unsigned*>(hbf + (size_t)ss * LDH + lane * 2);
            acc[0] += ww * bflo(u); acc[1] += ww * bfhi(u);
        } else {
            acc[0] += ww * bf2f(hbf[(size_t)ss * LDH + lane]);
        }
    }
}

// ---------------------------------------------------------------------------
// gat_agg8: fused segment-softmax + gather-aggregate, wave per node.
// OMODE 0: bias+BN+tanh, write o bf16 pairs, fused next-layer alpha dots.
// OMODE 1: raw sum, write split hi/lo bf16 (GEMM input)
// OMODE 2: +bias, write fp32 out (F=40)
// ---------------------------------------------------------------------------
template<int F, int GIN, int OMODE, int LDH>
__global__ __launch_bounds__(256) void gat_agg8(
    const unsigned short* __restrict__ hbf,
    const float* __restrict__ asrc, const float* __restrict__ adst,
    const int* __restrict__ row_ptr, const int* __restrict__ src_sorted,
    const float* __restrict__ bias, const float* __restrict__ gamma,
    const float* __restrict__ beta, const float* __restrict__ rmean,
    const float* __restrict__ rvar,
    const float* __restrict__ wsn, const float* __restrict__ wdn,
    unsigned short* __restrict__ ohi, unsigned short* __restrict__ olo,
    float* __restrict__ outf,
    float* __restrict__ asrc_n, float* __restrict__ adst_n)
{
    constexpr int NA = (GIN == 0) ? 2 : 1;
    int wave = threadIdx.x >> 6;
    int lane = threadIdx.x & 63;
    int node = blockIdx.x * 4 + wave;
    if (node >= N_NODES) return;

    int start = row_ptr[node];
    int end = row_ptr[node + 1];
    int deg = end - start;
    float ad = adst[node];

    float acc[NA];
#pragma unroll
    for (int v = 0; v < NA; v++) acc[v] = 0.f;

    if (deg <= 64) {
        int e = start + lane;
        int s = 0; float l = -1e30f;
        if (e < end) { s = src_sorted[e]; l = lrelu(asrc[s] + ad); }
        float m = l;
#pragma unroll
        for (int off = 32; off; off >>= 1) m = fmaxf(m, __shfl_xor(m, off));
        float pr = (e < end) ? __expf(l - m) : 0.f;
        float d = pr;
#pragma unroll
        for (int off = 32; off; off >>= 1) d += __shfl_xor(d, off);
        int wv = __float_as_int(pr / d);
        chunk_gather8<GIN, LDH>(hbf, s, wv, deg, lane, acc);
    } else {
        float m = -1e30f, d = 0.f;
        for (int cs = start; cs < end; cs += 64) {
            int e = cs + lane;
            float l = -1e30f;
            if (e < end) { int s = src_sorted[e]; l = lrelu(asrc[s] + ad); }
            float cm = l;
#pragma unroll
            for (int off = 32; off; off >>= 1) cm = fmaxf(cm, __shfl_xor(cm, off));
            float nm = fmaxf(m, cm);
            float cp = (e < end) ? __expf(l - nm) : 0.f;
#pragma unroll
            for (int off = 32; off; off >>= 1) cp += __shfl_xor(cp, off);
            d = d * __expf(m - nm) + cp;
            m = nm;
        }
        float inv = 1.0f / d;
        for (int cs = start; cs < end; cs += 64) {
            int e = cs + lane;
            int s = 0, wv = 0;
            if (e < end) {
                s = src_sorted[e];
                float l = lrelu(asrc[s] + ad);
                wv = __float_as_int(__expf(l - m) * inv);
            }
            chunk_gather8<GIN, LDH>(hbf, s, wv, min(64, end - cs), lane, acc);
        }
    }

    if constexpr (OMODE == 0) {
        float vals[2];
#pragma unroll
        for (int v = 0; v < 2; v++) {
            int f = lane * 2 + v;
            float val = acc[v] + bias[f];
            float rs = rsqrtf(rvar[f] + BN_EPS);
            vals[v] = tanh_fast((val - rmean[f]) * rs * gamma[f] + beta[f]);
        }
        unsigned w0 = (unsigned)f2bf(vals[0]) | ((unsigned)f2bf(vals[1]) << 16);
        *reinterpret_cast<unsigned*>(ohi + (size_t)node * F + lane * 2) = w0;
        float ps = vals[0] * wsn[lane * 2] + vals[1] * wsn[lane * 2 + 1];
        float pd = vals[0] * wdn[lane * 2] + vals[1] * wdn[lane * 2 + 1];
#pragma unroll
        for (int off = 32; off; off >>= 1) {
            ps += __shfl_xor(ps, off);
            pd += __shfl_xor(pd, off);
        }
        if (lane == 0) { asrc_n[node] = ps; adst_n[node] = pd; }
    } else if constexpr (OMODE == 1) {
        unsigned short h0 = f2bf(acc[0]), h1 = f2bf(acc[1]);
        unsigned short l0 = f2bf(acc[0] - bf2f(h0)), l1 = f2bf(acc[1] - bf2f(h1));
        *reinterpret_cast<unsigned*>(ohi + (size_t)node * F + lane * 2) =
            (unsigned)h0 | ((unsigned)h1 << 16);
        *reinterpret_cast<unsigned*>(olo + (size_t)node * F + lane * 2) =
            (unsigned)l0 | ((unsigned)l1 << 16);
    } else {
        if (lane < F) outf[(size_t)node * F + lane] = acc[0] + bias[lane];
    }
}

// ---------------------------------------------------------------------------

static inline size_t align256(size_t x) { return (x + 255) & ~(size_t)255; }

extern "C" void kernel_launch(void* const* d_in, const int* in_sizes, int n_in,
                              void* d_out, int out_size, void* d_ws, size_t ws_size,
                              hipStream_t stream) {
    const float* x   = (const float*)d_in[0];
    const int* ei    = (const int*)d_in[1];
    const float* w1  = (const float*)d_in[2];
    const float* as1 = (const float*)d_in[3];
    const float* ad1 = (const float*)d_in[4];
    const float* b1  = (const float*)d_in[5];
    const float* g1  = (const float*)d_in[6];
    const float* be1 = (const float*)d_in[7];
    const float* rm1 = (const float*)d_in[8];
    const float* rv1 = (const float*)d_in[9];
    const float* w2  = (const float*)d_in[10];
    const float* as2 = (const float*)d_in[11];
    const float* ad2 = (const float*)d_in[12];
    const float* b2  = (const float*)d_in[13];
    const float* g2  = (const float*)d_in[14];
    const float* be2 = (const float*)d_in[15];
    const float* rm2 = (const float*)d_in[16];
    const float* rv2 = (const float*)d_in[17];
    const float* w3  = (const float*)d_in[18];
    const float* as3 = (const float*)d_in[19];
    const float* ad3 = (const float*)d_in[20];
    const float* b3  = (const float*)d_in[21];
    float* out = (float*)d_out;

    const size_t P128 = align256((size_t)N_NODES * 128 * 2);
    const size_t P256 = align256((size_t)N_NODES * 256 * 2);

    char* p = (char*)d_ws;
    // regA: xhi|xlo -> o1hi (front half) -> o2hi (full)
    char* regA = p; p += P256;
    // regB: h1hi (front) -> g2hi|g2lo -> h3hi (front, ldh=64 padded)
    char* regB = p; p += P256;
    unsigned short* xhi  = (unsigned short*)regA;
    unsigned short* xlo  = (unsigned short*)(regA + P128);
    unsigned short* o1hi = (unsigned short*)regA;
    unsigned short* o2hi = (unsigned short*)regA;
    unsigned short* h1hi = (unsigned short*)regB;
    unsigned short* g2hi = (unsigned short*)regB;
    unsigned short* g2lo = (unsigned short*)(regB + P128);
    unsigned short* h3hi = (unsigned short*)regB;  // N*64 u16 padded rows

    float* asrcA = (float*)p; p += align256((size_t)N_NODES * 4);
    float* adstA = (float*)p; p += align256((size_t)N_NODES * 4);
    float* asrcB = (float*)p; p += align256((size_t)N_NODES * 4);
    float* adstB = (float*)p; p += align256((size_t)N_NODES * 4);
    int* counts    = (int*)p; p += align256((size_t)N_NODES * 4);
    int* row_ptr   = (int*)p; p += align256((size_t)(N_NODES + 1) * 4);
    int* write_pos = (int*)p; p += align256((size_t)N_NODES * 4);
    int* src_sorted = (int*)p; p += align256((size_t)TOT_EDGES * 4);
    int* partials  = (int*)p;  p += align256(512 * 4);
    unsigned short* w1th = (unsigned short*)p; p += align256(128 * 128 * 2);
    unsigned short* w1tl = (unsigned short*)p; p += align256(128 * 128 * 2);
    unsigned short* w2th = (unsigned short*)p; p += align256(256 * 128 * 2);
    unsigned short* w2tl = (unsigned short*)p; p += align256(256 * 128 * 2);
    unsigned short* w3th = (unsigned short*)p; p += align256(48 * 256 * 2);
    unsigned short* w3tl = (unsigned short*)p; p += align256(48 * 256 * 2);
    unsigned short* ab1h = (unsigned short*)p; p += align256(16 * 128 * 2);
    unsigned short* ab1l = (unsigned short*)p; p += align256(16 * 128 * 2);
    unsigned short* ab3h = (unsigned short*)p; p += align256(16 * 256 * 2);
    unsigned short* ab3l = (unsigned short*)p; p += align256(16 * 256 * 2);
    float* ws2f = (float*)p; p += align256(128 * 4);
    float* wd2f = (float*)p; p += align256(128 * 4);

    const int NB = (N_NODES + 255) / 256;
    const int WTOT = 128 * 128 + 256 * 128 + 48 * 256;

    xconv<<<4096, 256, 0, stream>>>(x, xhi, xlo, N_NODES * 128);
    wconv_all<<<(WTOT + 255) / 256, 256, 0, stream>>>(w1, w2, w3, w1th, w1tl,
                                                      w2th, w2tl, w3th, w3tl);
    wav_all<<<(2048 + 4096 + 256 + 255) / 256, 256, 0, stream>>>(
        w1, as1, ad1, w3, as3, ad3, w2, as2, ad2,
        ab1h, ab1l, ab3h, ab3l, ws2f, wd2f);

    hipMemsetAsync(counts, 0, (size_t)N_NODES * 4, stream);
    count_kernel<<<4096, 256, 0, stream>>>(ei, counts);
    scan_partial<<<NB, 256, 0, stream>>>(counts, partials);
    scan_partials_kernel<<<1, 512, 0, stream>>>(partials, NB);
    scan_final<<<NB, 256, 0, stream>>>(counts, partials, row_ptr, write_pos);
    for (int ps = 0; ps < NPASS; ps++)
        scatter_pass<<<2048, 256, 0, stream>>>(ei, write_pos, src_sorted,
                                               ps * PASS_W, (ps + 1) * PASS_W);

    const int NWB = (N_NODES + 3) / 4;
    const int G64 = (N_NODES + 63) / 64;
    const int G256 = (N_NODES + 255) / 256;

    // --- Layer 1: h1 = x@w1 (+alpha1); agg1 -> o1 (+alpha2 dots fused) ---
    mfma_gemm<128, 2, 1, 4, 128, true, true, false><<<G64, 256, 0, stream>>>(
        xhi, xlo, w1th, w1tl, ab1h, ab1l, h1hi, 128,
        nullptr, nullptr, nullptr, nullptr, nullptr, asrcA, adstA, N_NODES);
    gat_agg8<128, 0, 0, 128><<<NWB, 256, 0, stream>>>(
        h1hi, asrcA, adstA, row_ptr, src_sorted,
        b1, g1, be1, rm1, rv1, ws2f, wd2f,
        o1hi, nullptr, nullptr, asrcB, adstB);

    // --- Layer 2 (commuted): g2 = S2(o1); o2 = tanh(BN(g2@w2 + b2)) ---
    gat_agg8<128, 0, 1, 128><<<NWB, 256, 0, stream>>>(
        o1hi, asrcB, adstB, row_ptr, src_sorted,
        nullptr, nullptr, nullptr, nullptr, nullptr, nullptr, nullptr,
        g2hi, g2lo, nullptr, nullptr, nullptr);
    // n-split (blockIdx.y in {0,1}), NTILES=2: half the accumulator regs,
    // double the blocks vs R10's NTILES=4 (occupancy was 18%).
    mfma_gemm<128, 2, 1, 4, 256, true, false, true><<<dim3(G64, 2), 256, 0, stream>>>(
        g2hi, g2lo, w2th, w2tl, nullptr, nullptr, o2hi, 256,
        b2, g2, be2, rm2, rv2, nullptr, nullptr, N_NODES);

    // --- Layer 3: h3 = o2@w3 (bf16, +alpha3, rows padded to 64); agg3 -> out ---
    mfma_gemm<256, 3, 4, 1, 48, false, true, false><<<G256, 256, 0, stream>>>(
        o2hi, nullptr, w3th, w3tl, ab3h, ab3l, h3hi, 64,
        nullptr, nullptr, nullptr, nullptr, nullptr, asrcA, adstA, N_NODES);
    gat_agg8<40, 1, 2, 64><<<NWB, 256, 0, stream>>>(
        h3hi, asrcA, adstA, row_ptr, src_sorted,
        b3, nullptr, nullptr, nullptr, nullptr, nullptr, nullptr,
        nullptr, nullptr, out, nullptr, nullptr);
}

// Round 13
// 654.321 us; speedup vs baseline: 1.7116x; 1.0852x over previous
//
#include <hip/hip_runtime.h>
#include <hip/hip_bf16.h>
#include <cstddef>

#define N_NODES 100000
#define E_EDGES 1600000
#define TOT_EDGES (E_EDGES + N_NODES)
#define NEG_SLOPE 0.2f
#define BN_EPS 1e-5f
#define NPASS 4
#define PASS_W ((N_NODES + NPASS - 1) / NPASS)

typedef __attribute__((ext_vector_type(8))) short short8;
typedef __attribute__((ext_vector_type(4))) float f32x4;
typedef __attribute__((ext_vector_type(2))) float f32x2;

__device__ __forceinline__ unsigned short f2bf(float f) {
    union { float f; unsigned u; } c; c.f = f;
    unsigned u = c.u;
    u += 0x7fffu + ((u >> 16) & 1u);
    return (unsigned short)(u >> 16);
}
__device__ __forceinline__ float bf2f(unsigned short h) {
    union { unsigned u; float f; } c; c.u = ((unsigned)h) << 16;
    return c.f;
}
__device__ __forceinline__ float bflo(unsigned u) {
    union { unsigned u; float f; } c; c.u = u << 16; return c.f;
}
__device__ __forceinline__ float bfhi(unsigned u) {
    union { unsigned u; float f; } c; c.u = u & 0xffff0000u; return c.f;
}
__device__ __forceinline__ float lrelu(float t) {
    return (t > 0.f) ? t : NEG_SLOPE * t;
}
// fast tanh: 1 - 2/(e^{2x}+1). |err| ~1e-6 absolute; saturates correctly.
__device__ __forceinline__ float tanh_fast(float x) {
    float e = __expf(2.f * x);
    return 1.f - 2.f / (e + 1.f);
}

// ---------------------------------------------------------------------------
// CSR build
// ---------------------------------------------------------------------------

__global__ __launch_bounds__(256) void count_kernel(const int* __restrict__ ei,
                                                    int* __restrict__ counts) {
    int idx = blockIdx.x * blockDim.x + threadIdx.x;
    int stride = gridDim.x * blockDim.x;
    for (int e = idx; e < TOT_EDGES; e += stride) {
        int d = (e < E_EDGES) ? ei[E_EDGES + e] : (e - E_EDGES);
        atomicAdd(&counts[d], 1);
    }
}

__global__ __launch_bounds__(256) void scan_partial(const int* __restrict__ counts,
                                                    int* __restrict__ partials) {
    __shared__ int s[256];
    int t = threadIdx.x;
    int i = blockIdx.x * 256 + t;
    s[t] = (i < N_NODES) ? counts[i] : 0;
    __syncthreads();
    for (int off = 128; off; off >>= 1) {
        if (t < off) s[t] += s[t + off];
        __syncthreads();
    }
    if (t == 0) partials[blockIdx.x] = s[0];
}

__global__ __launch_bounds__(512) void scan_partials_kernel(int* __restrict__ partials, int nb) {
    __shared__ int s[512];
    int t = threadIdx.x;
    int v = (t < nb) ? partials[t] : 0;
    s[t] = v;
    __syncthreads();
    for (int off = 1; off < 512; off <<= 1) {
        int y = (t >= off) ? s[t - off] : 0;
        __syncthreads();
        s[t] += y;
        __syncthreads();
    }
    if (t < nb) partials[t] = s[t] - v;
}

__global__ __launch_bounds__(256) void scan_final(const int* __restrict__ counts,
                                                  const int* __restrict__ partials,
                                                  int* __restrict__ row_ptr,
                                                  int* __restrict__ write_pos) {
    __shared__ int s[256];
    int t = threadIdx.x;
    int i = blockIdx.x * 256 + t;
    int v = (i < N_NODES) ? counts[i] : 0;
    s[t] = v;
    __syncthreads();
    for (int off = 1; off < 256; off <<= 1) {
        int y = (t >= off) ? s[t - off] : 0;
        __syncthreads();
        s[t] += y;
        __syncthreads();
    }
    int excl = s[t] - v;
    int rp = partials[blockIdx.x] + excl;
    if (i <= N_NODES) row_ptr[i] = rp;
    if (i < N_NODES) write_pos[i] = rp;
}

__global__ __launch_bounds__(256) void scatter_pass(const int* __restrict__ ei,
                                                    int* __restrict__ write_pos,
                                                    int* __restrict__ src_sorted,
                                                    int lo, int hi) {
    int idx = blockIdx.x * blockDim.x + threadIdx.x;
    int stride = gridDim.x * blockDim.x;
    for (int e = idx; e < TOT_EDGES; e += stride) {
        int srcv, d;
        if (e < E_EDGES) { srcv = ei[e]; d = ei[E_EDGES + e]; }
        else             { srcv = e - E_EDGES; d = srcv; }
        if (d >= lo && d < hi) {
            int p = atomicAdd(&write_pos[d], 1);
            src_sorted[p] = srcv;
        }
    }
}

// ---------------------------------------------------------------------------
// Conversions. x -> fragment-major split-bf16 planes:
//   addr(row, k) = (k/32)*(N*32) + row*32 + (k%32)
// ---------------------------------------------------------------------------

__global__ __launch_bounds__(256) void xconv_frag(const float* __restrict__ x,
                                                  unsigned short* __restrict__ hi,
                                                  unsigned short* __restrict__ lo) {
    const size_t CSTRIDE = (size_t)N_NODES * 32;
    int idx = blockIdx.x * blockDim.x + threadIdx.x;
    int stride = gridDim.x * blockDim.x;
    const int n = N_NODES * 128;
    for (int i = idx; i < n; i += stride) {
        float v = x[i];
        int row = i >> 7, f = i & 127;
        size_t a = (size_t)(f >> 5) * CSTRIDE + (size_t)row * 32 + (f & 31);
        unsigned short h = f2bf(v);
        hi[a] = h;
        lo[a] = f2bf(v - bf2f(h));
    }
}

__global__ __launch_bounds__(256) void wconv_all(
    const float* __restrict__ w1, const float* __restrict__ w2, const float* __restrict__ w3,
    unsigned short* __restrict__ w1th, unsigned short* __restrict__ w1tl,
    unsigned short* __restrict__ w2th, unsigned short* __restrict__ w2tl,
    unsigned short* __restrict__ w3th, unsigned short* __restrict__ w3tl) {
    const int T1 = 128 * 128, T2 = 256 * 128, T3 = 48 * 256;
    int idx = blockIdx.x * 256 + threadIdx.x;
    float v; unsigned short* th; unsigned short* tl; int o;
    if (idx < T1) {
        int n = idx / 128, k = idx % 128;
        v = w1[k * 128 + n]; th = w1th; tl = w1tl; o = idx;
    } else if (idx < T1 + T2) {
        int i = idx - T1; int n = i / 128, k = i % 128;
        v = w2[k * 256 + n]; th = w2th; tl = w2tl; o = i;
    } else if (idx < T1 + T2 + T3) {
        int i = idx - T1 - T2; int n = i / 256, k = i % 256;
        v = (n < 40) ? w3[k * 40 + n] : 0.f; th = w3th; tl = w3tl; o = i;
    } else return;
    unsigned short h = f2bf(v);
    th[o] = h;
    tl[o] = f2bf(v - bf2f(h));
}

__global__ __launch_bounds__(256) void wav_all(
    const float* __restrict__ w1, const float* __restrict__ as1, const float* __restrict__ ad1,
    const float* __restrict__ w3, const float* __restrict__ as3, const float* __restrict__ ad3,
    const float* __restrict__ w2, const float* __restrict__ as2, const float* __restrict__ ad2,
    unsigned short* __restrict__ ab1h, unsigned short* __restrict__ ab1l,
    unsigned short* __restrict__ ab3h, unsigned short* __restrict__ ab3l,
    float* __restrict__ ws2f, float* __restrict__ wd2f) {
    int idx = blockIdx.x * 256 + threadIdx.x;
    if (idx < 2048) {
        int r = idx / 128, k = idx % 128;
        float v = 0.f;
        if (r < 2) {
            const float* a = r ? ad1 : as1;
            const float* wr = w1 + (size_t)k * 128;
            for (int n = 0; n < 128; n++) v += wr[n] * a[n];
        }
        unsigned short h = f2bf(v);
        ab1h[idx] = h; ab1l[idx] = f2bf(v - bf2f(h));
    } else if (idx < 2048 + 4096) {
        int i = idx - 2048; int r = i / 256, k = i % 256;
        float v = 0.f;
        if (r < 2) {
            const float* a = r ? ad3 : as3;
            const float* wr = w3 + (size_t)k * 40;
            for (int n = 0; n < 40; n++) v += wr[n] * a[n];
        }
        unsigned short h = f2bf(v);
        ab3h[i] = h; ab3l[i] = f2bf(v - bf2f(h));
    } else if (idx < 2048 + 4096 + 256) {
        int i = idx - 2048 - 4096; int r = i / 128, k = i % 128;
        const float* a = r ? ad2 : as2;
        const float* wr = w2 + (size_t)k * 256;
        float v = 0.f;
        for (int n = 0; n < 256; n++) v += wr[n] * a[n];
        if (r == 0) ws2f[k] = v; else wd2f[k] = v;
    }
}

// ---------------------------------------------------------------------------
// Split-bf16 MFMA GEMM. A is FRAGMENT-MAJOR: one A-load = 1 KB contiguous.
// CFRAG: C written fragment-major (for next GEMM's A); else row-major, ldc.
// ---------------------------------------------------------------------------
template<int K, int NTILES, int MWAVES, int NWAVES, int NACT, bool ASPLIT, bool ALPHA, bool BNT, bool CFRAG>
__global__ __launch_bounds__(256) void mfma_gemm(
    const unsigned short* __restrict__ Ahi, const unsigned short* __restrict__ Alo,
    const unsigned short* __restrict__ BThi, const unsigned short* __restrict__ BTlo,
    const unsigned short* __restrict__ ABh, const unsigned short* __restrict__ ABl,
    unsigned short* __restrict__ Chi, int ldc,
    const float* __restrict__ bias, const float* __restrict__ gamma,
    const float* __restrict__ beta, const float* __restrict__ rmean,
    const float* __restrict__ rvar,
    float* __restrict__ asrc, float* __restrict__ adst, int M)
{
    int lane = threadIdx.x & 63;
    int wave = threadIdx.x >> 6;
    int quad = lane >> 4;
    int l16  = lane & 15;
    long mbase = (long)blockIdx.x * (64 * MWAVES) + (long)(wave / NWAVES) * 64;
    int n0 = ((wave % NWAVES) + blockIdx.y * NWAVES) * (NTILES * 16);
    bool aw = ((wave % NWAVES) == 0) && (blockIdx.y == 0);
    const size_t CSTRIDE = (size_t)M * 32;  // fragment chunk stride (u16)

    size_t roff[4];
#pragma unroll
    for (int i = 0; i < 4; i++) {
        long r = mbase + i * 16 + l16;
        if (r > M - 1) r = M - 1;
        roff[i] = (size_t)r * 32 + (size_t)(quad * 8);
    }
    const unsigned short* bh[NTILES]; const unsigned short* bl[NTILES];
#pragma unroll
    for (int j = 0; j < NTILES; j++) {
        long n = n0 + j * 16 + l16;
        bh[j] = BThi + n * K; bl[j] = BTlo + n * K;
    }
    const unsigned short* bah = nullptr; const unsigned short* bal = nullptr;
    if constexpr (ALPHA) { bah = ABh + (size_t)l16 * K; bal = ABl + (size_t)l16 * K; }
    const int ko = quad * 8;

    f32x4 acc[4][NTILES];
    f32x4 acca[4];
#pragma unroll
    for (int i = 0; i < 4; i++) {
        acca[i] = (f32x4){0.f, 0.f, 0.f, 0.f};
#pragma unroll
        for (int j = 0; j < NTILES; j++)
            acc[i][j] = (f32x4){0.f, 0.f, 0.f, 0.f};
    }

    for (int kc = 0; kc < K / 32; kc++) {
        const int k0 = kc * 32;
        const unsigned short* Ah = Ahi + (size_t)kc * CSTRIDE;
        const unsigned short* Al = ASPLIT ? (Alo + (size_t)kc * CSTRIDE) : nullptr;
        short8 vah[4], vall[4], vbh[NTILES], vbl[NTILES];
#pragma unroll
        for (int i = 0; i < 4; i++) {
            vah[i] = *(const short8*)(Ah + roff[i]);
            if constexpr (ASPLIT) vall[i] = *(const short8*)(Al + roff[i]);
        }
#pragma unroll
        for (int j = 0; j < NTILES; j++) {
            vbh[j] = *(const short8*)(bh[j] + k0 + ko);
            vbl[j] = *(const short8*)(bl[j] + k0 + ko);
        }
#pragma unroll
        for (int i = 0; i < 4; i++)
#pragma unroll
            for (int j = 0; j < NTILES; j++) {
                acc[i][j] = __builtin_amdgcn_mfma_f32_16x16x32_bf16(vah[i], vbh[j], acc[i][j], 0, 0, 0);
                acc[i][j] = __builtin_amdgcn_mfma_f32_16x16x32_bf16(vah[i], vbl[j], acc[i][j], 0, 0, 0);
                if constexpr (ASPLIT)
                    acc[i][j] = __builtin_amdgcn_mfma_f32_16x16x32_bf16(vall[i], vbh[j], acc[i][j], 0, 0, 0);
            }
        if constexpr (ALPHA) {
            if (aw) {
                short8 vbah = *(const short8*)(bah + k0 + ko);
                short8 vbal = *(const short8*)(bal + k0 + ko);
#pragma unroll
                for (int i = 0; i < 4; i++) {
                    acca[i] = __builtin_amdgcn_mfma_f32_16x16x32_bf16(vah[i], vbah, acca[i], 0, 0, 0);
                    acca[i] = __builtin_amdgcn_mfma_f32_16x16x32_bf16(vah[i], vbal, acca[i], 0, 0, 0);
                    if constexpr (ASPLIT)
                        acca[i] = __builtin_amdgcn_mfma_f32_16x16x32_bf16(vall[i], vbah, acca[i], 0, 0, 0);
                }
            }
        }
    }

#pragma unroll
    for (int i = 0; i < 4; i++)
#pragma unroll
        for (int j = 0; j < NTILES; j++) {
            int col = n0 + j * 16 + l16;
            float bb = 0.f, rs = 1.f, gg = 1.f, bt = 0.f, rm = 0.f;
            if constexpr (BNT) {
                bb = bias[col]; gg = gamma[col]; bt = beta[col];
                rm = rmean[col]; rs = rsqrtf(rvar[col] + BN_EPS);
            }
#pragma unroll
            for (int r = 0; r < 4; r++) {
                long row = mbase + i * 16 + quad * 4 + r;
                if (row < M && col < NACT) {
                    float v = acc[i][j][r];
                    if constexpr (BNT) v = tanh_fast((v + bb - rm) * rs * gg + bt);
                    if constexpr (CFRAG) {
                        Chi[(size_t)(col >> 5) * CSTRIDE + (size_t)row * 32 + (col & 31)] = f2bf(v);
                    } else {
                        Chi[row * ldc + col] = f2bf(v);
                    }
                }
            }
        }
    if constexpr (ALPHA) {
        if (aw) {
#pragma unroll
            for (int i = 0; i < 4; i++)
#pragma unroll
                for (int r = 0; r < 4; r++) {
                    long row = mbase + i * 16 + quad * 4 + r;
                    if (row < M) {
                        float v = acca[i][r];
                        if (l16 == 0) asrc[row] = v;
                        else if (l16 == 1) adst[row] = v;
                    }
                }
        }
    }
}

// ---------------------------------------------------------------------------
// chunk_gather8: readlane scalar-base gather, unroll-8.
// GIN 0: u32/lane (bf16 pair, row stride LDH u16). GIN 1: u16/lane (stride LDH).
// ---------------------------------------------------------------------------
template<int GIN, int LDH>
__device__ __forceinline__ void chunk_gather8(
    const unsigned short* __restrict__ hbf,
    int sv, int wv, int cnt, int lane, float* acc)
{
    int j = 0;
    for (; j + 8 <= cnt; j += 8) {
        int ss[8], wb[8];
#pragma unroll
        for (int k = 0; k < 8; k++) {
            ss[k] = __builtin_amdgcn_readlane(sv, j + k);
            wb[k] = __builtin_amdgcn_readlane(wv, j + k);
        }
        if constexpr (GIN == 0) {
            unsigned u[8];
#pragma unroll
            for (int k = 0; k < 8; k++)
                u[k] = *reinterpret_cast<const unsigned*>(hbf + (size_t)ss[k] * LDH + lane * 2);
            f32x2* a2 = reinterpret_cast<f32x2*>(acc);
#pragma unroll
            for (int k = 0; k < 8; k++) {
                float ww = __int_as_float(wb[k]);
                *a2 += (f32x2){ww, ww} * (f32x2){bflo(u[k]), bfhi(u[k])};
            }
        } else {
            unsigned short u[8];
#pragma unroll
            for (int k = 0; k < 8; k++)
                u[k] = hbf[(size_t)ss[k] * LDH + lane];
#pragma unroll
            for (int k = 0; k < 8; k++)
                acc[0] += __int_as_float(wb[k]) * bf2f(u[k]);
        }
    }
    for (; j < cnt; j++) {
        int ss = __builtin_amdgcn_readlane(sv, j);
        int wb = __builtin_amdgcn_readlane(wv, j);
        float ww = __int_as_float(wb);
        if constexpr (GIN == 0) {
            unsigned u = *reinterpret_cast<const unsigned*>(hbf + (size_t)ss * LDH + lane * 2);
            acc[0] += ww * bflo(u); acc[1] += ww * bfhi(u);
        } else {
            acc[0] += ww * bf2f(hbf[(size_t)ss * LDH + lane]);
        }
    }
}

// ---------------------------------------------------------------------------
// gat_agg8: fused segment-softmax + gather-aggregate, wave per node.
// OMODE 0: bias+BN+tanh, write o bf16 pairs row-major, fused next alpha dots.
// OMODE 1: raw sum, write bf16-hi FRAGMENT-MAJOR (next GEMM's A)
// OMODE 2: +bias, write fp32 out (F=40)
// ---------------------------------------------------------------------------
template<int F, int GIN, int OMODE, int LDH>
__global__ __launch_bounds__(256) void gat_agg8(
    const unsigned short* __restrict__ hbf,
    const float* __restrict__ asrc, const float* __restrict__ adst,
    const int* __restrict__ row_ptr, const int* __restrict__ src_sorted,
    const float* __restrict__ bias, const float* __restrict__ gamma,
    const float* __restrict__ beta, const float* __restrict__ rmean,
    const float* __restrict__ rvar,
    const float* __restrict__ wsn, const float* __restrict__ wdn,
    unsigned short* __restrict__ ohi,
    float* __restrict__ outf,
    float* __restrict__ asrc_n, float* __restrict__ adst_n)
{
    constexpr int NA = (GIN == 0) ? 2 : 1;
    int wave = threadIdx.x >> 6;
    int lane = threadIdx.x & 63;
    int node = blockIdx.x * 4 + wave;
    if (node >= N_NODES) return;

    int start = row_ptr[node];
    int end = row_ptr[node + 1];
    int deg = end - start;
    float ad = adst[node];

    float acc[NA];
#pragma unroll
    for (int v = 0; v < NA; v++) acc[v] = 0.f;

    if (deg <= 64) {
        int e = start + lane;
        int s = 0; float l = -1e30f;
        if (e < end) { s = src_sorted[e]; l = lrelu(asrc[s] + ad); }
        float m = l;
#pragma unroll
        for (int off = 32; off; off >>= 1) m = fmaxf(m, __shfl_xor(m, off));
        float pr = (e < end) ? __expf(l - m) : 0.f;
        float d = pr;
#pragma unroll
        for (int off = 32; off; off >>= 1) d += __shfl_xor(d, off);
        int wv = __float_as_int(pr / d);
        chunk_gather8<GIN, LDH>(hbf, s, wv, deg, lane, acc);
    } else {
        float m = -1e30f, d = 0.f;
        for (int cs = start; cs < end; cs += 64) {
            int e = cs + lane;
            float l = -1e30f;
            if (e < end) { int s = src_sorted[e]; l = lrelu(asrc[s] + ad); }
            float cm = l;
#pragma unroll
            for (int off = 32; off; off >>= 1) cm = fmaxf(cm, __shfl_xor(cm, off));
            float nm = fmaxf(m, cm);
            float cp = (e < end) ? __expf(l - nm) : 0.f;
#pragma unroll
            for (int off = 32; off; off >>= 1) cp += __shfl_xor(cp, off);
            d = d * __expf(m - nm) + cp;
            m = nm;
        }
        float inv = 1.0f / d;
        for (int cs = start; cs < end; cs += 64) {
            int e = cs + lane;
            int s = 0, wv = 0;
            if (e < end) {
                s = src_sorted[e];
                float l = lrelu(asrc[s] + ad);
                wv = __float_as_int(__expf(l - m) * inv);
            }
            chunk_gather8<GIN, LDH>(hbf, s, wv, min(64, end - cs), lane, acc);
        }
    }

    if constexpr (OMODE == 0) {
        float vals[2];
#pragma unroll
        for (int v = 0; v < 2; v++) {
            int f = lane * 2 + v;
            float val = acc[v] + bias[f];
            float rs = rsqrtf(rvar[f] + BN_EPS);
            vals[v] = tanh_fast((val - rmean[f]) * rs * gamma[f] + beta[f]);
        }
        unsigned w0 = (unsigned)f2bf(vals[0]) | ((unsigned)f2bf(vals[1]) << 16);
        *reinterpret_cast<unsigned*>(ohi + (size_t)node * F + lane * 2) = w0;
        float ps = vals[0] * wsn[lane * 2] + vals[1] * wsn[lane * 2 + 1];
        float pd = vals[0] * wdn[lane * 2] + vals[1] * wdn[lane * 2 + 1];
#pragma unroll
        for (int off = 32; off; off >>= 1) {
            ps += __shfl_xor(ps, off);
            pd += __shfl_xor(pd, off);
        }
        if (lane == 0) { asrc_n[node] = ps; adst_n[node] = pd; }
    } else if constexpr (OMODE == 1) {
        // fragment-major bf16-hi write: chunk = lane/16, within = (lane*2)%32
        const size_t CSTRIDE = (size_t)N_NODES * 32;
        unsigned w0 = (unsigned)f2bf(acc[0]) | ((unsigned)f2bf(acc[1]) << 16);
        size_t a = (size_t)(lane >> 4) * CSTRIDE + (size_t)node * 32 + ((lane * 2) & 31);
        *reinterpret_cast<unsigned*>(ohi + a) = w0;
    } else {
        if (lane < F) outf[(size_t)node * F + lane] = acc[0] + bias[lane];
    }
}

// ---------------------------------------------------------------------------

static inline size_t align256(size_t x) { return (x + 255) & ~(size_t)255; }

extern "C" void kernel_launch(void* const* d_in, const int* in_sizes, int n_in,
                              void* d_out, int out_size, void* d_ws, size_t ws_size,
                              hipStream_t stream) {
    const float* x   = (const float*)d_in[0];
    const int* ei    = (const int*)d_in[1];
    const float* w1  = (const float*)d_in[2];
    const float* as1 = (const float*)d_in[3];
    const float* ad1 = (const float*)d_in[4];
    const float* b1  = (const float*)d_in[5];
    const float* g1  = (const float*)d_in[6];
    const float* be1 = (const float*)d_in[7];
    const float* rm1 = (const float*)d_in[8];
    const float* rv1 = (const float*)d_in[9];
    const float* w2  = (const float*)d_in[10];
    const float* as2 = (const float*)d_in[11];
    const float* ad2 = (const float*)d_in[12];
    const float* b2  = (const float*)d_in[13];
    const float* g2  = (const float*)d_in[14];
    const float* be2 = (const float*)d_in[15];
    const float* rm2 = (const float*)d_in[16];
    const float* rv2 = (const float*)d_in[17];
    const float* w3  = (const float*)d_in[18];
    const float* as3 = (const float*)d_in[19];
    const float* ad3 = (const float*)d_in[20];
    const float* b3  = (const float*)d_in[21];
    float* out = (float*)d_out;

    const size_t P128 = align256((size_t)N_NODES * 128 * 2);
    const size_t P256 = align256((size_t)N_NODES * 256 * 2);

    char* p = (char*)d_ws;
    // regA: xhi|xlo (fragment) -> o1hi (front, row-major) -> o2hi (full, fragment)
    char* regA = p; p += P256;
    // regB: h1hi (front, row-major) -> g2hi (front, fragment) -> h3hi (front, ldh=64)
    char* regB = p; p += P256;
    unsigned short* xhi  = (unsigned short*)regA;
    unsigned short* xlo  = (unsigned short*)(regA + P128);
    unsigned short* o1hi = (unsigned short*)regA;
    unsigned short* o2hi = (unsigned short*)regA;
    unsigned short* h1hi = (unsigned short*)regB;
    unsigned short* g2hi = (unsigned short*)regB;
    unsigned short* h3hi = (unsigned short*)regB;  // N*64 u16 padded rows

    float* asrcA = (float*)p; p += align256((size_t)N_NODES * 4);
    float* adstA = (float*)p; p += align256((size_t)N_NODES * 4);
    float* asrcB = (float*)p; p += align256((size_t)N_NODES * 4);
    float* adstB = (float*)p; p += align256((size_t)N_NODES * 4);
    int* counts    = (int*)p; p += align256((size_t)N_NODES * 4);
    int* row_ptr   = (int*)p; p += align256((size_t)(N_NODES + 1) * 4);
    int* write_pos = (int*)p; p += align256((size_t)N_NODES * 4);
    int* src_sorted = (int*)p; p += align256((size_t)TOT_EDGES * 4);
    int* partials  = (int*)p;  p += align256(512 * 4);
    unsigned short* w1th = (unsigned short*)p; p += align256(128 * 128 * 2);
    unsigned short* w1tl = (unsigned short*)p; p += align256(128 * 128 * 2);
    unsigned short* w2th = (unsigned short*)p; p += align256(256 * 128 * 2);
    unsigned short* w2tl = (unsigned short*)p; p += align256(256 * 128 * 2);
    unsigned short* w3th = (unsigned short*)p; p += align256(48 * 256 * 2);
    unsigned short* w3tl = (unsigned short*)p; p += align256(48 * 256 * 2);
    unsigned short* ab1h = (unsigned short*)p; p += align256(16 * 128 * 2);
    unsigned short* ab1l = (unsigned short*)p; p += align256(16 * 128 * 2);
    unsigned short* ab3h = (unsigned short*)p; p += align256(16 * 256 * 2);
    unsigned short* ab3l = (unsigned short*)p; p += align256(16 * 256 * 2);
    float* ws2f = (float*)p; p += align256(128 * 4);
    float* wd2f = (float*)p; p += align256(128 * 4);

    const int NB = (N_NODES + 255) / 256;
    const int WTOT = 128 * 128 + 256 * 128 + 48 * 256;

    xconv_frag<<<4096, 256, 0, stream>>>(x, xhi, xlo);
    wconv_all<<<(WTOT + 255) / 256, 256, 0, stream>>>(w1, w2, w3, w1th, w1tl,
                                                      w2th, w2tl, w3th, w3tl);
    wav_all<<<(2048 + 4096 + 256 + 255) / 256, 256, 0, stream>>>(
        w1, as1, ad1, w3, as3, ad3, w2, as2, ad2,
        ab1h, ab1l, ab3h, ab3l, ws2f, wd2f);

    hipMemsetAsync(counts, 0, (size_t)N_NODES * 4, stream);
    count_kernel<<<4096, 256, 0, stream>>>(ei, counts);
    scan_partial<<<NB, 256, 0, stream>>>(counts, partials);
    scan_partials_kernel<<<1, 512, 0, stream>>>(partials, NB);
    scan_final<<<NB, 256, 0, stream>>>(counts, partials, row_ptr, write_pos);
    for (int ps = 0; ps < NPASS; ps++)
        scatter_pass<<<2048, 256, 0, stream>>>(ei, write_pos, src_sorted,
                                               ps * PASS_W, (ps + 1) * PASS_W);

    const int NWB = (N_NODES + 3) / 4;
    const int G64 = (N_NODES + 63) / 64;
    const int G256 = (N_NODES + 255) / 256;

    // --- Layer 1: h1 = x@w1 (+alpha1), A fragment-major; agg1 -> o1 row-major ---
    mfma_gemm<128, 2, 1, 4, 128, true, true, false, false><<<G64, 256, 0, stream>>>(
        xhi, xlo, w1th, w1tl, ab1h, ab1l, h1hi, 128,
        nullptr, nullptr, nullptr, nullptr, nullptr, asrcA, adstA, N_NODES);
    gat_agg8<128, 0, 0, 128><<<NWB, 256, 0, stream>>>(
        h1hi, asrcA, adstA, row_ptr, src_sorted,
        b1, g1, be1, rm1, rv1, ws2f, wd2f,
        o1hi, nullptr, asrcB, adstB);

    // --- Layer 2 (commuted): g2 = S2(o1) -> fragment-major hi-only;
    //     o2 = tanh(BN(g2@w2 + b2)) -> fragment-major (GEMM3's A) ---
    gat_agg8<128, 0, 1, 128><<<NWB, 256, 0, stream>>>(
        o1hi, asrcB, adstB, row_ptr, src_sorted,
        nullptr, nullptr, nullptr, nullptr, nullptr, nullptr, nullptr,
        g2hi, nullptr, nullptr, nullptr);
    mfma_gemm<128, 2, 1, 4, 256, false, false, true, true><<<dim3(G64, 2), 256, 0, stream>>>(
        g2hi, nullptr, w2th, w2tl, nullptr, nullptr, o2hi, 256,
        b2, g2, be2, rm2, rv2, nullptr, nullptr, N_NODES);

    // --- Layer 3: h3 = o2@w3 (A fragment, +alpha3, C row-major ldh=64); agg3 -> out ---
    mfma_gemm<256, 3, 4, 1, 48, false, true, false, false><<<G256, 256, 0, stream>>>(
        o2hi, nullptr, w3th, w3tl, ab3h, ab3l, h3hi, 64,
        nullptr, nullptr, nullptr, nullptr, nullptr, asrcA, adstA, N_NODES);
    gat_agg8<40, 1, 2, 64><<<NWB, 256, 0, stream>>>(
        h3hi, asrcA, adstA, row_ptr, src_sorted,
        b3, nullptr, nullptr, nullptr, nullptr, nullptr, nullptr,
        nullptr, out, nullptr, nullptr);
}

// Round 14
// 642.666 us; speedup vs baseline: 1.7426x; 1.0181x over previous
//
#include <hip/hip_runtime.h>
#include <hip/hip_bf16.h>
#include <cstddef>

#define N_NODES 100000
#define E_EDGES 1600000
#define TOT_EDGES (E_EDGES + N_NODES)
#define NEG_SLOPE 0.2f
#define BN_EPS 1e-5f
#define NPASS 4
#define PASS_W ((N_NODES + NPASS - 1) / NPASS)

typedef __attribute__((ext_vector_type(8))) short short8;
typedef __attribute__((ext_vector_type(4))) float f32x4;
typedef __attribute__((ext_vector_type(2))) float f32x2;

__device__ __forceinline__ unsigned short f2bf(float f) {
    union { float f; unsigned u; } c; c.f = f;
    unsigned u = c.u;
    u += 0x7fffu + ((u >> 16) & 1u);
    return (unsigned short)(u >> 16);
}
__device__ __forceinline__ float bf2f(unsigned short h) {
    union { unsigned u; float f; } c; c.u = ((unsigned)h) << 16;
    return c.f;
}
__device__ __forceinline__ float bflo(unsigned u) {
    union { unsigned u; float f; } c; c.u = u << 16; return c.f;
}
__device__ __forceinline__ float bfhi(unsigned u) {
    union { unsigned u; float f; } c; c.u = u & 0xffff0000u; return c.f;
}
__device__ __forceinline__ float lrelu(float t) {
    return (t > 0.f) ? t : NEG_SLOPE * t;
}
// fast tanh: 1 - 2/(e^{2x}+1). |err| ~1e-6 absolute; saturates correctly.
__device__ __forceinline__ float tanh_fast(float x) {
    float e = __expf(2.f * x);
    return 1.f - 2.f / (e + 1.f);
}
// HW fp8 (e4m3 on gfx950) pack/unpack via inline asm — self-consistent
// roundtrip (encode and decode use the same HW interpretation).
__device__ __forceinline__ unsigned short pk_fp8(float a, float b) {
    unsigned v;
    asm volatile("v_cvt_pk_fp8_f32 %0, %1, %2" : "=v"(v) : "v"(a), "v"(b));
    return (unsigned short)v;
}
__device__ __forceinline__ f32x2 unpk_fp8(unsigned u) {
    f32x2 r;
    asm volatile("v_cvt_pk_f32_fp8 %0, %1" : "=v"(r) : "v"(u));
    return r;
}

// ---------------------------------------------------------------------------
// CSR build
// ---------------------------------------------------------------------------

__global__ __launch_bounds__(256) void count_kernel(const int* __restrict__ ei,
                                                    int* __restrict__ counts) {
    int idx = blockIdx.x * blockDim.x + threadIdx.x;
    int stride = gridDim.x * blockDim.x;
    for (int e = idx; e < TOT_EDGES; e += stride) {
        int d = (e < E_EDGES) ? ei[E_EDGES + e] : (e - E_EDGES);
        atomicAdd(&counts[d], 1);
    }
}

__global__ __launch_bounds__(256) void scan_partial(const int* __restrict__ counts,
                                                    int* __restrict__ partials) {
    __shared__ int s[256];
    int t = threadIdx.x;
    int i = blockIdx.x * 256 + t;
    s[t] = (i < N_NODES) ? counts[i] : 0;
    __syncthreads();
    for (int off = 128; off; off >>= 1) {
        if (t < off) s[t] += s[t + off];
        __syncthreads();
    }
    if (t == 0) partials[blockIdx.x] = s[0];
}

__global__ __launch_bounds__(512) void scan_partials_kernel(int* __restrict__ partials, int nb) {
    __shared__ int s[512];
    int t = threadIdx.x;
    int v = (t < nb) ? partials[t] : 0;
    s[t] = v;
    __syncthreads();
    for (int off = 1; off < 512; off <<= 1) {
        int y = (t >= off) ? s[t - off] : 0;
        __syncthreads();
        s[t] += y;
        __syncthreads();
    }
    if (t < nb) partials[t] = s[t] - v;
}

__global__ __launch_bounds__(256) void scan_final(const int* __restrict__ counts,
                                                  const int* __restrict__ partials,
                                                  int* __restrict__ row_ptr,
                                                  int* __restrict__ write_pos) {
    __shared__ int s[256];
    int t = threadIdx.x;
    int i = blockIdx.x * 256 + t;
    int v = (i < N_NODES) ? counts[i] : 0;
    s[t] = v;
    __syncthreads();
    for (int off = 1; off < 256; off <<= 1) {
        int y = (t >= off) ? s[t - off] : 0;
        __syncthreads();
        s[t] += y;
        __syncthreads();
    }
    int excl = s[t] - v;
    int rp = partials[blockIdx.x] + excl;
    if (i <= N_NODES) row_ptr[i] = rp;
    if (i < N_NODES) write_pos[i] = rp;
}

__global__ __launch_bounds__(256) void scatter_pass(const int* __restrict__ ei,
                                                    int* __restrict__ write_pos,
                                                    int* __restrict__ src_sorted,
                                                    int lo, int hi) {
    int idx = blockIdx.x * blockDim.x + threadIdx.x;
    int stride = gridDim.x * blockDim.x;
    for (int e = idx; e < TOT_EDGES; e += stride) {
        int srcv, d;
        if (e < E_EDGES) { srcv = ei[e]; d = ei[E_EDGES + e]; }
        else             { srcv = e - E_EDGES; d = srcv; }
        if (d >= lo && d < hi) {
            int p = atomicAdd(&write_pos[d], 1);
            src_sorted[p] = srcv;
        }
    }
}

// ---------------------------------------------------------------------------
// Conversions. x -> fragment-major split-bf16 planes:
//   addr(row, k) = (k/32)*(N*32) + row*32 + (k%32)
// ---------------------------------------------------------------------------

__global__ __launch_bounds__(256) void xconv_frag(const float* __restrict__ x,
                                                  unsigned short* __restrict__ hi,
                                                  unsigned short* __restrict__ lo) {
    const size_t CSTRIDE = (size_t)N_NODES * 32;
    int idx = blockIdx.x * blockDim.x + threadIdx.x;
    int stride = gridDim.x * blockDim.x;
    const int n = N_NODES * 128;
    for (int i = idx; i < n; i += stride) {
        float v = x[i];
        int row = i >> 7, f = i & 127;
        size_t a = (size_t)(f >> 5) * CSTRIDE + (size_t)row * 32 + (f & 31);
        unsigned short h = f2bf(v);
        hi[a] = h;
        lo[a] = f2bf(v - bf2f(h));
    }
}

// weight transposes + alpha vectors, one launch
__global__ __launch_bounds__(256) void wprep_all(
    const float* __restrict__ w1, const float* __restrict__ w2, const float* __restrict__ w3,
    const float* __restrict__ as1, const float* __restrict__ ad1,
    const float* __restrict__ as2, const float* __restrict__ ad2,
    const float* __restrict__ as3, const float* __restrict__ ad3,
    unsigned short* __restrict__ w1th, unsigned short* __restrict__ w1tl,
    unsigned short* __restrict__ w2th, unsigned short* __restrict__ w2tl,
    unsigned short* __restrict__ w3th, unsigned short* __restrict__ w3tl,
    unsigned short* __restrict__ ab1h, unsigned short* __restrict__ ab1l,
    unsigned short* __restrict__ ab3h, unsigned short* __restrict__ ab3l,
    float* __restrict__ ws2f, float* __restrict__ wd2f) {
    const int T1 = 128 * 128, T2 = 256 * 128, T3 = 48 * 256;
    const int W = T1 + T2 + T3;
    int idx = blockIdx.x * 256 + threadIdx.x;
    if (idx < W) {
        float v; unsigned short* th; unsigned short* tl; int o;
        if (idx < T1) {
            int n = idx / 128, k = idx % 128;
            v = w1[k * 128 + n]; th = w1th; tl = w1tl; o = idx;
        } else if (idx < T1 + T2) {
            int i = idx - T1; int n = i / 128, k = i % 128;
            v = w2[k * 256 + n]; th = w2th; tl = w2tl; o = i;
        } else {
            int i = idx - T1 - T2; int n = i / 256, k = i % 256;
            v = (n < 40) ? w3[k * 40 + n] : 0.f; th = w3th; tl = w3tl; o = i;
        }
        unsigned short h = f2bf(v);
        th[o] = h;
        tl[o] = f2bf(v - bf2f(h));
        return;
    }
    int j = idx - W;
    if (j < 2048) {
        int r = j / 128, k = j % 128;
        float v = 0.f;
        if (r < 2) {
            const float* a = r ? ad1 : as1;
            const float* wr = w1 + (size_t)k * 128;
            for (int n = 0; n < 128; n++) v += wr[n] * a[n];
        }
        unsigned short h = f2bf(v);
        ab1h[j] = h; ab1l[j] = f2bf(v - bf2f(h));
    } else if (j < 2048 + 4096) {
        int i = j - 2048; int r = i / 256, k = i % 256;
        float v = 0.f;
        if (r < 2) {
            const float* a = r ? ad3 : as3;
            const float* wr = w3 + (size_t)k * 40;
            for (int n = 0; n < 40; n++) v += wr[n] * a[n];
        }
        unsigned short h = f2bf(v);
        ab3h[i] = h; ab3l[i] = f2bf(v - bf2f(h));
    } else if (j < 2048 + 4096 + 256) {
        int i = j - 2048 - 4096; int r = i / 128, k = i % 128;
        const float* a = r ? ad2 : as2;
        const float* wr = w2 + (size_t)k * 256;
        float v = 0.f;
        for (int n = 0; n < 256; n++) v += wr[n] * a[n];
        if (r == 0) ws2f[k] = v; else wd2f[k] = v;
    }
}

// ---------------------------------------------------------------------------
// Split-bf16 MFMA GEMM. A is FRAGMENT-MAJOR: one A-load = 1 KB contiguous.
// CFRAG: C written fragment-major (for next GEMM's A); else row-major, ldc.
// ---------------------------------------------------------------------------
template<int K, int NTILES, int MWAVES, int NWAVES, int NACT, bool ASPLIT, bool ALPHA, bool BNT, bool CFRAG>
__global__ __launch_bounds__(256) void mfma_gemm(
    const unsigned short* __restrict__ Ahi, const unsigned short* __restrict__ Alo,
    const unsigned short* __restrict__ BThi, const unsigned short* __restrict__ BTlo,
    const unsigned short* __restrict__ ABh, const unsigned short* __restrict__ ABl,
    unsigned short* __restrict__ Chi, int ldc,
    const float* __restrict__ bias, const float* __restrict__ gamma,
    const float* __restrict__ beta, const float* __restrict__ rmean,
    const float* __restrict__ rvar,
    float* __restrict__ asrc, float* __restrict__ adst, int M)
{
    int lane = threadIdx.x & 63;
    int wave = threadIdx.x >> 6;
    int quad = lane >> 4;
    int l16  = lane & 15;
    long mbase = (long)blockIdx.x * (64 * MWAVES) + (long)(wave / NWAVES) * 64;
    int n0 = ((wave % NWAVES) + blockIdx.y * NWAVES) * (NTILES * 16);
    bool aw = ((wave % NWAVES) == 0) && (blockIdx.y == 0);
    const size_t CSTRIDE = (size_t)M * 32;  // fragment chunk stride (u16)

    size_t roff[4];
#pragma unroll
    for (int i = 0; i < 4; i++) {
        long r = mbase + i * 16 + l16;
        if (r > M - 1) r = M - 1;
        roff[i] = (size_t)r * 32 + (size_t)(quad * 8);
    }
    const unsigned short* bh[NTILES]; const unsigned short* bl[NTILES];
#pragma unroll
    for (int j = 0; j < NTILES; j++) {
        long n = n0 + j * 16 + l16;
        bh[j] = BThi + n * K; bl[j] = BTlo + n * K;
    }
    const unsigned short* bah = nullptr; const unsigned short* bal = nullptr;
    if constexpr (ALPHA) { bah = ABh + (size_t)l16 * K; bal = ABl + (size_t)l16 * K; }
    const int ko = quad * 8;

    f32x4 acc[4][NTILES];
    f32x4 acca[4];
#pragma unroll
    for (int i = 0; i < 4; i++) {
        acca[i] = (f32x4){0.f, 0.f, 0.f, 0.f};
#pragma unroll
        for (int j = 0; j < NTILES; j++)
            acc[i][j] = (f32x4){0.f, 0.f, 0.f, 0.f};
    }

    for (int kc = 0; kc < K / 32; kc++) {
        const int k0 = kc * 32;
        const unsigned short* Ah = Ahi + (size_t)kc * CSTRIDE;
        const unsigned short* Al = ASPLIT ? (Alo + (size_t)kc * CSTRIDE) : nullptr;
        short8 vah[4], vall[4], vbh[NTILES], vbl[NTILES];
#pragma unroll
        for (int i = 0; i < 4; i++) {
            vah[i] = *(const short8*)(Ah + roff[i]);
            if constexpr (ASPLIT) vall[i] = *(const short8*)(Al + roff[i]);
        }
#pragma unroll
        for (int j = 0; j < NTILES; j++) {
            vbh[j] = *(const short8*)(bh[j] + k0 + ko);
            vbl[j] = *(const short8*)(bl[j] + k0 + ko);
        }
#pragma unroll
        for (int i = 0; i < 4; i++)
#pragma unroll
            for (int j = 0; j < NTILES; j++) {
                acc[i][j] = __builtin_amdgcn_mfma_f32_16x16x32_bf16(vah[i], vbh[j], acc[i][j], 0, 0, 0);
                acc[i][j] = __builtin_amdgcn_mfma_f32_16x16x32_bf16(vah[i], vbl[j], acc[i][j], 0, 0, 0);
                if constexpr (ASPLIT)
                    acc[i][j] = __builtin_amdgcn_mfma_f32_16x16x32_bf16(vall[i], vbh[j], acc[i][j], 0, 0, 0);
            }
        if constexpr (ALPHA) {
            if (aw) {
                short8 vbah = *(const short8*)(bah + k0 + ko);
                short8 vbal = *(const short8*)(bal + k0 + ko);
#pragma unroll
                for (int i = 0; i < 4; i++) {
                    acca[i] = __builtin_amdgcn_mfma_f32_16x16x32_bf16(vah[i], vbah, acca[i], 0, 0, 0);
                    acca[i] = __builtin_amdgcn_mfma_f32_16x16x32_bf16(vah[i], vbal, acca[i], 0, 0, 0);
                    if constexpr (ASPLIT)
                        acca[i] = __builtin_amdgcn_mfma_f32_16x16x32_bf16(vall[i], vbah, acca[i], 0, 0, 0);
                }
            }
        }
    }

#pragma unroll
    for (int i = 0; i < 4; i++)
#pragma unroll
        for (int j = 0; j < NTILES; j++) {
            int col = n0 + j * 16 + l16;
            float bb = 0.f, rs = 1.f, gg = 1.f, bt = 0.f, rm = 0.f;
            if constexpr (BNT) {
                bb = bias[col]; gg = gamma[col]; bt = beta[col];
                rm = rmean[col]; rs = rsqrtf(rvar[col] + BN_EPS);
            }
#pragma unroll
            for (int r = 0; r < 4; r++) {
                long row = mbase + i * 16 + quad * 4 + r;
                if (row < M && col < NACT) {
                    float v = acc[i][j][r];
                    if constexpr (BNT) v = tanh_fast((v + bb - rm) * rs * gg + bt);
                    if constexpr (CFRAG) {
                        Chi[(size_t)(col >> 5) * CSTRIDE + (size_t)row * 32 + (col & 31)] = f2bf(v);
                    } else {
                        Chi[row * ldc + col] = f2bf(v);
                    }
                }
            }
        }
    if constexpr (ALPHA) {
        if (aw) {
#pragma unroll
            for (int i = 0; i < 4; i++)
#pragma unroll
                for (int r = 0; r < 4; r++) {
                    long row = mbase + i * 16 + quad * 4 + r;
                    if (row < M) {
                        float v = acca[i][r];
                        if (l16 == 0) asrc[row] = v;
                        else if (l16 == 1) adst[row] = v;
                    }
                }
        }
    }
}

// ---------------------------------------------------------------------------
// chunk_gather8: readlane scalar-base gather, unroll-8.
// GIN 0: u32/lane bf16 pair (stride LDH u16).
// GIN 1: u16/lane bf16 (stride LDH).
// GIN 2: u16/lane fp8 pair, HW cvt (stride LDH u16).
// ---------------------------------------------------------------------------
template<int GIN, int LDH>
__device__ __forceinline__ void chunk_gather8(
    const unsigned short* __restrict__ hbf,
    int sv, int wv, int cnt, int lane, float* acc)
{
    int j = 0;
    for (; j + 8 <= cnt; j += 8) {
        int ss[8], wb[8];
#pragma unroll
        for (int k = 0; k < 8; k++) {
            ss[k] = __builtin_amdgcn_readlane(sv, j + k);
            wb[k] = __builtin_amdgcn_readlane(wv, j + k);
        }
        if constexpr (GIN == 0) {
            unsigned u[8];
#pragma unroll
            for (int k = 0; k < 8; k++)
                u[k] = *reinterpret_cast<const unsigned*>(hbf + (size_t)ss[k] * LDH + lane * 2);
            f32x2* a2 = reinterpret_cast<f32x2*>(acc);
#pragma unroll
            for (int k = 0; k < 8; k++) {
                float ww = __int_as_float(wb[k]);
                *a2 += (f32x2){ww, ww} * (f32x2){bflo(u[k]), bfhi(u[k])};
            }
        } else if constexpr (GIN == 1) {
            unsigned short u[8];
#pragma unroll
            for (int k = 0; k < 8; k++)
                u[k] = hbf[(size_t)ss[k] * LDH + lane];
#pragma unroll
            for (int k = 0; k < 8; k++)
                acc[0] += __int_as_float(wb[k]) * bf2f(u[k]);
        } else {
            unsigned short u[8];
#pragma unroll
            for (int k = 0; k < 8; k++)
                u[k] = hbf[(size_t)ss[k] * LDH + lane];
            f32x2* a2 = reinterpret_cast<f32x2*>(acc);
#pragma unroll
            for (int k = 0; k < 8; k++) {
                float ww = __int_as_float(wb[k]);
                *a2 += (f32x2){ww, ww} * unpk_fp8((unsigned)u[k]);
            }
        }
    }
    for (; j < cnt; j++) {
        int ss = __builtin_amdgcn_readlane(sv, j);
        int wb = __builtin_amdgcn_readlane(wv, j);
        float ww = __int_as_float(wb);
        if constexpr (GIN == 0) {
            unsigned u = *reinterpret_cast<const unsigned*>(hbf + (size_t)ss * LDH + lane * 2);
            acc[0] += ww * bflo(u); acc[1] += ww * bfhi(u);
        } else if constexpr (GIN == 1) {
            acc[0] += ww * bf2f(hbf[(size_t)ss * LDH + lane]);
        } else {
            f32x2 v = unpk_fp8((unsigned)hbf[(size_t)ss * LDH + lane]);
            acc[0] += ww * v.x; acc[1] += ww * v.y;
        }
    }
}

// ---------------------------------------------------------------------------
// gat_agg8: fused segment-softmax + gather-aggregate, wave per node.
// OMODE 0: bias+BN+tanh, write o (fp8 pairs if OF8 else bf16 pairs row-major),
//          fused next-layer alpha dots.
// OMODE 1: raw sum, write bf16-hi FRAGMENT-MAJOR (next GEMM's A)
// OMODE 2: +bias, write fp32 out (F=40)
// ---------------------------------------------------------------------------
template<int F, int GIN, int OMODE, int LDH, bool OF8>
__global__ __launch_bounds__(256) void gat_agg8(
    const unsigned short* __restrict__ hbf,
    const float* __restrict__ asrc, const float* __restrict__ adst,
    const int* __restrict__ row_ptr, const int* __restrict__ src_sorted,
    const float* __restrict__ bias, const float* __restrict__ gamma,
    const float* __restrict__ beta, const float* __restrict__ rmean,
    const float* __restrict__ rvar,
    const float* __restrict__ wsn, const float* __restrict__ wdn,
    unsigned short* __restrict__ ohi,
    float* __restrict__ outf,
    float* __restrict__ asrc_n, float* __restrict__ adst_n)
{
    constexpr int NA = (GIN == 1) ? 1 : 2;
    int wave = threadIdx.x >> 6;
    int lane = threadIdx.x & 63;
    int node = blockIdx.x * 4 + wave;
    if (node >= N_NODES) return;

    int start = row_ptr[node];
    int end = row_ptr[node + 1];
    int deg = end - start;
    float ad = adst[node];

    float acc[NA];
#pragma unroll
    for (int v = 0; v < NA; v++) acc[v] = 0.f;

    if (deg <= 64) {
        int e = start + lane;
        int s = 0; float l = -1e30f;
        if (e < end) { s = src_sorted[e]; l = lrelu(asrc[s] + ad); }
        float m = l;
#pragma unroll
        for (int off = 32; off; off >>= 1) m = fmaxf(m, __shfl_xor(m, off));
        float pr = (e < end) ? __expf(l - m) : 0.f;
        float d = pr;
#pragma unroll
        for (int off = 32; off; off >>= 1) d += __shfl_xor(d, off);
        int wv = __float_as_int(pr / d);
        chunk_gather8<GIN, LDH>(hbf, s, wv, deg, lane, acc);
    } else {
        float m = -1e30f, d = 0.f;
        for (int cs = start; cs < end; cs += 64) {
            int e = cs + lane;
            float l = -1e30f;
            if (e < end) { int s = src_sorted[e]; l = lrelu(asrc[s] + ad); }
            float cm = l;
#pragma unroll
            for (int off = 32; off; off >>= 1) cm = fmaxf(cm, __shfl_xor(cm, off));
            float nm = fmaxf(m, cm);
            float cp = (e < end) ? __expf(l - nm) : 0.f;
#pragma unroll
            for (int off = 32; off; off >>= 1) cp += __shfl_xor(cp, off);
            d = d * __expf(m - nm) + cp;
            m = nm;
        }
        float inv = 1.0f / d;
        for (int cs = start; cs < end; cs += 64) {
            int e = cs + lane;
            int s = 0, wv = 0;
            if (e < end) {
                s = src_sorted[e];
                float l = lrelu(asrc[s] + ad);
                wv = __float_as_int(__expf(l - m) * inv);
            }
            chunk_gather8<GIN, LDH>(hbf, s, wv, min(64, end - cs), lane, acc);
        }
    }

    if constexpr (OMODE == 0) {
        float vals[2];
#pragma unroll
        for (int v = 0; v < 2; v++) {
            int f = lane * 2 + v;
            float val = acc[v] + bias[f];
            float rs = rsqrtf(rvar[f] + BN_EPS);
            vals[v] = tanh_fast((val - rmean[f]) * rs * gamma[f] + beta[f]);
        }
        if constexpr (OF8) {
            ohi[(size_t)node * (F / 2) + lane] = pk_fp8(vals[0], vals[1]);
        } else {
            unsigned w0 = (unsigned)f2bf(vals[0]) | ((unsigned)f2bf(vals[1]) << 16);
            *reinterpret_cast<unsigned*>(ohi + (size_t)node * F + lane * 2) = w0;
        }
        float ps = vals[0] * wsn[lane * 2] + vals[1] * wsn[lane * 2 + 1];
        float pd = vals[0] * wdn[lane * 2] + vals[1] * wdn[lane * 2 + 1];
#pragma unroll
        for (int off = 32; off; off >>= 1) {
            ps += __shfl_xor(ps, off);
            pd += __shfl_xor(pd, off);
        }
        if (lane == 0) { asrc_n[node] = ps; adst_n[node] = pd; }
    } else if constexpr (OMODE == 1) {
        // fragment-major bf16-hi write: chunk = lane/16, within = (lane*2)%32
        const size_t CSTRIDE = (size_t)N_NODES * 32;
        unsigned w0 = (unsigned)f2bf(acc[0]) | ((unsigned)f2bf(acc[1]) << 16);
        size_t a = (size_t)(lane >> 4) * CSTRIDE + (size_t)node * 32 + ((lane * 2) & 31);
        *reinterpret_cast<unsigned*>(ohi + a) = w0;
    } else {
        if (lane < F) outf[(size_t)node * F + lane] = acc[0] + bias[lane];
    }
}

// ---------------------------------------------------------------------------

static inline size_t align256(size_t x) { return (x + 255) & ~(size_t)255; }

extern "C" void kernel_launch(void* const* d_in, const int* in_sizes, int n_in,
                              void* d_out, int out_size, void* d_ws, size_t ws_size,
                              hipStream_t stream) {
    const float* x   = (const float*)d_in[0];
    const int* ei    = (const int*)d_in[1];
    const float* w1  = (const float*)d_in[2];
    const float* as1 = (const float*)d_in[3];
    const float* ad1 = (const float*)d_in[4];
    const float* b1  = (const float*)d_in[5];
    const float* g1  = (const float*)d_in[6];
    const float* be1 = (const float*)d_in[7];
    const float* rm1 = (const float*)d_in[8];
    const float* rv1 = (const float*)d_in[9];
    const float* w2  = (const float*)d_in[10];
    const float* as2 = (const float*)d_in[11];
    const float* ad2 = (const float*)d_in[12];
    const float* b2  = (const float*)d_in[13];
    const float* g2  = (const float*)d_in[14];
    const float* be2 = (const float*)d_in[15];
    const float* rm2 = (const float*)d_in[16];
    const float* rv2 = (const float*)d_in[17];
    const float* w3  = (const float*)d_in[18];
    const float* as3 = (const float*)d_in[19];
    const float* ad3 = (const float*)d_in[20];
    const float* b3  = (const float*)d_in[21];
    float* out = (float*)d_out;

    const size_t P128 = align256((size_t)N_NODES * 128 * 2);
    const size_t P256 = align256((size_t)N_NODES * 256 * 2);

    char* p = (char*)d_ws;
    // regA: xhi|xlo (fragment) -> o1fp8 (front quarter) -> o2hi (full, fragment)
    char* regA = p; p += P256;
    // regB: h1hi (front, row-major) -> g2hi (front, fragment) -> h3hi (front, ldh=64)
    char* regB = p; p += P256;
    unsigned short* xhi  = (unsigned short*)regA;
    unsigned short* xlo  = (unsigned short*)(regA + P128);
    unsigned short* o1p  = (unsigned short*)regA;   // fp8 pairs: N*64 u16
    unsigned short* o2hi = (unsigned short*)regA;
    unsigned short* h1hi = (unsigned short*)regB;
    unsigned short* g2hi = (unsigned short*)regB;
    unsigned short* h3hi = (unsigned short*)regB;  // N*64 u16 padded rows

    float* asrcA = (float*)p; p += align256((size_t)N_NODES * 4);
    float* adstA = (float*)p; p += align256((size_t)N_NODES * 4);
    float* asrcB = (float*)p; p += align256((size_t)N_NODES * 4);
    float* adstB = (float*)p; p += align256((size_t)N_NODES * 4);
    int* counts    = (int*)p; p += align256((size_t)N_NODES * 4);
    int* row_ptr   = (int*)p; p += align256((size_t)(N_NODES + 1) * 4);
    int* write_pos = (int*)p; p += align256((size_t)N_NODES * 4);
    int* src_sorted = (int*)p; p += align256((size_t)TOT_EDGES * 4);
    int* partials  = (int*)p;  p += align256(512 * 4);
    unsigned short* w1th = (unsigned short*)p; p += align256(128 * 128 * 2);
    unsigned short* w1tl = (unsigned short*)p; p += align256(128 * 128 * 2);
    unsigned short* w2th = (unsigned short*)p; p += align256(256 * 128 * 2);
    unsigned short* w2tl = (unsigned short*)p; p += align256(256 * 128 * 2);
    unsigned short* w3th = (unsigned short*)p; p += align256(48 * 256 * 2);
    unsigned short* w3tl = (unsigned short*)p; p += align256(48 * 256 * 2);
    unsigned short* ab1h = (unsigned short*)p; p += align256(16 * 128 * 2);
    unsigned short* ab1l = (unsigned short*)p; p += align256(16 * 128 * 2);
    unsigned short* ab3h = (unsigned short*)p; p += align256(16 * 256 * 2);
    unsigned short* ab3l = (unsigned short*)p; p += align256(16 * 256 * 2);
    float* ws2f = (float*)p; p += align256(128 * 4);
    float* wd2f = (float*)p; p += align256(128 * 4);

    const int NB = (N_NODES + 255) / 256;
    const int WTOT = 128 * 128 + 256 * 128 + 48 * 256 + 2048 + 4096 + 256;

    xconv_frag<<<4096, 256, 0, stream>>>(x, xhi, xlo);
    wprep_all<<<(WTOT + 255) / 256, 256, 0, stream>>>(
        w1, w2, w3, as1, ad1, as2, ad2, as3, ad3,
        w1th, w1tl, w2th, w2tl, w3th, w3tl,
        ab1h, ab1l, ab3h, ab3l, ws2f, wd2f);

    hipMemsetAsync(counts, 0, (size_t)N_NODES * 4, stream);
    count_kernel<<<4096, 256, 0, stream>>>(ei, counts);
    scan_partial<<<NB, 256, 0, stream>>>(counts, partials);
    scan_partials_kernel<<<1, 512, 0, stream>>>(partials, NB);
    scan_final<<<NB, 256, 0, stream>>>(counts, partials, row_ptr, write_pos);
    for (int ps = 0; ps < NPASS; ps++)
        scatter_pass<<<2048, 256, 0, stream>>>(ei, write_pos, src_sorted,
                                               ps * PASS_W, (ps + 1) * PASS_W);

    const int NWB = (N_NODES + 3) / 4;
    const int G64 = (N_NODES + 63) / 64;
    const int G256 = (N_NODES + 255) / 256;

    // --- Layer 1: h1 = x@w1 (+alpha1), A fragment-major; agg1 -> o1 (fp8) ---
    mfma_gemm<128, 2, 1, 4, 128, true, true, false, false><<<G64, 256, 0, stream>>>(
        xhi, xlo, w1th, w1tl, ab1h, ab1l, h1hi, 128,
        nullptr, nullptr, nullptr, nullptr, nullptr, asrcA, adstA, N_NODES);
    gat_agg8<128, 0, 0, 128, true><<<NWB, 256, 0, stream>>>(
        h1hi, asrcA, adstA, row_ptr, src_sorted,
        b1, g1, be1, rm1, rv1, ws2f, wd2f,
        o1p, nullptr, asrcB, adstB);

    // --- Layer 2 (commuted): g2 = S2(o1 fp8) -> fragment-major bf16-hi;
    //     o2 = tanh(BN(g2@w2 + b2)) -> fragment-major (GEMM3's A) ---
    gat_agg8<128, 2, 1, 64, false><<<NWB, 256, 0, stream>>>(
        o1p, asrcB, adstB, row_ptr, src_sorted,
        nullptr, nullptr, nullptr, nullptr, nullptr, nullptr, nullptr,
        g2hi, nullptr, nullptr, nullptr);
    mfma_gemm<128, 2, 1, 4, 256, false, false, true, true><<<dim3(G64, 2), 256, 0, stream>>>(
        g2hi, nullptr, w2th, w2tl, nullptr, nullptr, o2hi, 256,
        b2, g2, be2, rm2, rv2, nullptr, nullptr, N_NODES);

    // --- Layer 3: h3 = o2@w3 (A fragment, +alpha3, C row-major ldh=64); agg3 -> out ---
    mfma_gemm<256, 3, 4, 1, 48, false, true, false, false><<<G256, 256, 0, stream>>>(
        o2hi, nullptr, w3th, w3tl, ab3h, ab3l, h3hi, 64,
        nullptr, nullptr, nullptr, nullptr, nullptr, asrcA, adstA, N_NODES);
    gat_agg8<40, 1, 2, 64, false><<<NWB, 256, 0, stream>>>(
        h3hi, asrcA, adstA, row_ptr, src_sorted,
        b3, nullptr, nullptr, nullptr, nullptr, nullptr, nullptr,
        nullptr, out, nullptr, nullptr);
}